// Round 1
// baseline (3009.497 us; speedup 1.0000x reference)
//
#include <hip/hip_runtime.h>
#include <hip/hip_bf16.h>

// Problem constants (fixed by reference)
#define NSEQ 8192
#define DDIM 512
#define HEADS 8
#define DH 64
#define MLM 256
#define LSUB 32          // NSEQ / MLM
#define WP 256
#define KCONV 33
#define INNER 512        // HEADS*DH
#define QKV_LD 1536

// ---------------- workspace layout (in floats) ----------------
// qkv region reused later for q_edge/k_edge/value
static const size_t OFF_QKV   = 0;                 // 8192*1536 = 12,582,912
static const size_t OFF_ATTN  = 12582912;          // 8192*512
static const size_t OFF_ENC   = 16777216;          // 8192*512
static const size_t OFF_WQT   = 20971520;          // 256*512
static const size_t OFF_WKT   = 21102592;
static const size_t OFF_QL    = 21233664;          // 8*256*64
static const size_t OFF_KL    = 21364736;
static const size_t OFF_A2    = 21495808;          // 8*256*256
static const size_t OFF_Z0    = 22020096;
static const size_t OFF_Z1    = 22544384;
static const size_t OFF_P     = 23068672;
static const size_t OFF_T1    = 23592960;
static const size_t OFF_T2    = 24117248;
static const size_t OFF_A3V   = 24641536;          // 8*256*64
static const size_t OFF_BB    = 24772608;          // 8*256*64
static const size_t OFF_SCAL  = 24903680;          // 2 uints
static const size_t OFF_ALPHA = 24903696;          // 8192
// reuse of qkv region (only valid after enc GEMM):
static const size_t OFF_QE    = 0;                 // 8192*256
static const size_t OFF_KE    = 2097152;           // 8192*256
static const size_t OFF_VAL   = 4194304;           // 8192*512

// ---------------- generic NT GEMM: C[m,n] = sum_k A[m,k]*B[n,k] (+bias +add) ----
// tiles 64x64x16, 256 threads, 4x4 per thread, K-major LDS for b128 reads
__global__ __launch_bounds__(256) void gemm_nt(
    const float* __restrict__ A, int lda,
    const float* __restrict__ B, int ldb,
    float* __restrict__ C, int ldc, int K,
    const float* __restrict__ bias,
    const float* __restrict__ addsrc)
{
    __shared__ __align__(16) float As[16][68];
    __shared__ __align__(16) float Bs[16][68];
    const int tid = threadIdx.x;
    const int tx = tid & 15, ty = tid >> 4;
    const size_t bm = (size_t)blockIdx.x * 64;
    const size_t bn = (size_t)blockIdx.y * 64;
    const int lr = tid >> 2;           // 0..63
    const int lc = (tid & 3) << 2;     // 0,4,8,12
    const float* Ap = A + (bm + lr) * (size_t)lda + lc;
    const float* Bp = B + (bn + lr) * (size_t)ldb + lc;
    float acc[4][4] = {};
    for (int k0 = 0; k0 < K; k0 += 16) {
        float4 av = *reinterpret_cast<const float4*>(Ap + k0);
        float4 bv = *reinterpret_cast<const float4*>(Bp + k0);
        __syncthreads();
        As[lc + 0][lr] = av.x; As[lc + 1][lr] = av.y;
        As[lc + 2][lr] = av.z; As[lc + 3][lr] = av.w;
        Bs[lc + 0][lr] = bv.x; Bs[lc + 1][lr] = bv.y;
        Bs[lc + 2][lr] = bv.z; Bs[lc + 3][lr] = bv.w;
        __syncthreads();
#pragma unroll
        for (int kk = 0; kk < 16; ++kk) {
            float4 a = *reinterpret_cast<const float4*>(&As[kk][ty << 2]);
            float4 b = *reinterpret_cast<const float4*>(&Bs[kk][tx << 2]);
            acc[0][0] += a.x * b.x; acc[0][1] += a.x * b.y; acc[0][2] += a.x * b.z; acc[0][3] += a.x * b.w;
            acc[1][0] += a.y * b.x; acc[1][1] += a.y * b.y; acc[1][2] += a.y * b.z; acc[1][3] += a.y * b.w;
            acc[2][0] += a.z * b.x; acc[2][1] += a.z * b.y; acc[2][2] += a.z * b.z; acc[2][3] += a.z * b.w;
            acc[3][0] += a.w * b.x; acc[3][1] += a.w * b.y; acc[3][2] += a.w * b.z; acc[3][3] += a.w * b.w;
        }
    }
#pragma unroll
    for (int i = 0; i < 4; ++i) {
        size_t row = bm + (ty << 2) + i;
#pragma unroll
        for (int j = 0; j < 4; ++j) {
            size_t col = bn + (tx << 2) + j;
            float v = acc[i][j];
            if (bias)   v += bias[col];
            if (addsrc) v += addsrc[row * (size_t)ldc + col];
            C[row * (size_t)ldc + col] = v;
        }
    }
}

// ------------- batched NN GEMM: C = beta*(A@B) + alpha*A  (alpha path needs square) ----
__global__ __launch_bounds__(256) void bmm_nn(
    const float* __restrict__ A, const float* __restrict__ B, float* __restrict__ C,
    int M, int N, int K, int sA, int sB, int sC, float alpha, float beta)
{
    __shared__ float As[32][33];
    __shared__ float Bs[32][33];
    const int b = blockIdx.y;
    const int ntiles = N >> 5;
    const int tm = blockIdx.x / ntiles, tn = blockIdx.x % ntiles;
    const float* Ab = A + (size_t)b * sA;
    const float* Bb = B + (size_t)b * sB;
    float* Cb = C + (size_t)b * sC;
    const int tid = threadIdx.x;
    const int tx = tid & 15, ty = tid >> 4;
    const int lr = tid >> 3;          // 0..31
    const int lc = (tid & 7) << 2;    // 0..28
    float acc[2][2] = {};
    for (int k0 = 0; k0 < K; k0 += 32) {
        float4 av = *reinterpret_cast<const float4*>(Ab + (size_t)(tm * 32 + lr) * K + k0 + lc);
        float4 bv = *reinterpret_cast<const float4*>(Bb + (size_t)(k0 + lr) * N + tn * 32 + lc);
        __syncthreads();
        As[lr][lc + 0] = av.x; As[lr][lc + 1] = av.y; As[lr][lc + 2] = av.z; As[lr][lc + 3] = av.w;
        Bs[lr][lc + 0] = bv.x; Bs[lr][lc + 1] = bv.y; Bs[lr][lc + 2] = bv.z; Bs[lr][lc + 3] = bv.w;
        __syncthreads();
#pragma unroll
        for (int kk = 0; kk < 32; ++kk) {
            float a0 = As[ty * 2 + 0][kk], a1 = As[ty * 2 + 1][kk];
            float b0 = Bs[kk][tx * 2 + 0], b1 = Bs[kk][tx * 2 + 1];
            acc[0][0] += a0 * b0; acc[0][1] += a0 * b1;
            acc[1][0] += a1 * b0; acc[1][1] += a1 * b1;
        }
    }
#pragma unroll
    for (int i = 0; i < 2; ++i)
#pragma unroll
        for (int j = 0; j < 2; ++j) {
            int row = tm * 32 + ty * 2 + i, col = tn * 32 + tx * 2 + j;
            float v = beta * acc[i][j];
            if (alpha != 0.f) v += alpha * Ab[(size_t)row * K + col];
            Cb[(size_t)row * N + col] = v;
        }
}

// ------------- small transpose: out[c,r] = in[r,c] -------------
__global__ __launch_bounds__(256) void transpose_k(
    const float* __restrict__ in, float* __restrict__ out, int R, int C)
{
    int idx = blockIdx.x * 256 + threadIdx.x;
    if (idx < R * C) {
        int r = idx / C, c = idx % C;
        out[(size_t)c * R + r] = in[idx];
    }
}

// ------------- landmark means (q scaled by 1/8) -------------
__global__ __launch_bounds__(64) void landmark_k(
    const float* __restrict__ qkv, float* __restrict__ q_l, float* __restrict__ k_l)
{
    int m = blockIdx.x, h = blockIdx.y, d = threadIdx.x;
    float sq = 0.f, sk = 0.f;
    for (int i = 0; i < LSUB; ++i) {
        size_t n = (size_t)m * LSUB + i;
        sq += qkv[n * QKV_LD + h * DH + d];
        sk += qkv[n * QKV_LD + 512 + h * DH + d];
    }
    q_l[((size_t)h * MLM + m) * DH + d] = sq * (0.125f / (float)LSUB);
    k_l[((size_t)h * MLM + m) * DH + d] = sk * (1.f / (float)LSUB);
}

// ------------- a2 = softmax(q_l @ k_l^T) rows -------------
__global__ __launch_bounds__(256) void a2_k(
    const float* __restrict__ q_l, const float* __restrict__ k_l, float* __restrict__ a2)
{
    int i = blockIdx.x, h = blockIdx.y, t = threadIdx.x;
    __shared__ float ql[64];
    __shared__ float red[256];
    if (t < 64) ql[t] = q_l[((size_t)h * MLM + i) * DH + t];
    __syncthreads();
    const float* kr = k_l + ((size_t)h * MLM + t) * DH;
    float s = 0.f;
#pragma unroll
    for (int d = 0; d < 64; d += 4) {
        float4 kv = *reinterpret_cast<const float4*>(kr + d);
        s += kv.x * ql[d] + kv.y * ql[d + 1] + kv.z * ql[d + 2] + kv.w * ql[d + 3];
    }
    red[t] = s; __syncthreads();
    for (int off = 128; off > 0; off >>= 1) { if (t < off) red[t] = fmaxf(red[t], red[t + off]); __syncthreads(); }
    float m = red[0]; __syncthreads();
    float e = __expf(s - m);
    red[t] = e; __syncthreads();
    for (int off = 128; off > 0; off >>= 1) { if (t < off) red[t] += red[t + off]; __syncthreads(); }
    a2[(((size_t)h * MLM + i) * MLM) + t] = e / red[0];
}

// ------------- global max of row-abs-sums / col-abs-sums of a2 -------------
__global__ __launch_bounds__(256) void absmax_k(
    const float* __restrict__ a2, unsigned int* __restrict__ scal)
{
    int b = blockIdx.x, t = threadIdx.x;
    __shared__ float red[256];
    float sum = 0.f;
    if (b < 8) {
        const float* r = a2 + ((size_t)b * MLM + t) * MLM;
        for (int j = 0; j < MLM; ++j) sum += fabsf(r[j]);
    } else {
        int h = b - 8;
        for (int i = 0; i < MLM; ++i) sum += fabsf(a2[((size_t)h * MLM + i) * MLM + t]);
    }
    red[t] = sum; __syncthreads();
    for (int off = 128; off > 0; off >>= 1) { if (t < off) red[t] = fmaxf(red[t], red[t + off]); __syncthreads(); }
    if (t == 0) atomicMax(scal + (b < 8 ? 0 : 1), __float_as_uint(red[0]));
}

// ------------- z0 = a2^T / (rmax*cmax) -------------
__global__ __launch_bounds__(256) void zinit_k(
    const float* __restrict__ a2, const unsigned int* __restrict__ scal, float* __restrict__ z)
{
    int idx = blockIdx.x * 256 + threadIdx.x;   // 8*256*256 total
    float rmax = __uint_as_float(scal[0]);
    float cmax = __uint_as_float(scal[1]);
    float inv = 1.f / (rmax * cmax);
    int h = idx >> 16, rem = idx & 65535, i = rem >> 8, j = rem & 255;
    z[idx] = a2[((size_t)h << 16) + (j << 8) + i] * inv;
}

// ------------- a3v[h,i,:] = softmax_j(q_l[h,i]·k[h,j]) @ v -------------
__global__ __launch_bounds__(256) void a3v_k(
    const float* __restrict__ qkv, const float* __restrict__ q_l, float* __restrict__ a3v)
{
    int i = blockIdx.x, h = blockIdx.y, t = threadIdx.x;
    __shared__ float sc[NSEQ];
    __shared__ float ql[64];
    __shared__ float red[256];
    if (t < 64) ql[t] = q_l[((size_t)h * MLM + i) * DH + t];
    __syncthreads();
    float lmax = -1e30f;
    for (int j = t; j < NSEQ; j += 256) {
        const float* kr = qkv + (size_t)j * QKV_LD + 512 + h * DH;
        float s = 0.f;
#pragma unroll
        for (int d = 0; d < 64; d += 4) {
            float4 kv = *reinterpret_cast<const float4*>(kr + d);
            s += kv.x * ql[d] + kv.y * ql[d + 1] + kv.z * ql[d + 2] + kv.w * ql[d + 3];
        }
        sc[j] = s; lmax = fmaxf(lmax, s);
    }
    red[t] = lmax; __syncthreads();
    for (int off = 128; off > 0; off >>= 1) { if (t < off) red[t] = fmaxf(red[t], red[t + off]); __syncthreads(); }
    float m = red[0]; __syncthreads();
    float lsum = 0.f;
    for (int j = t; j < NSEQ; j += 256) { float e = __expf(sc[j] - m); sc[j] = e; lsum += e; }
    red[t] = lsum; __syncthreads();
    for (int off = 128; off > 0; off >>= 1) { if (t < off) red[t] += red[t + off]; __syncthreads(); }
    float inv = 1.f / red[0];
    __syncthreads();
    int d = t & 63, g = t >> 6;
    float acc = 0.f;
    for (int j = g; j < NSEQ; j += 4)
        acc += sc[j] * qkv[(size_t)j * QKV_LD + 1024 + h * DH + d];
    red[t] = acc; __syncthreads();
    if (t < 64)
        a3v[((size_t)h * MLM + i) * DH + t] = (red[t] + red[t + 64] + red[t + 128] + red[t + 192]) * inv;
}

// ------------- attn row: softmax(q[h,n]·k_l) @ Bbuf -> attnbuf[n, h*64+d] ----
__global__ __launch_bounds__(256) void a1_k(
    const float* __restrict__ qkv, const float* __restrict__ k_l,
    const float* __restrict__ Bbuf, float* __restrict__ attnbuf)
{
    int n = blockIdx.x, h = blockIdx.y, t = threadIdx.x;
    __shared__ float qrow[64];
    __shared__ float p[256];
    __shared__ float red[256];
    if (t < 64) qrow[t] = qkv[(size_t)n * QKV_LD + h * DH + t] * 0.125f;
    __syncthreads();
    const float* kr = k_l + ((size_t)h * MLM + t) * DH;
    float s = 0.f;
#pragma unroll
    for (int d = 0; d < 64; d += 4) {
        float4 kv = *reinterpret_cast<const float4*>(kr + d);
        s += kv.x * qrow[d] + kv.y * qrow[d + 1] + kv.z * qrow[d + 2] + kv.w * qrow[d + 3];
    }
    red[t] = s; __syncthreads();
    for (int off = 128; off > 0; off >>= 1) { if (t < off) red[t] = fmaxf(red[t], red[t + off]); __syncthreads(); }
    float m = red[0]; __syncthreads();
    float e = __expf(s - m);
    p[t] = e; red[t] = e; __syncthreads();
    for (int off = 128; off > 0; off >>= 1) { if (t < off) red[t] += red[t + off]; __syncthreads(); }
    float inv = 1.f / red[0];
    __syncthreads();
    int d = t & 63, g = t >> 6;
    float acc = 0.f;
    for (int mm = g; mm < MLM; mm += 4)
        acc += p[mm] * Bbuf[((size_t)h * MLM + mm) * DH + d];
    red[t] = acc; __syncthreads();
    if (t < 64)
        attnbuf[(size_t)n * INNER + h * DH + t] = (red[t] + red[t + 64] + red[t + 128] + red[t + 192]) * inv;
}

// ------------- depthwise conv residual add -------------
__global__ __launch_bounds__(256) void conv_res_k(
    const float* __restrict__ qkv, const float* __restrict__ kern, float* __restrict__ attnbuf)
{
    size_t idx = (size_t)blockIdx.x * 256 + threadIdx.x;
    int n = (int)(idx >> 9), c = (int)(idx & 511), h = c >> 6;
    float acc = 0.f;
#pragma unroll
    for (int t2 = 0; t2 < KCONV; ++t2) {
        int nn = n + t2 - KCONV / 2;
        if (nn >= 0 && nn < NSEQ)
            acc += qkv[(size_t)nn * QKV_LD + 1024 + c] * kern[h * KCONV + t2];
    }
    attnbuf[idx] += acc;
}

// ------------- sparse edge scores + segment sum -------------
__global__ __launch_bounds__(256) void edge_k(
    const float* __restrict__ qe, const float* __restrict__ ke,
    const int* __restrict__ rows, const int* __restrict__ cols,
    const float* __restrict__ vals, float* __restrict__ A_raw)
{
    int e = blockIdx.x * 4 + (threadIdx.x >> 6);
    int lane = threadIdx.x & 63;
    int r = rows[e], c = cols[e];
    const float* qr = qe + (size_t)r * WP;
    const float* kr = ke + (size_t)c * WP;
    float4 a = *reinterpret_cast<const float4*>(qr + lane * 4);
    float4 b = *reinterpret_cast<const float4*>(kr + lane * 4);
    float s = a.x * b.x + a.y * b.y + a.z * b.z + a.w * b.w;
    for (int off = 32; off > 0; off >>= 1) s += __shfl_down(s, off, 64);
    if (lane == 0) atomicAdd(&A_raw[r], s * vals[e] * 0.0625f);
}

// ------------- alpha = softmax(A_raw) over all N -------------
__global__ __launch_bounds__(1024) void alpha_k(
    const float* __restrict__ A_raw, float* __restrict__ alpha)
{
    __shared__ float red[1024];
    int t = threadIdx.x;
    float m = -1e30f;
    for (int i = t; i < NSEQ; i += 1024) m = fmaxf(m, A_raw[i]);
    red[t] = m; __syncthreads();
    for (int off = 512; off > 0; off >>= 1) { if (t < off) red[t] = fmaxf(red[t], red[t + off]); __syncthreads(); }
    m = red[0]; __syncthreads();
    float s = 0.f;
    for (int i = t; i < NSEQ; i += 1024) s += __expf(A_raw[i] - m);
    red[t] = s; __syncthreads();
    for (int off = 512; off > 0; off >>= 1) { if (t < off) red[t] += red[t + off]; __syncthreads(); }
    float inv = 1.f / red[0];
    for (int i = t; i < NSEQ; i += 1024) alpha[i] = __expf(A_raw[i] - m) * inv;
}

// ------------- final gated blend -------------
__global__ __launch_bounds__(256) void final_k(
    const float* __restrict__ alpha, const float* __restrict__ value,
    const float* __restrict__ enc, float* __restrict__ xo)
{
    size_t idx = (size_t)blockIdx.x * 256 + threadIdx.x;
    int n = (int)(idx >> 9);
    float xl = alpha[n] * value[idx];
    float w = 1.f / (1.f + __expf(xl));   // sigmoid(-xl)
    float sq = w * w;
    xo[idx] = xl * 2.f * sq + 2.f * enc[idx] * (1.f - sq);
}

extern "C" void kernel_launch(void* const* d_in, const int* in_sizes, int n_in,
                              void* d_out, int out_size, void* d_ws, size_t ws_size,
                              hipStream_t stream)
{
    const float* dense      = (const float*)d_in[0];
    const int*   adj_rows   = (const int*)d_in[1];
    const int*   adj_cols   = (const int*)d_in[2];
    const float* adj_vals   = (const float*)d_in[3];
    const float* wq         = (const float*)d_in[4];
    const float* wk         = (const float*)d_in[5];
    const float* w_qkv      = (const float*)d_in[6];
    const float* w_out      = (const float*)d_in[7];
    const float* b_out      = (const float*)d_in[8];
    const float* res_kernel = (const float*)d_in[9];
    const float* wv_w       = (const float*)d_in[10];
    const float* wv_b       = (const float*)d_in[11];
    const int E = in_sizes[1];

    float* ws  = (float*)d_ws;
    float* out = (float*)d_out;
    float* A_raw = out + (size_t)NSEQ * DDIM;

    hipMemsetAsync(A_raw, 0, NSEQ * sizeof(float), stream);
    hipMemsetAsync(ws + OFF_SCAL, 0, 2 * sizeof(unsigned int), stream);

    transpose_k<<<512, 256, 0, stream>>>(wq, ws + OFF_WQT, DDIM, WP);
    transpose_k<<<512, 256, 0, stream>>>(wk, ws + OFF_WKT, DDIM, WP);

    // qkv = dense @ w_qkv^T
    gemm_nt<<<dim3(NSEQ / 64, 1536 / 64), 256, 0, stream>>>(
        dense, DDIM, w_qkv, DDIM, ws + OFF_QKV, QKV_LD, DDIM, nullptr, nullptr);

    landmark_k<<<dim3(MLM, HEADS), 64, 0, stream>>>(ws + OFF_QKV, ws + OFF_QL, ws + OFF_KL);
    a2_k<<<dim3(MLM, HEADS), 256, 0, stream>>>(ws + OFF_QL, ws + OFF_KL, ws + OFF_A2);
    absmax_k<<<16, 256, 0, stream>>>(ws + OFF_A2, (unsigned int*)(ws + OFF_SCAL));
    zinit_k<<<(HEADS * MLM * MLM) / 256, 256, 0, stream>>>(
        ws + OFF_A2, (const unsigned int*)(ws + OFF_SCAL), ws + OFF_Z0);
    a3v_k<<<dim3(MLM, HEADS), 256, 0, stream>>>(ws + OFF_QKV, ws + OFF_QL, ws + OFF_A3V);

    // pinv iterations: z' = 3.25 z - 0.25 z@(15P - P@(7P - P@P))  with P = a2@z
    for (int it = 0; it < 6; ++it) {
        float* zin  = ws + ((it & 1) ? OFF_Z1 : OFF_Z0);
        float* zout = ws + ((it & 1) ? OFF_Z0 : OFF_Z1);
        bmm_nn<<<dim3(64, HEADS), 256, 0, stream>>>(ws + OFF_A2, zin, ws + OFF_P,
            256, 256, 256, 65536, 65536, 65536, 0.f, 1.f);
        bmm_nn<<<dim3(64, HEADS), 256, 0, stream>>>(ws + OFF_P, ws + OFF_P, ws + OFF_T1,
            256, 256, 256, 65536, 65536, 65536, 7.f, -1.f);
        bmm_nn<<<dim3(64, HEADS), 256, 0, stream>>>(ws + OFF_P, ws + OFF_T1, ws + OFF_T2,
            256, 256, 256, 65536, 65536, 65536, 15.f, -1.f);
        bmm_nn<<<dim3(64, HEADS), 256, 0, stream>>>(zin, ws + OFF_T2, zout,
            256, 256, 256, 65536, 65536, 65536, 3.25f, -0.25f);
    }
    // Bbuf = z_final @ a3v   (z_final is in Z0 after 6 iterations)
    bmm_nn<<<dim3(16, HEADS), 256, 0, stream>>>(ws + OFF_Z0, ws + OFF_A3V, ws + OFF_BB,
        256, 64, 256, 65536, 16384, 16384, 0.f, 1.f);

    a1_k<<<dim3(NSEQ, HEADS), 256, 0, stream>>>(ws + OFF_QKV, ws + OFF_KL, ws + OFF_BB, ws + OFF_ATTN);
    conv_res_k<<<(NSEQ * INNER) / 256, 256, 0, stream>>>(ws + OFF_QKV, res_kernel, ws + OFF_ATTN);

    // enc = attn @ w_out^T + b_out + dense
    gemm_nt<<<dim3(NSEQ / 64, DDIM / 64), 256, 0, stream>>>(
        ws + OFF_ATTN, INNER, w_out, INNER, ws + OFF_ENC, DDIM, INNER, b_out, dense);

    // q_edge / k_edge  (qkv region is free now)
    gemm_nt<<<dim3(NSEQ / 64, WP / 64), 256, 0, stream>>>(
        ws + OFF_ENC, DDIM, ws + OFF_WQT, DDIM, ws + OFF_QE, WP, DDIM, nullptr, nullptr);
    gemm_nt<<<dim3(NSEQ / 64, WP / 64), 256, 0, stream>>>(
        ws + OFF_ENC, DDIM, ws + OFF_WKT, DDIM, ws + OFF_KE, WP, DDIM, nullptr, nullptr);

    edge_k<<<E / 4, 256, 0, stream>>>(ws + OFF_QE, ws + OFF_KE, adj_rows, adj_cols, adj_vals, A_raw);
    alpha_k<<<1, 1024, 0, stream>>>(A_raw, ws + OFF_ALPHA);

    // value = dense @ wv_w^T + wv_b
    gemm_nt<<<dim3(NSEQ / 64, DDIM / 64), 256, 0, stream>>>(
        dense, DDIM, wv_w, DDIM, ws + OFF_VAL, DDIM, DDIM, wv_b, nullptr);

    final_k<<<(NSEQ * DDIM) / 256, 256, 0, stream>>>(
        ws + OFF_ALPHA, ws + OFF_VAL, ws + OFF_ENC, out);
}

// Round 2
// 1092.841 us; speedup vs baseline: 2.7538x; 2.7538x over previous
//
#include <hip/hip_runtime.h>
#include <hip/hip_bf16.h>

// Problem constants (fixed by reference)
#define NSEQ 8192
#define DDIM 512
#define HEADS 8
#define DH 64
#define MLM 256
#define LSUB 32          // NSEQ / MLM
#define WP 256
#define KCONV 33
#define INNER 512        // HEADS*DH
#define QKV_LD 1536

// ---------------- workspace layout (in floats) ----------------
static const size_t OFF_QKV   = 0;                 // 8192*1536
static const size_t OFF_ATTN  = 12582912;          // 8192*512
static const size_t OFF_ENC   = 16777216;          // 8192*512
static const size_t OFF_WQT   = 20971520;          // 256*512
static const size_t OFF_WKT   = 21102592;
static const size_t OFF_QL    = 21233664;          // 8*256*64
static const size_t OFF_KL    = 21364736;
static const size_t OFF_A2    = 21495808;          // 8*256*256
static const size_t OFF_Z0    = 22020096;
static const size_t OFF_Z1    = 22544384;          // also PV3 partials [16][8][256][64]
static const size_t OFF_P     = 23068672;
static const size_t OFF_T1    = 23592960;
static const size_t OFF_T2    = 24117248;
static const size_t OFF_A3V   = 24641536;          // 8*256*64
static const size_t OFF_BB    = 24772608;          // 8*256*64
static const size_t OFF_SCAL  = 24903680;          // 2 uints
static const size_t OFF_ALPHA = 24903696;          // 8192
// reuse of qkv region (only valid after enc GEMM):
static const size_t OFF_QE    = 0;                 // 8192*256
static const size_t OFF_KE    = 2097152;           // 8192*256
static const size_t OFF_VAL   = 4194304;           // 8192*512
// bf16 scores: a3 scores at OFF_ATTN (spans ATTN+ENC = 33.55 MB);
//              a1 scores (4 heads/half) at OFF_ENC (16.77 MB)

__device__ __forceinline__ float bf2f(unsigned short u) {
    return __uint_as_float(((unsigned int)u) << 16);
}
__device__ __forceinline__ unsigned short f2bf(float x) {
    unsigned int u = __float_as_uint(x);
    u += 0x7FFFu + ((u >> 16) & 1u);   // RNE
    return (unsigned short)(u >> 16);
}

// ---------------- generic NT GEMM: C[m,n] = sum_k A[m,k]*B[n,k] (+bias +add) ----
__global__ __launch_bounds__(256) void gemm_nt(
    const float* __restrict__ A, int lda,
    const float* __restrict__ B, int ldb,
    float* __restrict__ C, int ldc, int K,
    const float* __restrict__ bias,
    const float* __restrict__ addsrc)
{
    __shared__ __align__(16) float As[16][68];
    __shared__ __align__(16) float Bs[16][68];
    const int tid = threadIdx.x;
    const int tx = tid & 15, ty = tid >> 4;
    const size_t bm = (size_t)blockIdx.x * 64;
    const size_t bn = (size_t)blockIdx.y * 64;
    const int lr = tid >> 2;
    const int lc = (tid & 3) << 2;
    const float* Ap = A + (bm + lr) * (size_t)lda + lc;
    const float* Bp = B + (bn + lr) * (size_t)ldb + lc;
    float acc[4][4] = {};
    for (int k0 = 0; k0 < K; k0 += 16) {
        float4 av = *reinterpret_cast<const float4*>(Ap + k0);
        float4 bv = *reinterpret_cast<const float4*>(Bp + k0);
        __syncthreads();
        As[lc + 0][lr] = av.x; As[lc + 1][lr] = av.y;
        As[lc + 2][lr] = av.z; As[lc + 3][lr] = av.w;
        Bs[lc + 0][lr] = bv.x; Bs[lc + 1][lr] = bv.y;
        Bs[lc + 2][lr] = bv.z; Bs[lc + 3][lr] = bv.w;
        __syncthreads();
#pragma unroll
        for (int kk = 0; kk < 16; ++kk) {
            float4 a = *reinterpret_cast<const float4*>(&As[kk][ty << 2]);
            float4 b = *reinterpret_cast<const float4*>(&Bs[kk][tx << 2]);
            acc[0][0] += a.x * b.x; acc[0][1] += a.x * b.y; acc[0][2] += a.x * b.z; acc[0][3] += a.x * b.w;
            acc[1][0] += a.y * b.x; acc[1][1] += a.y * b.y; acc[1][2] += a.y * b.z; acc[1][3] += a.y * b.w;
            acc[2][0] += a.z * b.x; acc[2][1] += a.z * b.y; acc[2][2] += a.z * b.z; acc[2][3] += a.z * b.w;
            acc[3][0] += a.w * b.x; acc[3][1] += a.w * b.y; acc[3][2] += a.w * b.z; acc[3][3] += a.w * b.w;
        }
    }
#pragma unroll
    for (int i = 0; i < 4; ++i) {
        size_t row = bm + (ty << 2) + i;
#pragma unroll
        for (int j = 0; j < 4; ++j) {
            size_t col = bn + (tx << 2) + j;
            float v = acc[i][j];
            if (bias)   v += bias[col];
            if (addsrc) v += addsrc[row * (size_t)ldc + col];
            C[row * (size_t)ldc + col] = v;
        }
    }
}

// ------------- batched NN GEMM: C = beta*(A@B) + alpha*A -------------
__global__ __launch_bounds__(256) void bmm_nn(
    const float* __restrict__ A, const float* __restrict__ B, float* __restrict__ C,
    int M, int N, int K, int sA, int sB, int sC, float alpha, float beta)
{
    __shared__ float As[32][33];
    __shared__ float Bs[32][33];
    const int b = blockIdx.y;
    const int ntiles = N >> 5;
    const int tm = blockIdx.x / ntiles, tn = blockIdx.x % ntiles;
    const float* Ab = A + (size_t)b * sA;
    const float* Bb = B + (size_t)b * sB;
    float* Cb = C + (size_t)b * sC;
    const int tid = threadIdx.x;
    const int tx = tid & 15, ty = tid >> 4;
    const int lr = tid >> 3;
    const int lc = (tid & 7) << 2;
    float acc[2][2] = {};
    for (int k0 = 0; k0 < K; k0 += 32) {
        float4 av = *reinterpret_cast<const float4*>(Ab + (size_t)(tm * 32 + lr) * K + k0 + lc);
        float4 bv = *reinterpret_cast<const float4*>(Bb + (size_t)(k0 + lr) * N + tn * 32 + lc);
        __syncthreads();
        As[lr][lc + 0] = av.x; As[lr][lc + 1] = av.y; As[lr][lc + 2] = av.z; As[lr][lc + 3] = av.w;
        Bs[lr][lc + 0] = bv.x; Bs[lr][lc + 1] = bv.y; Bs[lr][lc + 2] = bv.z; Bs[lr][lc + 3] = bv.w;
        __syncthreads();
#pragma unroll
        for (int kk = 0; kk < 32; ++kk) {
            float a0 = As[ty * 2 + 0][kk], a1 = As[ty * 2 + 1][kk];
            float b0 = Bs[kk][tx * 2 + 0], b1 = Bs[kk][tx * 2 + 1];
            acc[0][0] += a0 * b0; acc[0][1] += a0 * b1;
            acc[1][0] += a1 * b0; acc[1][1] += a1 * b1;
        }
    }
#pragma unroll
    for (int i = 0; i < 2; ++i)
#pragma unroll
        for (int j = 0; j < 2; ++j) {
            int row = tm * 32 + ty * 2 + i, col = tn * 32 + tx * 2 + j;
            float v = beta * acc[i][j];
            if (alpha != 0.f) v += alpha * Ab[(size_t)row * K + col];
            Cb[(size_t)row * N + col] = v;
        }
}

// ------------- small transpose -------------
__global__ __launch_bounds__(256) void transpose_k(
    const float* __restrict__ in, float* __restrict__ out, int R, int C)
{
    int idx = blockIdx.x * 256 + threadIdx.x;
    if (idx < R * C) {
        int r = idx / C, c = idx % C;
        out[(size_t)c * R + r] = in[idx];
    }
}

// ------------- landmark means (q scaled by 1/8) -------------
__global__ __launch_bounds__(64) void landmark_k(
    const float* __restrict__ qkv, float* __restrict__ q_l, float* __restrict__ k_l)
{
    int m = blockIdx.x, h = blockIdx.y, d = threadIdx.x;
    float sq = 0.f, sk = 0.f;
    for (int i = 0; i < LSUB; ++i) {
        size_t n = (size_t)m * LSUB + i;
        sq += qkv[n * QKV_LD + h * DH + d];
        sk += qkv[n * QKV_LD + 512 + h * DH + d];
    }
    q_l[((size_t)h * MLM + m) * DH + d] = sq * (0.125f / (float)LSUB);
    k_l[((size_t)h * MLM + m) * DH + d] = sk * (1.f / (float)LSUB);
}

// ------------- a2 = softmax(q_l @ k_l^T) rows -------------
__global__ __launch_bounds__(256) void a2_k(
    const float* __restrict__ q_l, const float* __restrict__ k_l, float* __restrict__ a2)
{
    int i = blockIdx.x, h = blockIdx.y, t = threadIdx.x;
    __shared__ float ql[64];
    __shared__ float red[256];
    if (t < 64) ql[t] = q_l[((size_t)h * MLM + i) * DH + t];
    __syncthreads();
    const float* kr = k_l + ((size_t)h * MLM + t) * DH;
    float s = 0.f;
#pragma unroll
    for (int d = 0; d < 64; d += 4) {
        float4 kv = *reinterpret_cast<const float4*>(kr + d);
        s += kv.x * ql[d] + kv.y * ql[d + 1] + kv.z * ql[d + 2] + kv.w * ql[d + 3];
    }
    red[t] = s; __syncthreads();
    for (int off = 128; off > 0; off >>= 1) { if (t < off) red[t] = fmaxf(red[t], red[t + off]); __syncthreads(); }
    float m = red[0]; __syncthreads();
    float e = __expf(s - m);
    red[t] = e; __syncthreads();
    for (int off = 128; off > 0; off >>= 1) { if (t < off) red[t] += red[t + off]; __syncthreads(); }
    a2[(((size_t)h * MLM + i) * MLM) + t] = e / red[0];
}

// ------------- global max of row/col abs-sums of a2 -------------
__global__ __launch_bounds__(256) void absmax_k(
    const float* __restrict__ a2, unsigned int* __restrict__ scal)
{
    int b = blockIdx.x, t = threadIdx.x;
    __shared__ float red[256];
    float sum = 0.f;
    if (b < 8) {
        const float* r = a2 + ((size_t)b * MLM + t) * MLM;
        for (int j = 0; j < MLM; ++j) sum += fabsf(r[j]);
    } else {
        int h = b - 8;
        for (int i = 0; i < MLM; ++i) sum += fabsf(a2[((size_t)h * MLM + i) * MLM + t]);
    }
    red[t] = sum; __syncthreads();
    for (int off = 128; off > 0; off >>= 1) { if (t < off) red[t] = fmaxf(red[t], red[t + off]); __syncthreads(); }
    if (t == 0) atomicMax(scal + (b < 8 ? 0 : 1), __float_as_uint(red[0]));
}

// ------------- z0 = a2^T / (rmax*cmax) -------------
__global__ __launch_bounds__(256) void zinit_k(
    const float* __restrict__ a2, const unsigned int* __restrict__ scal, float* __restrict__ z)
{
    int idx = blockIdx.x * 256 + threadIdx.x;
    float rmax = __uint_as_float(scal[0]);
    float cmax = __uint_as_float(scal[1]);
    float inv = 1.f / (rmax * cmax);
    int h = idx >> 16, rem = idx & 65535, i = rem >> 8, j = rem & 255;
    z[idx] = a2[((size_t)h << 16) + (j << 8) + i] * inv;
}

// ======================= a3 pipeline (GEMM-style) =======================
// scores3[h,i,j] = dot(q_l[h,i,:], k[h,j,:])  -> bf16, ldc = NSEQ
__global__ __launch_bounds__(256) void qk3_k(
    const float* __restrict__ q_l, const float* __restrict__ qkv,
    unsigned short* __restrict__ sc)
{
    __shared__ __align__(16) float As[16][68];
    __shared__ __align__(16) float Bs[16][68];
    const int h = blockIdx.z;
    const int tid = threadIdx.x;
    const int tx = tid & 15, ty = tid >> 4;
    const size_t bm = (size_t)blockIdx.x * 64;   // i
    const size_t bn = (size_t)blockIdx.y * 64;   // j
    const int lr = tid >> 2, lc = (tid & 3) << 2;
    const float* Ap = q_l + ((size_t)h * MLM + bm + lr) * DH + lc;
    const float* Bp = qkv + 512 + h * DH + (bn + lr) * (size_t)QKV_LD + lc;
    float acc[4][4] = {};
    for (int k0 = 0; k0 < DH; k0 += 16) {
        float4 av = *reinterpret_cast<const float4*>(Ap + k0);
        float4 bv = *reinterpret_cast<const float4*>(Bp + k0);
        __syncthreads();
        As[lc + 0][lr] = av.x; As[lc + 1][lr] = av.y;
        As[lc + 2][lr] = av.z; As[lc + 3][lr] = av.w;
        Bs[lc + 0][lr] = bv.x; Bs[lc + 1][lr] = bv.y;
        Bs[lc + 2][lr] = bv.z; Bs[lc + 3][lr] = bv.w;
        __syncthreads();
#pragma unroll
        for (int kk = 0; kk < 16; ++kk) {
            float4 a = *reinterpret_cast<const float4*>(&As[kk][ty << 2]);
            float4 b = *reinterpret_cast<const float4*>(&Bs[kk][tx << 2]);
            acc[0][0] += a.x * b.x; acc[0][1] += a.x * b.y; acc[0][2] += a.x * b.z; acc[0][3] += a.x * b.w;
            acc[1][0] += a.y * b.x; acc[1][1] += a.y * b.y; acc[1][2] += a.y * b.z; acc[1][3] += a.y * b.w;
            acc[2][0] += a.z * b.x; acc[2][1] += a.z * b.y; acc[2][2] += a.z * b.z; acc[2][3] += a.z * b.w;
            acc[3][0] += a.w * b.x; acc[3][1] += a.w * b.y; acc[3][2] += a.w * b.z; acc[3][3] += a.w * b.w;
        }
    }
    unsigned short* C = sc + (size_t)h * MLM * NSEQ;
#pragma unroll
    for (int i = 0; i < 4; ++i)
#pragma unroll
        for (int j = 0; j < 4; ++j)
            C[(bm + (ty << 2) + i) * NSEQ + bn + (tx << 2) + j] = f2bf(acc[i][j]);
}

// row softmax over 8192 bf16, in place; one block per row
__global__ __launch_bounds__(256) void sm3_k(unsigned short* __restrict__ sc)
{
    __shared__ float red[256];
    const int t = threadIdx.x;
    unsigned short* row = sc + (size_t)blockIdx.x * NSEQ;
    float v[32];
    float lmax = -1e30f;
#pragma unroll
    for (int u = 0; u < 4; ++u) {
        uint4 pk = *reinterpret_cast<const uint4*>(row + t * 32 + u * 8);
        unsigned int w[4] = {pk.x, pk.y, pk.z, pk.w};
#pragma unroll
        for (int q = 0; q < 4; ++q) {
            float lo = bf2f((unsigned short)(w[q] & 0xFFFF));
            float hi = bf2f((unsigned short)(w[q] >> 16));
            v[u * 8 + q * 2 + 0] = lo; v[u * 8 + q * 2 + 1] = hi;
            lmax = fmaxf(lmax, fmaxf(lo, hi));
        }
    }
    red[t] = lmax; __syncthreads();
    for (int off = 128; off > 0; off >>= 1) { if (t < off) red[t] = fmaxf(red[t], red[t + off]); __syncthreads(); }
    float m = red[0]; __syncthreads();
    float s = 0.f;
#pragma unroll
    for (int u = 0; u < 32; ++u) { v[u] = __expf(v[u] - m); s += v[u]; }
    red[t] = s; __syncthreads();
    for (int off = 128; off > 0; off >>= 1) { if (t < off) red[t] += red[t + off]; __syncthreads(); }
    float inv = 1.f / red[0];
#pragma unroll
    for (int u = 0; u < 4; ++u) {
        uint4 pk;
        unsigned int w[4];
#pragma unroll
        for (int q = 0; q < 4; ++q) {
            unsigned int lo = f2bf(v[u * 8 + q * 2 + 0] * inv);
            unsigned int hi = f2bf(v[u * 8 + q * 2 + 1] * inv);
            w[q] = lo | (hi << 16);
        }
        pk.x = w[0]; pk.y = w[1]; pk.z = w[2]; pk.w = w[3];
        *reinterpret_cast<uint4*>(row + t * 32 + u * 8) = pk;
    }
}

// PV split-K: part[kc][h][i][d] = sum_{j in chunk kc} P[h,i,j] * v[h,j,d]
__global__ __launch_bounds__(256) void pv3_k(
    const unsigned short* __restrict__ sc, const float* __restrict__ qkv,
    float* __restrict__ part)
{
    __shared__ __align__(16) float As[16][68];
    __shared__ __align__(16) float Bs[16][68];
    const int it = blockIdx.x;     // i-tile (0..3)
    const int kc = blockIdx.y;     // k-chunk (0..15), 512 each
    const int h  = blockIdx.z;
    const int tid = threadIdx.x;
    const int tx = tid & 15, ty = tid >> 4;
    const int lr = tid >> 2, lc = (tid & 3) << 2;    // A load
    const int kr = tid >> 4, dc = (tid & 15) << 2;   // B load
    const unsigned short* Ap = sc + ((size_t)h * MLM + it * 64 + lr) * NSEQ + kc * 512;
    const float* Bp = qkv + 1024 + h * DH + dc;
    float acc[4][4] = {};
    for (int k0 = 0; k0 < 512; k0 += 16) {
        ushort4 av = *reinterpret_cast<const ushort4*>(Ap + k0 + lc);
        float4 bv = *reinterpret_cast<const float4*>(Bp + (size_t)(kc * 512 + k0 + kr) * QKV_LD);
        __syncthreads();
        As[lc + 0][lr] = bf2f(av.x); As[lc + 1][lr] = bf2f(av.y);
        As[lc + 2][lr] = bf2f(av.z); As[lc + 3][lr] = bf2f(av.w);
        Bs[kr][dc + 0] = bv.x; Bs[kr][dc + 1] = bv.y;
        Bs[kr][dc + 2] = bv.z; Bs[kr][dc + 3] = bv.w;
        __syncthreads();
#pragma unroll
        for (int kk = 0; kk < 16; ++kk) {
            float4 a = *reinterpret_cast<const float4*>(&As[kk][ty << 2]);
            float4 b = *reinterpret_cast<const float4*>(&Bs[kk][tx << 2]);
            acc[0][0] += a.x * b.x; acc[0][1] += a.x * b.y; acc[0][2] += a.x * b.z; acc[0][3] += a.x * b.w;
            acc[1][0] += a.y * b.x; acc[1][1] += a.y * b.y; acc[1][2] += a.y * b.z; acc[1][3] += a.y * b.w;
            acc[2][0] += a.z * b.x; acc[2][1] += a.z * b.y; acc[2][2] += a.z * b.z; acc[2][3] += a.z * b.w;
            acc[3][0] += a.w * b.x; acc[3][1] += a.w * b.y; acc[3][2] += a.w * b.z; acc[3][3] += a.w * b.w;
        }
    }
    float* Cp = part + ((size_t)(kc * 8 + h) * MLM + it * 64) * DH;
#pragma unroll
    for (int i = 0; i < 4; ++i)
#pragma unroll
        for (int j = 0; j < 4; ++j)
            Cp[((ty << 2) + i) * DH + (tx << 2) + j] = acc[i][j];
}

__global__ __launch_bounds__(256) void red3_k(
    const float* __restrict__ part, float* __restrict__ a3v)
{
    int o = blockIdx.x * 256 + threadIdx.x;   // 131072 outputs
    float s = 0.f;
#pragma unroll
    for (int kc = 0; kc < 16; ++kc) s += part[(size_t)kc * 131072 + o];
    a3v[o] = s;
}

// ======================= a1 pipeline (GEMM-style, 4 heads/half) ==========
// scores1[hz,n,j] = dot(0.125*q[n, h*64:...], k_l[h,j,:]) bf16, ldc=MLM
__global__ __launch_bounds__(256) void qk1_k(
    const float* __restrict__ qkv, const float* __restrict__ k_l,
    unsigned short* __restrict__ sc, int hb)
{
    __shared__ __align__(16) float As[16][68];
    __shared__ __align__(16) float Bs[16][68];
    const int hz = blockIdx.z;
    const int h = hb + hz;
    const int tid = threadIdx.x;
    const int tx = tid & 15, ty = tid >> 4;
    const size_t bm = (size_t)blockIdx.x * 64;   // n
    const size_t bn = (size_t)blockIdx.y * 64;   // j
    const int lr = tid >> 2, lc = (tid & 3) << 2;
    const float* Ap = qkv + (bm + lr) * (size_t)QKV_LD + h * DH + lc;
    const float* Bp = k_l + ((size_t)h * MLM + bn + lr) * DH + lc;
    float acc[4][4] = {};
    for (int k0 = 0; k0 < DH; k0 += 16) {
        float4 av = *reinterpret_cast<const float4*>(Ap + k0);
        float4 bv = *reinterpret_cast<const float4*>(Bp + k0);
        av.x *= 0.125f; av.y *= 0.125f; av.z *= 0.125f; av.w *= 0.125f;
        __syncthreads();
        As[lc + 0][lr] = av.x; As[lc + 1][lr] = av.y;
        As[lc + 2][lr] = av.z; As[lc + 3][lr] = av.w;
        Bs[lc + 0][lr] = bv.x; Bs[lc + 1][lr] = bv.y;
        Bs[lc + 2][lr] = bv.z; Bs[lc + 3][lr] = bv.w;
        __syncthreads();
#pragma unroll
        for (int kk = 0; kk < 16; ++kk) {
            float4 a = *reinterpret_cast<const float4*>(&As[kk][ty << 2]);
            float4 b = *reinterpret_cast<const float4*>(&Bs[kk][tx << 2]);
            acc[0][0] += a.x * b.x; acc[0][1] += a.x * b.y; acc[0][2] += a.x * b.z; acc[0][3] += a.x * b.w;
            acc[1][0] += a.y * b.x; acc[1][1] += a.y * b.y; acc[1][2] += a.y * b.z; acc[1][3] += a.y * b.w;
            acc[2][0] += a.z * b.x; acc[2][1] += a.z * b.y; acc[2][2] += a.z * b.z; acc[2][3] += a.z * b.w;
            acc[3][0] += a.w * b.x; acc[3][1] += a.w * b.y; acc[3][2] += a.w * b.z; acc[3][3] += a.w * b.w;
        }
    }
    unsigned short* C = sc + (size_t)hz * NSEQ * MLM;
#pragma unroll
    for (int i = 0; i < 4; ++i)
#pragma unroll
        for (int j = 0; j < 4; ++j)
            C[(bm + (ty << 2) + i) * MLM + bn + (tx << 2) + j] = f2bf(acc[i][j]);
}

// softmax over rows of length 256, one wave per row (4 rows/block)
__global__ __launch_bounds__(256) void sm1_k(unsigned short* __restrict__ sc)
{
    const int row = blockIdx.x * 4 + (threadIdx.x >> 6);
    const int lane = threadIdx.x & 63;
    unsigned short* rp = sc + (size_t)row * MLM;
    uint2 pk = *reinterpret_cast<const uint2*>(rp + lane * 4);
    float x0 = bf2f((unsigned short)(pk.x & 0xFFFF));
    float x1 = bf2f((unsigned short)(pk.x >> 16));
    float x2 = bf2f((unsigned short)(pk.y & 0xFFFF));
    float x3 = bf2f((unsigned short)(pk.y >> 16));
    float m = fmaxf(fmaxf(x0, x1), fmaxf(x2, x3));
    for (int off = 32; off > 0; off >>= 1) m = fmaxf(m, __shfl_xor(m, off));
    x0 = __expf(x0 - m); x1 = __expf(x1 - m); x2 = __expf(x2 - m); x3 = __expf(x3 - m);
    float s = x0 + x1 + x2 + x3;
    for (int off = 32; off > 0; off >>= 1) s += __shfl_xor(s, off);
    float inv = 1.f / s;
    unsigned int l0 = f2bf(x0 * inv), h0 = f2bf(x1 * inv);
    unsigned int l1 = f2bf(x2 * inv), h1 = f2bf(x3 * inv);
    pk.x = l0 | (h0 << 16); pk.y = l1 | (h1 << 16);
    *reinterpret_cast<uint2*>(rp + lane * 4) = pk;
}

// PV: attn[n, h*64+d] = sum_j P1[hz,n,j] * Bbuf[h,j,d]
__global__ __launch_bounds__(256) void pv1_k(
    const unsigned short* __restrict__ sc, const float* __restrict__ Bb,
    float* __restrict__ attn, int hb)
{
    __shared__ __align__(16) float As[16][68];
    __shared__ __align__(16) float Bs[16][68];
    const int hz = blockIdx.y;
    const int h = hb + hz;
    const int tid = threadIdx.x;
    const int tx = tid & 15, ty = tid >> 4;
    const size_t bm = (size_t)blockIdx.x * 64;   // n
    const int lr = tid >> 2, lc = (tid & 3) << 2;    // A load
    const int kr = tid >> 4, dc = (tid & 15) << 2;   // B load
    const unsigned short* Ap = sc + ((size_t)hz * NSEQ + bm + lr) * MLM;
    const float* Bp = Bb + (size_t)h * MLM * DH + dc;
    float acc[4][4] = {};
    for (int k0 = 0; k0 < MLM; k0 += 16) {
        ushort4 av = *reinterpret_cast<const ushort4*>(Ap + k0 + lc);
        float4 bv = *reinterpret_cast<const float4*>(Bp + (size_t)(k0 + kr) * DH);
        __syncthreads();
        As[lc + 0][lr] = bf2f(av.x); As[lc + 1][lr] = bf2f(av.y);
        As[lc + 2][lr] = bf2f(av.z); As[lc + 3][lr] = bf2f(av.w);
        Bs[kr][dc + 0] = bv.x; Bs[kr][dc + 1] = bv.y;
        Bs[kr][dc + 2] = bv.z; Bs[kr][dc + 3] = bv.w;
        __syncthreads();
#pragma unroll
        for (int kk = 0; kk < 16; ++kk) {
            float4 a = *reinterpret_cast<const float4*>(&As[kk][ty << 2]);
            float4 b = *reinterpret_cast<const float4*>(&Bs[kk][tx << 2]);
            acc[0][0] += a.x * b.x; acc[0][1] += a.x * b.y; acc[0][2] += a.x * b.z; acc[0][3] += a.x * b.w;
            acc[1][0] += a.y * b.x; acc[1][1] += a.y * b.y; acc[1][2] += a.y * b.z; acc[1][3] += a.y * b.w;
            acc[2][0] += a.z * b.x; acc[2][1] += a.z * b.y; acc[2][2] += a.z * b.z; acc[2][3] += a.z * b.w;
            acc[3][0] += a.w * b.x; acc[3][1] += a.w * b.y; acc[3][2] += a.w * b.z; acc[3][3] += a.w * b.w;
        }
    }
#pragma unroll
    for (int i = 0; i < 4; ++i)
#pragma unroll
        for (int j = 0; j < 4; ++j)
            attn[(bm + (ty << 2) + i) * (size_t)INNER + h * DH + (tx << 2) + j] = acc[i][j];
}

// ------------- depthwise conv residual add -------------
__global__ __launch_bounds__(256) void conv_res_k(
    const float* __restrict__ qkv, const float* __restrict__ kern, float* __restrict__ attnbuf)
{
    size_t idx = (size_t)blockIdx.x * 256 + threadIdx.x;
    int n = (int)(idx >> 9), c = (int)(idx & 511), h = c >> 6;
    float acc = 0.f;
#pragma unroll
    for (int t2 = 0; t2 < KCONV; ++t2) {
        int nn = n + t2 - KCONV / 2;
        if (nn >= 0 && nn < NSEQ)
            acc += qkv[(size_t)nn * QKV_LD + 1024 + c] * kern[h * KCONV + t2];
    }
    attnbuf[idx] += acc;
}

// ------------- sparse edge scores + segment sum -------------
__global__ __launch_bounds__(256) void edge_k(
    const float* __restrict__ qe, const float* __restrict__ ke,
    const int* __restrict__ rows, const int* __restrict__ cols,
    const float* __restrict__ vals, float* __restrict__ A_raw)
{
    int e = blockIdx.x * 4 + (threadIdx.x >> 6);
    int lane = threadIdx.x & 63;
    int r = rows[e], c = cols[e];
    const float* qr = qe + (size_t)r * WP;
    const float* kr = ke + (size_t)c * WP;
    float4 a = *reinterpret_cast<const float4*>(qr + lane * 4);
    float4 b = *reinterpret_cast<const float4*>(kr + lane * 4);
    float s = a.x * b.x + a.y * b.y + a.z * b.z + a.w * b.w;
    for (int off = 32; off > 0; off >>= 1) s += __shfl_down(s, off, 64);
    if (lane == 0) atomicAdd(&A_raw[r], s * vals[e] * 0.0625f);
}

// ------------- alpha = softmax(A_raw) -------------
__global__ __launch_bounds__(1024) void alpha_k(
    const float* __restrict__ A_raw, float* __restrict__ alpha)
{
    __shared__ float red[1024];
    int t = threadIdx.x;
    float m = -1e30f;
    for (int i = t; i < NSEQ; i += 1024) m = fmaxf(m, A_raw[i]);
    red[t] = m; __syncthreads();
    for (int off = 512; off > 0; off >>= 1) { if (t < off) red[t] = fmaxf(red[t], red[t + off]); __syncthreads(); }
    m = red[0]; __syncthreads();
    float s = 0.f;
    for (int i = t; i < NSEQ; i += 1024) s += __expf(A_raw[i] - m);
    red[t] = s; __syncthreads();
    for (int off = 512; off > 0; off >>= 1) { if (t < off) red[t] += red[t + off]; __syncthreads(); }
    float inv = 1.f / red[0];
    for (int i = t; i < NSEQ; i += 1024) alpha[i] = __expf(A_raw[i] - m) * inv;
}

// ------------- final gated blend -------------
__global__ __launch_bounds__(256) void final_k(
    const float* __restrict__ alpha, const float* __restrict__ value,
    const float* __restrict__ enc, float* __restrict__ xo)
{
    size_t idx = (size_t)blockIdx.x * 256 + threadIdx.x;
    int n = (int)(idx >> 9);
    float xl = alpha[n] * value[idx];
    float w = 1.f / (1.f + __expf(xl));
    float sq = w * w;
    xo[idx] = xl * 2.f * sq + 2.f * enc[idx] * (1.f - sq);
}

extern "C" void kernel_launch(void* const* d_in, const int* in_sizes, int n_in,
                              void* d_out, int out_size, void* d_ws, size_t ws_size,
                              hipStream_t stream)
{
    const float* dense      = (const float*)d_in[0];
    const int*   adj_rows   = (const int*)d_in[1];
    const int*   adj_cols   = (const int*)d_in[2];
    const float* adj_vals   = (const float*)d_in[3];
    const float* wq         = (const float*)d_in[4];
    const float* wk         = (const float*)d_in[5];
    const float* w_qkv      = (const float*)d_in[6];
    const float* w_out      = (const float*)d_in[7];
    const float* b_out      = (const float*)d_in[8];
    const float* res_kernel = (const float*)d_in[9];
    const float* wv_w       = (const float*)d_in[10];
    const float* wv_b       = (const float*)d_in[11];
    const int E = in_sizes[1];

    float* ws  = (float*)d_ws;
    float* out = (float*)d_out;
    float* A_raw = out + (size_t)NSEQ * DDIM;
    unsigned short* sc3 = (unsigned short*)(ws + OFF_ATTN);   // 8*256*8192 bf16
    unsigned short* sc1 = (unsigned short*)(ws + OFF_ENC);    // 4*8192*256 bf16

    hipMemsetAsync(A_raw, 0, NSEQ * sizeof(float), stream);
    hipMemsetAsync(ws + OFF_SCAL, 0, 2 * sizeof(unsigned int), stream);

    transpose_k<<<512, 256, 0, stream>>>(wq, ws + OFF_WQT, DDIM, WP);
    transpose_k<<<512, 256, 0, stream>>>(wk, ws + OFF_WKT, DDIM, WP);

    // qkv = dense @ w_qkv^T
    gemm_nt<<<dim3(NSEQ / 64, 1536 / 64), 256, 0, stream>>>(
        dense, DDIM, w_qkv, DDIM, ws + OFF_QKV, QKV_LD, DDIM, nullptr, nullptr);

    landmark_k<<<dim3(MLM, HEADS), 64, 0, stream>>>(ws + OFF_QKV, ws + OFF_QL, ws + OFF_KL);

    // ---- a3 pipeline ----
    qk3_k<<<dim3(4, 128, 8), 256, 0, stream>>>(ws + OFF_QL, ws + OFF_QKV, sc3);
    sm3_k<<<2048, 256, 0, stream>>>(sc3);
    pv3_k<<<dim3(4, 16, 8), 256, 0, stream>>>(sc3, ws + OFF_QKV, ws + OFF_Z1);
    red3_k<<<512, 256, 0, stream>>>(ws + OFF_Z1, ws + OFF_A3V);

    a2_k<<<dim3(MLM, HEADS), 256, 0, stream>>>(ws + OFF_QL, ws + OFF_KL, ws + OFF_A2);
    absmax_k<<<16, 256, 0, stream>>>(ws + OFF_A2, (unsigned int*)(ws + OFF_SCAL));
    zinit_k<<<(HEADS * MLM * MLM) / 256, 256, 0, stream>>>(
        ws + OFF_A2, (const unsigned int*)(ws + OFF_SCAL), ws + OFF_Z0);

    // pinv iterations
    for (int it = 0; it < 6; ++it) {
        float* zin  = ws + ((it & 1) ? OFF_Z1 : OFF_Z0);
        float* zout = ws + ((it & 1) ? OFF_Z0 : OFF_Z1);
        bmm_nn<<<dim3(64, HEADS), 256, 0, stream>>>(ws + OFF_A2, zin, ws + OFF_P,
            256, 256, 256, 65536, 65536, 65536, 0.f, 1.f);
        bmm_nn<<<dim3(64, HEADS), 256, 0, stream>>>(ws + OFF_P, ws + OFF_P, ws + OFF_T1,
            256, 256, 256, 65536, 65536, 65536, 7.f, -1.f);
        bmm_nn<<<dim3(64, HEADS), 256, 0, stream>>>(ws + OFF_P, ws + OFF_T1, ws + OFF_T2,
            256, 256, 256, 65536, 65536, 65536, 15.f, -1.f);
        bmm_nn<<<dim3(64, HEADS), 256, 0, stream>>>(zin, ws + OFF_T2, zout,
            256, 256, 256, 65536, 65536, 65536, 3.25f, -0.25f);
    }
    bmm_nn<<<dim3(16, HEADS), 256, 0, stream>>>(ws + OFF_Z0, ws + OFF_A3V, ws + OFF_BB,
        256, 64, 256, 65536, 16384, 16384, 0.f, 1.f);

    // ---- a1 pipeline (two 4-head halves) ----
    for (int hb = 0; hb < 8; hb += 4) {
        qk1_k<<<dim3(128, 4, 4), 256, 0, stream>>>(ws + OFF_QKV, ws + OFF_KL, sc1, hb);
        sm1_k<<<8192, 256, 0, stream>>>(sc1);
        pv1_k<<<dim3(128, 4), 256, 0, stream>>>(sc1, ws + OFF_BB, ws + OFF_ATTN, hb);
    }
    conv_res_k<<<(NSEQ * INNER) / 256, 256, 0, stream>>>(ws + OFF_QKV, res_kernel, ws + OFF_ATTN);

    // enc = attn @ w_out^T + b_out + dense
    gemm_nt<<<dim3(NSEQ / 64, DDIM / 64), 256, 0, stream>>>(
        ws + OFF_ATTN, INNER, w_out, INNER, ws + OFF_ENC, DDIM, INNER, b_out, dense);

    // q_edge / k_edge
    gemm_nt<<<dim3(NSEQ / 64, WP / 64), 256, 0, stream>>>(
        ws + OFF_ENC, DDIM, ws + OFF_WQT, DDIM, ws + OFF_QE, WP, DDIM, nullptr, nullptr);
    gemm_nt<<<dim3(NSEQ / 64, WP / 64), 256, 0, stream>>>(
        ws + OFF_ENC, DDIM, ws + OFF_WKT, DDIM, ws + OFF_KE, WP, DDIM, nullptr, nullptr);

    edge_k<<<E / 4, 256, 0, stream>>>(ws + OFF_QE, ws + OFF_KE, adj_rows, adj_cols, adj_vals, A_raw);
    alpha_k<<<1, 1024, 0, stream>>>(A_raw, ws + OFF_ALPHA);

    // value = dense @ wv_w^T + wv_b
    gemm_nt<<<dim3(NSEQ / 64, DDIM / 64), 256, 0, stream>>>(
        dense, DDIM, wv_w, DDIM, ws + OFF_VAL, DDIM, DDIM, wv_b, nullptr);

    final_k<<<(NSEQ * DDIM) / 256, 256, 0, stream>>>(
        ws + OFF_ALPHA, ws + OFF_VAL, ws + OFF_ENC, out);
}

// Round 3
// 926.565 us; speedup vs baseline: 3.2480x; 1.1795x over previous
//
#include <hip/hip_runtime.h>
#include <hip/hip_bf16.h>

// Problem constants (fixed by reference)
#define NSEQ 8192
#define DDIM 512
#define HEADS 8
#define DH 64
#define MLM 256
#define LSUB 32          // NSEQ / MLM
#define WP 256
#define KCONV 33
#define INNER 512        // HEADS*DH
#define QKV_LD 1536

// ---------------- workspace layout (in floats) ----------------
static const size_t OFF_QKV   = 0;                 // 8192*1536
static const size_t OFF_ATTN  = 12582912;          // 8192*512
static const size_t OFF_ENC   = 16777216;          // 8192*512
static const size_t OFF_QL    = 21233664;          // 8*256*64
static const size_t OFF_KL    = 21364736;
static const size_t OFF_A2    = 21495808;          // 8*256*256
static const size_t OFF_Z0    = 22020096;
static const size_t OFF_Z1    = 22544384;          // also PV3 partials [16][8][256][64]
static const size_t OFF_P     = 23068672;
static const size_t OFF_T1    = 23592960;
static const size_t OFF_T2    = 24117248;
static const size_t OFF_A3V   = 24641536;          // 8*256*64
static const size_t OFF_BB    = 24772608;          // 8*256*64
static const size_t OFF_SCAL  = 24903680;          // 2 uints
static const size_t OFF_ALPHA = 24903696;          // 8192
// reuse of qkv region (only valid after its phase ends):
static const size_t OFF_QE    = 0;                 // 8192*256 fp32
static const size_t OFF_KE    = 2097152;           // 8192*256 fp32
static const size_t OFF_VAL   = 4194304;           // 8192*512 fp32
static const size_t OFF_ATTNBF= 8388608;           // 8192*512 bf16 (2.1M float slots)
static const size_t OFF_ENCBF = 10485760;          // 8192*512 bf16
// bf16 overlays: w_qkv_bf + (late) w_out/wqt/wkt/wv in ATTN region;
// dense_bf in Z0..T1 region (dead at start and at end);
// sc3 (a3 scores) spans ATTN+ENC; sc1 (a1 scores) in ENC.

__device__ __forceinline__ float bf2f(unsigned short u) {
    return __uint_as_float(((unsigned int)u) << 16);
}
__device__ __forceinline__ unsigned short f2bf(float x) {
    unsigned int u = __float_as_uint(x);
    u += 0x7FFFu + ((u >> 16) & 1u);   // RNE
    return (unsigned short)(u >> 16);
}

typedef __attribute__((ext_vector_type(8))) short bf16x8;
typedef __attribute__((ext_vector_type(4))) float f32x4;

// ---------------- fp32 -> bf16 conversion (8 elems/thread) ----------------
__global__ __launch_bounds__(256) void cvt_bf16_k(
    const float* __restrict__ in, unsigned short* __restrict__ out)
{
    size_t i = ((size_t)blockIdx.x * 256 + threadIdx.x) * 8;
    float4 a = *reinterpret_cast<const float4*>(in + i);
    float4 b = *reinterpret_cast<const float4*>(in + i + 4);
    uint4 p;
    p.x = (unsigned int)f2bf(a.x) | ((unsigned int)f2bf(a.y) << 16);
    p.y = (unsigned int)f2bf(a.z) | ((unsigned int)f2bf(a.w) << 16);
    p.z = (unsigned int)f2bf(b.x) | ((unsigned int)f2bf(b.y) << 16);
    p.w = (unsigned int)f2bf(b.z) | ((unsigned int)f2bf(b.w) << 16);
    *reinterpret_cast<uint4*>(out + i) = p;
}

// ---------------- transpose + convert: out[c][r] = bf16(in[r][c]) ----------
// in: [R x C] fp32, out: [C x R] bf16
__global__ __launch_bounds__(256) void tcvt_bf16_k(
    const float* __restrict__ in, unsigned short* __restrict__ out, int R, int C)
{
    int idx = blockIdx.x * 256 + threadIdx.x;   // over C*R outputs
    if (idx < R * C) {
        int oc = idx / R;   // wait: out is [C][R]; linear idx = c*R + r
        int orow = idx % R;
        out[idx] = f2bf(in[(size_t)orow * C + oc]);
    }
}

// ---------------- bf16 MFMA NT GEMM: C[m,n] = sum_k A[m,k]*B[n,k] ----------
// A: [M x K] bf16 row-major; B: [N x K] bf16 row-major; C fp32 [M x ldc]
// tile 128x128, BK=64, 256 threads = 4 waves (2x2), each wave 64x64
__global__ __launch_bounds__(256) void gemm_bf16_nt(
    const unsigned short* __restrict__ A,
    const unsigned short* __restrict__ B,
    float* __restrict__ C, int ldc, int K,
    const float* __restrict__ bias,
    const float* __restrict__ addsrc)
{
    __shared__ unsigned short As[128 * 72];   // row stride 72 bf16 = 144B
    __shared__ unsigned short Bs[128 * 72];
    const int tid = threadIdx.x;
    const int wave = tid >> 6, lane = tid & 63;
    const int wm = wave >> 1, wn = wave & 1;
    const size_t bm = (size_t)blockIdx.x * 128;
    const size_t bn = (size_t)blockIdx.y * 128;
    const int l15 = lane & 15, l4 = lane >> 4;
    f32x4 acc[4][4] = {};
    for (int k0 = 0; k0 < K; k0 += 64) {
        uint4 va[4], vb[4];
#pragma unroll
        for (int j = 0; j < 4; ++j) {
            int id = tid + j * 256;
            int row = id >> 3, c8 = id & 7;
            va[j] = *reinterpret_cast<const uint4*>(A + (bm + row) * (size_t)K + k0 + c8 * 8);
            vb[j] = *reinterpret_cast<const uint4*>(B + (bn + row) * (size_t)K + k0 + c8 * 8);
        }
        __syncthreads();
#pragma unroll
        for (int j = 0; j < 4; ++j) {
            int id = tid + j * 256;
            int row = id >> 3, c8 = id & 7;
            *reinterpret_cast<uint4*>(&As[row * 72 + c8 * 8]) = va[j];
            *reinterpret_cast<uint4*>(&Bs[row * 72 + c8 * 8]) = vb[j];
        }
        __syncthreads();
#pragma unroll
        for (int c = 0; c < 2; ++c) {
            bf16x8 af[4], bfr[4];
#pragma unroll
            for (int i = 0; i < 4; ++i) {
                int arow = wm * 64 + i * 16 + l15;
                af[i] = *reinterpret_cast<const bf16x8*>(&As[arow * 72 + c * 32 + l4 * 8]);
                int brow = wn * 64 + i * 16 + l15;
                bfr[i] = *reinterpret_cast<const bf16x8*>(&Bs[brow * 72 + c * 32 + l4 * 8]);
            }
#pragma unroll
            for (int i = 0; i < 4; ++i)
#pragma unroll
                for (int j = 0; j < 4; ++j)
                    acc[i][j] = __builtin_amdgcn_mfma_f32_16x16x32_bf16(
                        af[i], bfr[j], acc[i][j], 0, 0, 0);
        }
    }
#pragma unroll
    for (int i = 0; i < 4; ++i) {
#pragma unroll
        for (int j = 0; j < 4; ++j) {
#pragma unroll
            for (int r = 0; r < 4; ++r) {
                size_t row = bm + wm * 64 + i * 16 + l4 * 4 + r;
                size_t col = bn + wn * 64 + j * 16 + l15;
                float v = acc[i][j][r];
                if (bias)   v += bias[col];
                if (addsrc) v += addsrc[row * (size_t)ldc + col];
                C[row * (size_t)ldc + col] = v;
            }
        }
    }
}

// ------------- batched NN GEMM: C = beta*(A@B) + alpha*A -------------
__global__ __launch_bounds__(256) void bmm_nn(
    const float* __restrict__ A, const float* __restrict__ B, float* __restrict__ C,
    int M, int N, int K, int sA, int sB, int sC, float alpha, float beta)
{
    __shared__ float As[32][33];
    __shared__ float Bs[32][33];
    const int b = blockIdx.y;
    const int ntiles = N >> 5;
    const int tm = blockIdx.x / ntiles, tn = blockIdx.x % ntiles;
    const float* Ab = A + (size_t)b * sA;
    const float* Bb = B + (size_t)b * sB;
    float* Cb = C + (size_t)b * sC;
    const int tid = threadIdx.x;
    const int tx = tid & 15, ty = tid >> 4;
    const int lr = tid >> 3;
    const int lc = (tid & 7) << 2;
    float acc[2][2] = {};
    for (int k0 = 0; k0 < K; k0 += 32) {
        float4 av = *reinterpret_cast<const float4*>(Ab + (size_t)(tm * 32 + lr) * K + k0 + lc);
        float4 bv = *reinterpret_cast<const float4*>(Bb + (size_t)(k0 + lr) * N + tn * 32 + lc);
        __syncthreads();
        As[lr][lc + 0] = av.x; As[lr][lc + 1] = av.y; As[lr][lc + 2] = av.z; As[lr][lc + 3] = av.w;
        Bs[lr][lc + 0] = bv.x; Bs[lr][lc + 1] = bv.y; Bs[lr][lc + 2] = bv.z; Bs[lr][lc + 3] = bv.w;
        __syncthreads();
#pragma unroll
        for (int kk = 0; kk < 32; ++kk) {
            float a0 = As[ty * 2 + 0][kk], a1 = As[ty * 2 + 1][kk];
            float b0 = Bs[kk][tx * 2 + 0], b1 = Bs[kk][tx * 2 + 1];
            acc[0][0] += a0 * b0; acc[0][1] += a0 * b1;
            acc[1][0] += a1 * b0; acc[1][1] += a1 * b1;
        }
    }
#pragma unroll
    for (int i = 0; i < 2; ++i)
#pragma unroll
        for (int j = 0; j < 2; ++j) {
            int row = tm * 32 + ty * 2 + i, col = tn * 32 + tx * 2 + j;
            float v = beta * acc[i][j];
            if (alpha != 0.f) v += alpha * Ab[(size_t)row * K + col];
            Cb[(size_t)row * N + col] = v;
        }
}

// ------------- landmark means (q scaled by 1/8) -------------
__global__ __launch_bounds__(64) void landmark_k(
    const float* __restrict__ qkv, float* __restrict__ q_l, float* __restrict__ k_l)
{
    int m = blockIdx.x, h = blockIdx.y, d = threadIdx.x;
    float sq = 0.f, sk = 0.f;
    for (int i = 0; i < LSUB; ++i) {
        size_t n = (size_t)m * LSUB + i;
        sq += qkv[n * QKV_LD + h * DH + d];
        sk += qkv[n * QKV_LD + 512 + h * DH + d];
    }
    q_l[((size_t)h * MLM + m) * DH + d] = sq * (0.125f / (float)LSUB);
    k_l[((size_t)h * MLM + m) * DH + d] = sk * (1.f / (float)LSUB);
}

// ------------- a2 = softmax(q_l @ k_l^T) rows -------------
__global__ __launch_bounds__(256) void a2_k(
    const float* __restrict__ q_l, const float* __restrict__ k_l, float* __restrict__ a2)
{
    int i = blockIdx.x, h = blockIdx.y, t = threadIdx.x;
    __shared__ float ql[64];
    __shared__ float red[256];
    if (t < 64) ql[t] = q_l[((size_t)h * MLM + i) * DH + t];
    __syncthreads();
    const float* kr = k_l + ((size_t)h * MLM + t) * DH;
    float s = 0.f;
#pragma unroll
    for (int d = 0; d < 64; d += 4) {
        float4 kv = *reinterpret_cast<const float4*>(kr + d);
        s += kv.x * ql[d] + kv.y * ql[d + 1] + kv.z * ql[d + 2] + kv.w * ql[d + 3];
    }
    red[t] = s; __syncthreads();
    for (int off = 128; off > 0; off >>= 1) { if (t < off) red[t] = fmaxf(red[t], red[t + off]); __syncthreads(); }
    float m = red[0]; __syncthreads();
    float e = __expf(s - m);
    red[t] = e; __syncthreads();
    for (int off = 128; off > 0; off >>= 1) { if (t < off) red[t] += red[t + off]; __syncthreads(); }
    a2[(((size_t)h * MLM + i) * MLM) + t] = e / red[0];
}

// ------------- global max of row/col abs-sums of a2 -------------
__global__ __launch_bounds__(256) void absmax_k(
    const float* __restrict__ a2, unsigned int* __restrict__ scal)
{
    int b = blockIdx.x, t = threadIdx.x;
    __shared__ float red[256];
    float sum = 0.f;
    if (b < 8) {
        const float* r = a2 + ((size_t)b * MLM + t) * MLM;
        for (int j = 0; j < MLM; ++j) sum += fabsf(r[j]);
    } else {
        int h = b - 8;
        for (int i = 0; i < MLM; ++i) sum += fabsf(a2[((size_t)h * MLM + i) * MLM + t]);
    }
    red[t] = sum; __syncthreads();
    for (int off = 128; off > 0; off >>= 1) { if (t < off) red[t] = fmaxf(red[t], red[t + off]); __syncthreads(); }
    if (t == 0) atomicMax(scal + (b < 8 ? 0 : 1), __float_as_uint(red[0]));
}

// ------------- z0 = a2^T / (rmax*cmax) -------------
__global__ __launch_bounds__(256) void zinit_k(
    const float* __restrict__ a2, const unsigned int* __restrict__ scal, float* __restrict__ z)
{
    int idx = blockIdx.x * 256 + threadIdx.x;
    float rmax = __uint_as_float(scal[0]);
    float cmax = __uint_as_float(scal[1]);
    float inv = 1.f / (rmax * cmax);
    int h = idx >> 16, rem = idx & 65535, i = rem >> 8, j = rem & 255;
    z[idx] = a2[((size_t)h << 16) + (j << 8) + i] * inv;
}

// ======================= a3 pipeline (GEMM-style) =======================
__global__ __launch_bounds__(256) void qk3_k(
    const float* __restrict__ q_l, const float* __restrict__ qkv,
    unsigned short* __restrict__ sc)
{
    __shared__ __align__(16) float As[16][68];
    __shared__ __align__(16) float Bs[16][68];
    const int h = blockIdx.z;
    const int tid = threadIdx.x;
    const int tx = tid & 15, ty = tid >> 4;
    const size_t bm = (size_t)blockIdx.x * 64;   // i
    const size_t bn = (size_t)blockIdx.y * 64;   // j
    const int lr = tid >> 2, lc = (tid & 3) << 2;
    const float* Ap = q_l + ((size_t)h * MLM + bm + lr) * DH + lc;
    const float* Bp = qkv + 512 + h * DH + (bn + lr) * (size_t)QKV_LD + lc;
    float acc[4][4] = {};
    for (int k0 = 0; k0 < DH; k0 += 16) {
        float4 av = *reinterpret_cast<const float4*>(Ap + k0);
        float4 bv = *reinterpret_cast<const float4*>(Bp + k0);
        __syncthreads();
        As[lc + 0][lr] = av.x; As[lc + 1][lr] = av.y;
        As[lc + 2][lr] = av.z; As[lc + 3][lr] = av.w;
        Bs[lc + 0][lr] = bv.x; Bs[lc + 1][lr] = bv.y;
        Bs[lc + 2][lr] = bv.z; Bs[lc + 3][lr] = bv.w;
        __syncthreads();
#pragma unroll
        for (int kk = 0; kk < 16; ++kk) {
            float4 a = *reinterpret_cast<const float4*>(&As[kk][ty << 2]);
            float4 b = *reinterpret_cast<const float4*>(&Bs[kk][tx << 2]);
            acc[0][0] += a.x * b.x; acc[0][1] += a.x * b.y; acc[0][2] += a.x * b.z; acc[0][3] += a.x * b.w;
            acc[1][0] += a.y * b.x; acc[1][1] += a.y * b.y; acc[1][2] += a.y * b.z; acc[1][3] += a.y * b.w;
            acc[2][0] += a.z * b.x; acc[2][1] += a.z * b.y; acc[2][2] += a.z * b.z; acc[2][3] += a.z * b.w;
            acc[3][0] += a.w * b.x; acc[3][1] += a.w * b.y; acc[3][2] += a.w * b.z; acc[3][3] += a.w * b.w;
        }
    }
    unsigned short* C = sc + (size_t)h * MLM * NSEQ;
#pragma unroll
    for (int i = 0; i < 4; ++i)
#pragma unroll
        for (int j = 0; j < 4; ++j)
            C[(bm + (ty << 2) + i) * NSEQ + bn + (tx << 2) + j] = f2bf(acc[i][j]);
}

// row softmax over 8192 bf16, in place; one block per row
__global__ __launch_bounds__(256) void sm3_k(unsigned short* __restrict__ sc)
{
    __shared__ float red[256];
    const int t = threadIdx.x;
    unsigned short* row = sc + (size_t)blockIdx.x * NSEQ;
    float v[32];
    float lmax = -1e30f;
#pragma unroll
    for (int u = 0; u < 4; ++u) {
        uint4 pk = *reinterpret_cast<const uint4*>(row + t * 32 + u * 8);
        unsigned int w[4] = {pk.x, pk.y, pk.z, pk.w};
#pragma unroll
        for (int q = 0; q < 4; ++q) {
            float lo = bf2f((unsigned short)(w[q] & 0xFFFF));
            float hi = bf2f((unsigned short)(w[q] >> 16));
            v[u * 8 + q * 2 + 0] = lo; v[u * 8 + q * 2 + 1] = hi;
            lmax = fmaxf(lmax, fmaxf(lo, hi));
        }
    }
    red[t] = lmax; __syncthreads();
    for (int off = 128; off > 0; off >>= 1) { if (t < off) red[t] = fmaxf(red[t], red[t + off]); __syncthreads(); }
    float m = red[0]; __syncthreads();
    float s = 0.f;
#pragma unroll
    for (int u = 0; u < 32; ++u) { v[u] = __expf(v[u] - m); s += v[u]; }
    red[t] = s; __syncthreads();
    for (int off = 128; off > 0; off >>= 1) { if (t < off) red[t] += red[t + off]; __syncthreads(); }
    float inv = 1.f / red[0];
#pragma unroll
    for (int u = 0; u < 4; ++u) {
        uint4 pk;
        unsigned int w[4];
#pragma unroll
        for (int q = 0; q < 4; ++q) {
            unsigned int lo = f2bf(v[u * 8 + q * 2 + 0] * inv);
            unsigned int hi = f2bf(v[u * 8 + q * 2 + 1] * inv);
            w[q] = lo | (hi << 16);
        }
        pk.x = w[0]; pk.y = w[1]; pk.z = w[2]; pk.w = w[3];
        *reinterpret_cast<uint4*>(row + t * 32 + u * 8) = pk;
    }
}

// PV split-K: part[kc][h][i][d] = sum_{j in chunk kc} P[h,i,j] * v[h,j,d]
__global__ __launch_bounds__(256) void pv3_k(
    const unsigned short* __restrict__ sc, const float* __restrict__ qkv,
    float* __restrict__ part)
{
    __shared__ __align__(16) float As[16][68];
    __shared__ __align__(16) float Bs[16][68];
    const int it = blockIdx.x;
    const int kc = blockIdx.y;
    const int h  = blockIdx.z;
    const int tid = threadIdx.x;
    const int tx = tid & 15, ty = tid >> 4;
    const int lr = tid >> 2, lc = (tid & 3) << 2;
    const int kr = tid >> 4, dc = (tid & 15) << 2;
    const unsigned short* Ap = sc + ((size_t)h * MLM + it * 64 + lr) * NSEQ + kc * 512;
    const float* Bp = qkv + 1024 + h * DH + dc;
    float acc[4][4] = {};
    for (int k0 = 0; k0 < 512; k0 += 16) {
        ushort4 av = *reinterpret_cast<const ushort4*>(Ap + k0 + lc);
        float4 bv = *reinterpret_cast<const float4*>(Bp + (size_t)(kc * 512 + k0 + kr) * QKV_LD);
        __syncthreads();
        As[lc + 0][lr] = bf2f(av.x); As[lc + 1][lr] = bf2f(av.y);
        As[lc + 2][lr] = bf2f(av.z); As[lc + 3][lr] = bf2f(av.w);
        Bs[kr][dc + 0] = bv.x; Bs[kr][dc + 1] = bv.y;
        Bs[kr][dc + 2] = bv.z; Bs[kr][dc + 3] = bv.w;
        __syncthreads();
#pragma unroll
        for (int kk = 0; kk < 16; ++kk) {
            float4 a = *reinterpret_cast<const float4*>(&As[kk][ty << 2]);
            float4 b = *reinterpret_cast<const float4*>(&Bs[kk][tx << 2]);
            acc[0][0] += a.x * b.x; acc[0][1] += a.x * b.y; acc[0][2] += a.x * b.z; acc[0][3] += a.x * b.w;
            acc[1][0] += a.y * b.x; acc[1][1] += a.y * b.y; acc[1][2] += a.y * b.z; acc[1][3] += a.y * b.w;
            acc[2][0] += a.z * b.x; acc[2][1] += a.z * b.y; acc[2][2] += a.z * b.z; acc[2][3] += a.z * b.w;
            acc[3][0] += a.w * b.x; acc[3][1] += a.w * b.y; acc[3][2] += a.w * b.z; acc[3][3] += a.w * b.w;
        }
    }
    float* Cp = part + ((size_t)(kc * 8 + h) * MLM + it * 64) * DH;
#pragma unroll
    for (int i = 0; i < 4; ++i)
#pragma unroll
        for (int j = 0; j < 4; ++j)
            Cp[((ty << 2) + i) * DH + (tx << 2) + j] = acc[i][j];
}

__global__ __launch_bounds__(256) void red3_k(
    const float* __restrict__ part, float* __restrict__ a3v)
{
    int o = blockIdx.x * 256 + threadIdx.x;
    float s = 0.f;
#pragma unroll
    for (int kc = 0; kc < 16; ++kc) s += part[(size_t)kc * 131072 + o];
    a3v[o] = s;
}

// ======================= a1 pipeline (GEMM-style, 4 heads/half) ==========
__global__ __launch_bounds__(256) void qk1_k(
    const float* __restrict__ qkv, const float* __restrict__ k_l,
    unsigned short* __restrict__ sc, int hb)
{
    __shared__ __align__(16) float As[16][68];
    __shared__ __align__(16) float Bs[16][68];
    const int hz = blockIdx.z;
    const int h = hb + hz;
    const int tid = threadIdx.x;
    const int tx = tid & 15, ty = tid >> 4;
    const size_t bm = (size_t)blockIdx.x * 64;
    const size_t bn = (size_t)blockIdx.y * 64;
    const int lr = tid >> 2, lc = (tid & 3) << 2;
    const float* Ap = qkv + (bm + lr) * (size_t)QKV_LD + h * DH + lc;
    const float* Bp = k_l + ((size_t)h * MLM + bn + lr) * DH + lc;
    float acc[4][4] = {};
    for (int k0 = 0; k0 < DH; k0 += 16) {
        float4 av = *reinterpret_cast<const float4*>(Ap + k0);
        float4 bv = *reinterpret_cast<const float4*>(Bp + k0);
        av.x *= 0.125f; av.y *= 0.125f; av.z *= 0.125f; av.w *= 0.125f;
        __syncthreads();
        As[lc + 0][lr] = av.x; As[lc + 1][lr] = av.y;
        As[lc + 2][lr] = av.z; As[lc + 3][lr] = av.w;
        Bs[lc + 0][lr] = bv.x; Bs[lc + 1][lr] = bv.y;
        Bs[lc + 2][lr] = bv.z; Bs[lc + 3][lr] = bv.w;
        __syncthreads();
#pragma unroll
        for (int kk = 0; kk < 16; ++kk) {
            float4 a = *reinterpret_cast<const float4*>(&As[kk][ty << 2]);
            float4 b = *reinterpret_cast<const float4*>(&Bs[kk][tx << 2]);
            acc[0][0] += a.x * b.x; acc[0][1] += a.x * b.y; acc[0][2] += a.x * b.z; acc[0][3] += a.x * b.w;
            acc[1][0] += a.y * b.x; acc[1][1] += a.y * b.y; acc[1][2] += a.y * b.z; acc[1][3] += a.y * b.w;
            acc[2][0] += a.z * b.x; acc[2][1] += a.z * b.y; acc[2][2] += a.z * b.z; acc[2][3] += a.z * b.w;
            acc[3][0] += a.w * b.x; acc[3][1] += a.w * b.y; acc[3][2] += a.w * b.z; acc[3][3] += a.w * b.w;
        }
    }
    unsigned short* C = sc + (size_t)hz * NSEQ * MLM;
#pragma unroll
    for (int i = 0; i < 4; ++i)
#pragma unroll
        for (int j = 0; j < 4; ++j)
            C[(bm + (ty << 2) + i) * MLM + bn + (tx << 2) + j] = f2bf(acc[i][j]);
}

// softmax over rows of length 256, one wave per row (4 rows/block)
__global__ __launch_bounds__(256) void sm1_k(unsigned short* __restrict__ sc)
{
    const int row = blockIdx.x * 4 + (threadIdx.x >> 6);
    const int lane = threadIdx.x & 63;
    unsigned short* rp = sc + (size_t)row * MLM;
    uint2 pk = *reinterpret_cast<const uint2*>(rp + lane * 4);
    float x0 = bf2f((unsigned short)(pk.x & 0xFFFF));
    float x1 = bf2f((unsigned short)(pk.x >> 16));
    float x2 = bf2f((unsigned short)(pk.y & 0xFFFF));
    float x3 = bf2f((unsigned short)(pk.y >> 16));
    float m = fmaxf(fmaxf(x0, x1), fmaxf(x2, x3));
    for (int off = 32; off > 0; off >>= 1) m = fmaxf(m, __shfl_xor(m, off));
    x0 = __expf(x0 - m); x1 = __expf(x1 - m); x2 = __expf(x2 - m); x3 = __expf(x3 - m);
    float s = x0 + x1 + x2 + x3;
    for (int off = 32; off > 0; off >>= 1) s += __shfl_xor(s, off);
    float inv = 1.f / s;
    unsigned int l0 = f2bf(x0 * inv), h0 = f2bf(x1 * inv);
    unsigned int l1 = f2bf(x2 * inv), h1 = f2bf(x3 * inv);
    pk.x = l0 | (h0 << 16); pk.y = l1 | (h1 << 16);
    *reinterpret_cast<uint2*>(rp + lane * 4) = pk;
}

// PV: attn[n, h*64+d] = sum_j P1[hz,n,j] * Bbuf[h,j,d]
__global__ __launch_bounds__(256) void pv1_k(
    const unsigned short* __restrict__ sc, const float* __restrict__ Bb,
    float* __restrict__ attn, int hb)
{
    __shared__ __align__(16) float As[16][68];
    __shared__ __align__(16) float Bs[16][68];
    const int hz = blockIdx.y;
    const int h = hb + hz;
    const int tid = threadIdx.x;
    const int tx = tid & 15, ty = tid >> 4;
    const size_t bm = (size_t)blockIdx.x * 64;
    const int lr = tid >> 2, lc = (tid & 3) << 2;
    const int kr = tid >> 4, dc = (tid & 15) << 2;
    const unsigned short* Ap = sc + ((size_t)hz * NSEQ + bm + lr) * MLM;
    const float* Bp = Bb + (size_t)h * MLM * DH + dc;
    float acc[4][4] = {};
    for (int k0 = 0; k0 < MLM; k0 += 16) {
        ushort4 av = *reinterpret_cast<const ushort4*>(Ap + k0 + lc);
        float4 bv = *reinterpret_cast<const float4*>(Bp + (size_t)(k0 + kr) * DH);
        __syncthreads();
        As[lc + 0][lr] = bf2f(av.x); As[lc + 1][lr] = bf2f(av.y);
        As[lc + 2][lr] = bf2f(av.z); As[lc + 3][lr] = bf2f(av.w);
        Bs[kr][dc + 0] = bv.x; Bs[kr][dc + 1] = bv.y;
        Bs[kr][dc + 2] = bv.z; Bs[kr][dc + 3] = bv.w;
        __syncthreads();
#pragma unroll
        for (int kk = 0; kk < 16; ++kk) {
            float4 a = *reinterpret_cast<const float4*>(&As[kk][ty << 2]);
            float4 b = *reinterpret_cast<const float4*>(&Bs[kk][tx << 2]);
            acc[0][0] += a.x * b.x; acc[0][1] += a.x * b.y; acc[0][2] += a.x * b.z; acc[0][3] += a.x * b.w;
            acc[1][0] += a.y * b.x; acc[1][1] += a.y * b.y; acc[1][2] += a.y * b.z; acc[1][3] += a.y * b.w;
            acc[2][0] += a.z * b.x; acc[2][1] += a.z * b.y; acc[2][2] += a.z * b.z; acc[2][3] += a.z * b.w;
            acc[3][0] += a.w * b.x; acc[3][1] += a.w * b.y; acc[3][2] += a.w * b.z; acc[3][3] += a.w * b.w;
        }
    }
#pragma unroll
    for (int i = 0; i < 4; ++i)
#pragma unroll
        for (int j = 0; j < 4; ++j)
            attn[(bm + (ty << 2) + i) * (size_t)INNER + h * DH + (tx << 2) + j] = acc[i][j];
}

// ------------- depthwise conv residual add -------------
__global__ __launch_bounds__(256) void conv_res_k(
    const float* __restrict__ qkv, const float* __restrict__ kern, float* __restrict__ attnbuf)
{
    size_t idx = (size_t)blockIdx.x * 256 + threadIdx.x;
    int n = (int)(idx >> 9), c = (int)(idx & 511), h = c >> 6;
    float acc = 0.f;
#pragma unroll
    for (int t2 = 0; t2 < KCONV; ++t2) {
        int nn = n + t2 - KCONV / 2;
        if (nn >= 0 && nn < NSEQ)
            acc += qkv[(size_t)nn * QKV_LD + 1024 + c] * kern[h * KCONV + t2];
    }
    attnbuf[idx] += acc;
}

// ------------- sparse edge scores + segment sum -------------
__global__ __launch_bounds__(256) void edge_k(
    const float* __restrict__ qe, const float* __restrict__ ke,
    const int* __restrict__ rows, const int* __restrict__ cols,
    const float* __restrict__ vals, float* __restrict__ A_raw)
{
    int e = blockIdx.x * 4 + (threadIdx.x >> 6);
    int lane = threadIdx.x & 63;
    int r = rows[e], c = cols[e];
    const float* qr = qe + (size_t)r * WP;
    const float* kr = ke + (size_t)c * WP;
    float4 a = *reinterpret_cast<const float4*>(qr + lane * 4);
    float4 b = *reinterpret_cast<const float4*>(kr + lane * 4);
    float s = a.x * b.x + a.y * b.y + a.z * b.z + a.w * b.w;
    for (int off = 32; off > 0; off >>= 1) s += __shfl_down(s, off, 64);
    if (lane == 0) atomicAdd(&A_raw[r], s * vals[e] * 0.0625f);
}

// ------------- alpha = softmax(A_raw) -------------
__global__ __launch_bounds__(1024) void alpha_k(
    const float* __restrict__ A_raw, float* __restrict__ alpha)
{
    __shared__ float red[1024];
    int t = threadIdx.x;
    float m = -1e30f;
    for (int i = t; i < NSEQ; i += 1024) m = fmaxf(m, A_raw[i]);
    red[t] = m; __syncthreads();
    for (int off = 512; off > 0; off >>= 1) { if (t < off) red[t] = fmaxf(red[t], red[t + off]); __syncthreads(); }
    m = red[0]; __syncthreads();
    float s = 0.f;
    for (int i = t; i < NSEQ; i += 1024) s += __expf(A_raw[i] - m);
    red[t] = s; __syncthreads();
    for (int off = 512; off > 0; off >>= 1) { if (t < off) red[t] += red[t + off]; __syncthreads(); }
    float inv = 1.f / red[0];
    for (int i = t; i < NSEQ; i += 1024) alpha[i] = __expf(A_raw[i] - m) * inv;
}

// ------------- final gated blend -------------
__global__ __launch_bounds__(256) void final_k(
    const float* __restrict__ alpha, const float* __restrict__ value,
    const float* __restrict__ enc, float* __restrict__ xo)
{
    size_t idx = (size_t)blockIdx.x * 256 + threadIdx.x;
    int n = (int)(idx >> 9);
    float xl = alpha[n] * value[idx];
    float w = 1.f / (1.f + __expf(xl));
    float sq = w * w;
    xo[idx] = xl * 2.f * sq + 2.f * enc[idx] * (1.f - sq);
}

extern "C" void kernel_launch(void* const* d_in, const int* in_sizes, int n_in,
                              void* d_out, int out_size, void* d_ws, size_t ws_size,
                              hipStream_t stream)
{
    const float* dense      = (const float*)d_in[0];
    const int*   adj_rows   = (const int*)d_in[1];
    const int*   adj_cols   = (const int*)d_in[2];
    const float* adj_vals   = (const float*)d_in[3];
    const float* wq         = (const float*)d_in[4];
    const float* wk         = (const float*)d_in[5];
    const float* w_qkv      = (const float*)d_in[6];
    const float* w_out      = (const float*)d_in[7];
    const float* b_out      = (const float*)d_in[8];
    const float* res_kernel = (const float*)d_in[9];
    const float* wv_w       = (const float*)d_in[10];
    const float* wv_b       = (const float*)d_in[11];
    const int E = in_sizes[1];

    float* ws  = (float*)d_ws;
    float* out = (float*)d_out;
    float* A_raw = out + (size_t)NSEQ * DDIM;
    unsigned short* sc3 = (unsigned short*)(ws + OFF_ATTN);   // 8*256*8192 bf16
    unsigned short* sc1 = (unsigned short*)(ws + OFF_ENC);    // 4*8192*256 bf16

    // bf16 overlays
    unsigned short* wqkv_bf  = (unsigned short*)(ws + OFF_ATTN);   // dead before sc3
    unsigned short* dense_bf = (unsigned short*)(ws + OFF_Z0);     // dead before zinit / after pinv
    unsigned short* attn_bf  = (unsigned short*)(ws + OFF_ATTNBF);
    unsigned short* enc_bf   = (unsigned short*)(ws + OFF_ENCBF);
    unsigned short* wout_bf  = (unsigned short*)(ws + OFF_ATTN);             // after attn consumed
    unsigned short* wqt_bf   = (unsigned short*)(ws + OFF_ATTN + 131072);
    unsigned short* wkt_bf   = (unsigned short*)(ws + OFF_ATTN + 196608);
    unsigned short* wv_bf    = (unsigned short*)(ws + OFF_ATTN + 262144);

    hipMemsetAsync(A_raw, 0, NSEQ * sizeof(float), stream);
    hipMemsetAsync(ws + OFF_SCAL, 0, 2 * sizeof(unsigned int), stream);

    // ---- convert inputs for qkv GEMM ----
    cvt_bf16_k<<<(NSEQ * DDIM) / 2048, 256, 0, stream>>>(dense, dense_bf);
    cvt_bf16_k<<<(1536 * DDIM) / 2048, 256, 0, stream>>>(w_qkv, wqkv_bf);

    // qkv = dense @ w_qkv^T   [8192 x 1536], K=512
    gemm_bf16_nt<<<dim3(NSEQ / 128, 1536 / 128), 256, 0, stream>>>(
        dense_bf, wqkv_bf, ws + OFF_QKV, QKV_LD, DDIM, nullptr, nullptr);

    landmark_k<<<dim3(MLM, HEADS), 64, 0, stream>>>(ws + OFF_QKV, ws + OFF_QL, ws + OFF_KL);

    // ---- a3 pipeline ----
    qk3_k<<<dim3(4, 128, 8), 256, 0, stream>>>(ws + OFF_QL, ws + OFF_QKV, sc3);
    sm3_k<<<2048, 256, 0, stream>>>(sc3);
    pv3_k<<<dim3(4, 16, 8), 256, 0, stream>>>(sc3, ws + OFF_QKV, ws + OFF_Z1);
    red3_k<<<512, 256, 0, stream>>>(ws + OFF_Z1, ws + OFF_A3V);

    a2_k<<<dim3(MLM, HEADS), 256, 0, stream>>>(ws + OFF_QL, ws + OFF_KL, ws + OFF_A2);
    absmax_k<<<16, 256, 0, stream>>>(ws + OFF_A2, (unsigned int*)(ws + OFF_SCAL));
    zinit_k<<<(HEADS * MLM * MLM) / 256, 256, 0, stream>>>(
        ws + OFF_A2, (const unsigned int*)(ws + OFF_SCAL), ws + OFF_Z0);

    // pinv iterations
    for (int it = 0; it < 6; ++it) {
        float* zin  = ws + ((it & 1) ? OFF_Z1 : OFF_Z0);
        float* zout = ws + ((it & 1) ? OFF_Z0 : OFF_Z1);
        bmm_nn<<<dim3(64, HEADS), 256, 0, stream>>>(ws + OFF_A2, zin, ws + OFF_P,
            256, 256, 256, 65536, 65536, 65536, 0.f, 1.f);
        bmm_nn<<<dim3(64, HEADS), 256, 0, stream>>>(ws + OFF_P, ws + OFF_P, ws + OFF_T1,
            256, 256, 256, 65536, 65536, 65536, 7.f, -1.f);
        bmm_nn<<<dim3(64, HEADS), 256, 0, stream>>>(ws + OFF_P, ws + OFF_T1, ws + OFF_T2,
            256, 256, 256, 65536, 65536, 65536, 15.f, -1.f);
        bmm_nn<<<dim3(64, HEADS), 256, 0, stream>>>(zin, ws + OFF_T2, zout,
            256, 256, 256, 65536, 65536, 65536, 3.25f, -0.25f);
    }
    bmm_nn<<<dim3(16, HEADS), 256, 0, stream>>>(ws + OFF_Z0, ws + OFF_A3V, ws + OFF_BB,
        256, 64, 256, 65536, 16384, 16384, 0.f, 1.f);

    // ---- a1 pipeline (two 4-head halves) ----
    for (int hb = 0; hb < 8; hb += 4) {
        qk1_k<<<dim3(128, 4, 4), 256, 0, stream>>>(ws + OFF_QKV, ws + OFF_KL, sc1, hb);
        sm1_k<<<8192, 256, 0, stream>>>(sc1);
        pv1_k<<<dim3(128, 4), 256, 0, stream>>>(sc1, ws + OFF_BB, ws + OFF_ATTN, hb);
    }
    conv_res_k<<<(NSEQ * INNER) / 256, 256, 0, stream>>>(ws + OFF_QKV, res_kernel, ws + OFF_ATTN);

    // ---- convert attn + late weights to bf16 (ATTN fp32 consumed here) ----
    cvt_bf16_k<<<(NSEQ * INNER) / 2048, 256, 0, stream>>>(ws + OFF_ATTN, attn_bf);
    cvt_bf16_k<<<(DDIM * INNER) / 2048, 256, 0, stream>>>(w_out, wout_bf);
    tcvt_bf16_k<<<(WP * DDIM + 255) / 256, 256, 0, stream>>>(wq, wqt_bf, DDIM, WP);
    tcvt_bf16_k<<<(WP * DDIM + 255) / 256, 256, 0, stream>>>(wk, wkt_bf, DDIM, WP);
    cvt_bf16_k<<<(DDIM * DDIM) / 2048, 256, 0, stream>>>(wv_w, wv_bf);

    // enc = attn @ w_out^T + b_out + dense   [8192 x 512], K=512
    gemm_bf16_nt<<<dim3(NSEQ / 128, DDIM / 128), 256, 0, stream>>>(
        attn_bf, wout_bf, ws + OFF_ENC, DDIM, INNER, b_out, dense);

    cvt_bf16_k<<<(NSEQ * DDIM) / 2048, 256, 0, stream>>>(ws + OFF_ENC, enc_bf);

    // q_edge / k_edge  [8192 x 256], K=512
    gemm_bf16_nt<<<dim3(NSEQ / 128, WP / 128), 256, 0, stream>>>(
        enc_bf, wqt_bf, ws + OFF_QE, WP, DDIM, nullptr, nullptr);
    gemm_bf16_nt<<<dim3(NSEQ / 128, WP / 128), 256, 0, stream>>>(
        enc_bf, wkt_bf, ws + OFF_KE, WP, DDIM, nullptr, nullptr);

    edge_k<<<E / 4, 256, 0, stream>>>(ws + OFF_QE, ws + OFF_KE, adj_rows, adj_cols, adj_vals, A_raw);
    alpha_k<<<1, 1024, 0, stream>>>(A_raw, ws + OFF_ALPHA);

    // value = dense @ wv_w^T + wv_b   [8192 x 512], K=512  (Z region is dead again)
    cvt_bf16_k<<<(NSEQ * DDIM) / 2048, 256, 0, stream>>>(dense, dense_bf);
    gemm_bf16_nt<<<dim3(NSEQ / 128, DDIM / 128), 256, 0, stream>>>(
        dense_bf, wv_bf, ws + OFF_VAL, DDIM, DDIM, wv_b, nullptr);

    final_k<<<(NSEQ * DDIM) / 256, 256, 0, stream>>>(
        ws + OFF_ALPHA, ws + OFF_VAL, ws + OFF_ENC, out);
}

// Round 4
// 804.972 us; speedup vs baseline: 3.7386x; 1.1511x over previous
//
#include <hip/hip_runtime.h>
#include <hip/hip_bf16.h>

// Problem constants (fixed by reference)
#define NSEQ 8192
#define DDIM 512
#define HEADS 8
#define DH 64
#define MLM 256
#define LSUB 32          // NSEQ / MLM
#define WP 256
#define KCONV 33
#define INNER 512        // HEADS*DH
#define QKV_LD 1536

// ---------------- workspace layout (in floats) ----------------
static const size_t OFF_QKV   = 0;                 // 8192*1536 fp32
static const size_t OFF_ATTN  = 12582912;          // 8192*512
static const size_t OFF_ENC   = 16777216;          // 8192*512
static const size_t OFF_QL    = 21233664;          // 8*256*64
static const size_t OFF_KL    = 21364736;
static const size_t OFF_A2    = 21495808;          // 8*256*256
static const size_t OFF_Z0    = 22020096;
static const size_t OFF_Z1    = 22544384;          // also PV3 partials [16][8][256][64]
static const size_t OFF_P     = 23068672;
static const size_t OFF_T1    = 23592960;
static const size_t OFF_T2    = 24117248;
static const size_t OFF_A3V   = 24641536;          // 8*256*64
static const size_t OFF_BB    = 24772608;          // 8*256*64
static const size_t OFF_SCAL  = 24903680;          // 2 uints
static const size_t OFF_ALPHA = 24903696;          // 8192
// reuse of qkv region (only valid after its phase ends):
static const size_t OFF_QKE   = 0;                 // 8192*512 bf16 (2.1M float slots)
static const size_t OFF_VAL   = 4194304;           // 8192*512 fp32
static const size_t OFF_ATTNBF= 8388608;           // 8192*512 bf16
static const size_t OFF_ENCBF = 10485760;          // 8192*512 bf16
// bf16 overlays: w_qkv_bf early + (late) w_out/wqkT/wv in ATTN region;
// dense_bf in Z0 region (dead at start and after pinv);
// sc3 (a3 scores) spans ATTN+ENC; sc1 (a1 scores) in ENC.

__device__ __forceinline__ float bf2f(unsigned short u) {
    return __uint_as_float(((unsigned int)u) << 16);
}
__device__ __forceinline__ unsigned short f2bf(float x) {
    unsigned int u = __float_as_uint(x);
    u += 0x7FFFu + ((u >> 16) & 1u);   // RNE
    return (unsigned short)(u >> 16);
}

typedef __attribute__((ext_vector_type(8))) short bf16x8;
typedef __attribute__((ext_vector_type(4))) float f32x4;

__device__ __forceinline__ void gload_lds16(const void* g, void* l) {
    __builtin_amdgcn_global_load_lds(
        (const __attribute__((address_space(1))) unsigned int*)g,
        (__attribute__((address_space(3))) unsigned int*)l, 16, 0, 0);
}

// ---------------- fp32 -> bf16 conversion (8 elems/thread) ----------------
__global__ __launch_bounds__(256) void cvt_bf16_k(
    const float* __restrict__ in, unsigned short* __restrict__ out)
{
    size_t i = ((size_t)blockIdx.x * 256 + threadIdx.x) * 8;
    float4 a = *reinterpret_cast<const float4*>(in + i);
    float4 b = *reinterpret_cast<const float4*>(in + i + 4);
    uint4 p;
    p.x = (unsigned int)f2bf(a.x) | ((unsigned int)f2bf(a.y) << 16);
    p.y = (unsigned int)f2bf(a.z) | ((unsigned int)f2bf(a.w) << 16);
    p.z = (unsigned int)f2bf(b.x) | ((unsigned int)f2bf(b.y) << 16);
    p.w = (unsigned int)f2bf(b.z) | ((unsigned int)f2bf(b.w) << 16);
    *reinterpret_cast<uint4*>(out + i) = p;
}

// ---------------- transpose + convert: out[c][r] = bf16(in[r][c]) ----------
__global__ __launch_bounds__(256) void tcvt_bf16_k(
    const float* __restrict__ in, unsigned short* __restrict__ out, int R, int C)
{
    int idx = blockIdx.x * 256 + threadIdx.x;   // over C*R outputs, linear in out
    if (idx < R * C) {
        int oc = idx / R;       // out row (former col)
        int orow = idx % R;     // out col (former row)
        out[idx] = f2bf(in[(size_t)orow * C + oc]);
    }
}

// ======= bf16 MFMA NT GEMM (m97-style): C[m,n] = sum_k A[m,k]*B[n,k] =======
// A: [M x lda] bf16 row-major; B: [N x ldb] bf16 row-major.
// tile 64x128, BK=64, 256 threads = 4 waves (2x2), wave computes 32x64.
// LDS staged via global_load_lds w/ XOR swizzle (elem ^= (row&7)<<3, 8-elem gran).
__global__ __launch_bounds__(256) void gemm_mfma_nt(
    const unsigned short* __restrict__ A, int lda,
    const unsigned short* __restrict__ B, int ldb,
    float* __restrict__ C, unsigned short* __restrict__ Cbf, int ldc, int K,
    const float* __restrict__ bias, const float* __restrict__ addsrc)
{
    __shared__ __align__(16) unsigned short As[64 * 64];
    __shared__ __align__(16) unsigned short Bs[128 * 64];
    const int tid = threadIdx.x;
    const int wave = tid >> 6, lane = tid & 63;
    const int l15 = lane & 15, l4 = lane >> 4;
    const int wm = wave >> 1, wn = wave & 1;
    const size_t bm = (size_t)blockIdx.x * 64;
    const size_t bn = (size_t)blockIdx.y * 128;
    const int swzr = (l15 & 7) << 3;
    f32x4 acc[2][4] = {};
    for (int k0 = 0; k0 < K; k0 += 64) {
        __syncthreads();
#pragma unroll
        for (int c2 = 0; c2 < 2; ++c2) {       // A: 64x64 = 512 x 16B
            int id = c2 * 256 + tid;
            int row = id >> 3;
            int cg = ((id & 7) ^ (row & 7)) << 3;
            gload_lds16(A + (bm + row) * (size_t)lda + k0 + cg, As + id * 8);
        }
#pragma unroll
        for (int c2 = 0; c2 < 4; ++c2) {       // B: 128x64 = 1024 x 16B
            int id = c2 * 256 + tid;
            int row = id >> 3;
            int cg = ((id & 7) ^ (row & 7)) << 3;
            gload_lds16(B + (bn + row) * (size_t)ldb + k0 + cg, Bs + id * 8);
        }
        __syncthreads();
#pragma unroll
        for (int c = 0; c < 2; ++c) {
            bf16x8 af[2], bfv[4];
#pragma unroll
            for (int i = 0; i < 2; ++i)
                af[i] = *reinterpret_cast<const bf16x8*>(
                    &As[(wm * 32 + i * 16 + l15) * 64 + ((c * 32 + l4 * 8) ^ swzr)]);
#pragma unroll
            for (int j = 0; j < 4; ++j)
                bfv[j] = *reinterpret_cast<const bf16x8*>(
                    &Bs[(wn * 64 + j * 16 + l15) * 64 + ((c * 32 + l4 * 8) ^ swzr)]);
#pragma unroll
            for (int i = 0; i < 2; ++i)
#pragma unroll
                for (int j = 0; j < 4; ++j)
                    acc[i][j] = __builtin_amdgcn_mfma_f32_16x16x32_bf16(
                        af[i], bfv[j], acc[i][j], 0, 0, 0);
        }
    }
#pragma unroll
    for (int i = 0; i < 2; ++i)
#pragma unroll
        for (int j = 0; j < 4; ++j)
#pragma unroll
            for (int r = 0; r < 4; ++r) {
                size_t row = bm + wm * 32 + i * 16 + l4 * 4 + r;
                size_t col = bn + wn * 64 + j * 16 + l15;
                float v = acc[i][j][r];
                if (bias)   v += bias[col];
                if (addsrc) v += addsrc[row * (size_t)ldc + col];
                if (C)   C[row * (size_t)ldc + col] = v;
                if (Cbf) Cbf[row * (size_t)ldc + col] = f2bf(v);
            }
}

// ------------- batched NN GEMM: C = beta*(A@B) + alpha*A -------------
__global__ __launch_bounds__(256) void bmm_nn(
    const float* __restrict__ A, const float* __restrict__ B, float* __restrict__ C,
    int M, int N, int K, int sA, int sB, int sC, float alpha, float beta)
{
    __shared__ float As[32][33];
    __shared__ float Bs[32][33];
    const int b = blockIdx.y;
    const int ntiles = N >> 5;
    const int tm = blockIdx.x / ntiles, tn = blockIdx.x % ntiles;
    const float* Ab = A + (size_t)b * sA;
    const float* Bb = B + (size_t)b * sB;
    float* Cb = C + (size_t)b * sC;
    const int tid = threadIdx.x;
    const int tx = tid & 15, ty = tid >> 4;
    const int lr = tid >> 3;
    const int lc = (tid & 7) << 2;
    float acc[2][2] = {};
    for (int k0 = 0; k0 < K; k0 += 32) {
        float4 av = *reinterpret_cast<const float4*>(Ab + (size_t)(tm * 32 + lr) * K + k0 + lc);
        float4 bv = *reinterpret_cast<const float4*>(Bb + (size_t)(k0 + lr) * N + tn * 32 + lc);
        __syncthreads();
        As[lr][lc + 0] = av.x; As[lr][lc + 1] = av.y; As[lr][lc + 2] = av.z; As[lr][lc + 3] = av.w;
        Bs[lr][lc + 0] = bv.x; Bs[lr][lc + 1] = bv.y; Bs[lr][lc + 2] = bv.z; Bs[lr][lc + 3] = bv.w;
        __syncthreads();
#pragma unroll
        for (int kk = 0; kk < 32; ++kk) {
            float a0 = As[ty * 2 + 0][kk], a1 = As[ty * 2 + 1][kk];
            float b0 = Bs[kk][tx * 2 + 0], b1 = Bs[kk][tx * 2 + 1];
            acc[0][0] += a0 * b0; acc[0][1] += a0 * b1;
            acc[1][0] += a1 * b0; acc[1][1] += a1 * b1;
        }
    }
#pragma unroll
    for (int i = 0; i < 2; ++i)
#pragma unroll
        for (int j = 0; j < 2; ++j) {
            int row = tm * 32 + ty * 2 + i, col = tn * 32 + tx * 2 + j;
            float v = beta * acc[i][j];
            if (alpha != 0.f) v += alpha * Ab[(size_t)row * K + col];
            Cb[(size_t)row * N + col] = v;
        }
}

// ------------- landmark means (q scaled by 1/8) -------------
__global__ __launch_bounds__(64) void landmark_k(
    const float* __restrict__ qkv, float* __restrict__ q_l, float* __restrict__ k_l)
{
    int m = blockIdx.x, h = blockIdx.y, d = threadIdx.x;
    float sq = 0.f, sk = 0.f;
    for (int i = 0; i < LSUB; ++i) {
        size_t n = (size_t)m * LSUB + i;
        sq += qkv[n * QKV_LD + h * DH + d];
        sk += qkv[n * QKV_LD + 512 + h * DH + d];
    }
    q_l[((size_t)h * MLM + m) * DH + d] = sq * (0.125f / (float)LSUB);
    k_l[((size_t)h * MLM + m) * DH + d] = sk * (1.f / (float)LSUB);
}

// ------------- a2 = softmax(q_l @ k_l^T) rows -------------
__global__ __launch_bounds__(256) void a2_k(
    const float* __restrict__ q_l, const float* __restrict__ k_l, float* __restrict__ a2)
{
    int i = blockIdx.x, h = blockIdx.y, t = threadIdx.x;
    __shared__ float ql[64];
    __shared__ float red[256];
    if (t < 64) ql[t] = q_l[((size_t)h * MLM + i) * DH + t];
    __syncthreads();
    const float* kr = k_l + ((size_t)h * MLM + t) * DH;
    float s = 0.f;
#pragma unroll
    for (int d = 0; d < 64; d += 4) {
        float4 kv = *reinterpret_cast<const float4*>(kr + d);
        s += kv.x * ql[d] + kv.y * ql[d + 1] + kv.z * ql[d + 2] + kv.w * ql[d + 3];
    }
    red[t] = s; __syncthreads();
    for (int off = 128; off > 0; off >>= 1) { if (t < off) red[t] = fmaxf(red[t], red[t + off]); __syncthreads(); }
    float m = red[0]; __syncthreads();
    float e = __expf(s - m);
    red[t] = e; __syncthreads();
    for (int off = 128; off > 0; off >>= 1) { if (t < off) red[t] += red[t + off]; __syncthreads(); }
    a2[(((size_t)h * MLM + i) * MLM) + t] = e / red[0];
}

// ------------- global max of row/col abs-sums of a2 -------------
__global__ __launch_bounds__(256) void absmax_k(
    const float* __restrict__ a2, unsigned int* __restrict__ scal)
{
    int b = blockIdx.x, t = threadIdx.x;
    __shared__ float red[256];
    float sum = 0.f;
    if (b < 8) {
        const float* r = a2 + ((size_t)b * MLM + t) * MLM;
        for (int j = 0; j < MLM; ++j) sum += fabsf(r[j]);
    } else {
        int h = b - 8;
        for (int i = 0; i < MLM; ++i) sum += fabsf(a2[((size_t)h * MLM + i) * MLM + t]);
    }
    red[t] = sum; __syncthreads();
    for (int off = 128; off > 0; off >>= 1) { if (t < off) red[t] = fmaxf(red[t], red[t + off]); __syncthreads(); }
    if (t == 0) atomicMax(scal + (b < 8 ? 0 : 1), __float_as_uint(red[0]));
}

// ------------- z0 = a2^T / (rmax*cmax) -------------
__global__ __launch_bounds__(256) void zinit_k(
    const float* __restrict__ a2, const unsigned int* __restrict__ scal, float* __restrict__ z)
{
    int idx = blockIdx.x * 256 + threadIdx.x;
    float rmax = __uint_as_float(scal[0]);
    float cmax = __uint_as_float(scal[1]);
    float inv = 1.f / (rmax * cmax);
    int h = idx >> 16, rem = idx & 65535, i = rem >> 8, j = rem & 255;
    z[idx] = a2[((size_t)h << 16) + (j << 8) + i] * inv;
}

// ======================= a3 pipeline (GEMM-style) =======================
__global__ __launch_bounds__(256) void qk3_k(
    const float* __restrict__ q_l, const float* __restrict__ qkv,
    unsigned short* __restrict__ sc)
{
    __shared__ __align__(16) float As[16][68];
    __shared__ __align__(16) float Bs[16][68];
    const int h = blockIdx.z;
    const int tid = threadIdx.x;
    const int tx = tid & 15, ty = tid >> 4;
    const size_t bm = (size_t)blockIdx.x * 64;   // i
    const size_t bn = (size_t)blockIdx.y * 64;   // j
    const int lr = tid >> 2, lc = (tid & 3) << 2;
    const float* Ap = q_l + ((size_t)h * MLM + bm + lr) * DH + lc;
    const float* Bp = qkv + 512 + h * DH + (bn + lr) * (size_t)QKV_LD + lc;
    float acc[4][4] = {};
    for (int k0 = 0; k0 < DH; k0 += 16) {
        float4 av = *reinterpret_cast<const float4*>(Ap + k0);
        float4 bv = *reinterpret_cast<const float4*>(Bp + k0);
        __syncthreads();
        As[lc + 0][lr] = av.x; As[lc + 1][lr] = av.y;
        As[lc + 2][lr] = av.z; As[lc + 3][lr] = av.w;
        Bs[lc + 0][lr] = bv.x; Bs[lc + 1][lr] = bv.y;
        Bs[lc + 2][lr] = bv.z; Bs[lc + 3][lr] = bv.w;
        __syncthreads();
#pragma unroll
        for (int kk = 0; kk < 16; ++kk) {
            float4 a = *reinterpret_cast<const float4*>(&As[kk][ty << 2]);
            float4 b = *reinterpret_cast<const float4*>(&Bs[kk][tx << 2]);
            acc[0][0] += a.x * b.x; acc[0][1] += a.x * b.y; acc[0][2] += a.x * b.z; acc[0][3] += a.x * b.w;
            acc[1][0] += a.y * b.x; acc[1][1] += a.y * b.y; acc[1][2] += a.y * b.z; acc[1][3] += a.y * b.w;
            acc[2][0] += a.z * b.x; acc[2][1] += a.z * b.y; acc[2][2] += a.z * b.z; acc[2][3] += a.z * b.w;
            acc[3][0] += a.w * b.x; acc[3][1] += a.w * b.y; acc[3][2] += a.w * b.z; acc[3][3] += a.w * b.w;
        }
    }
    unsigned short* C = sc + (size_t)h * MLM * NSEQ;
#pragma unroll
    for (int i = 0; i < 4; ++i)
#pragma unroll
        for (int j = 0; j < 4; ++j)
            C[(bm + (ty << 2) + i) * NSEQ + bn + (tx << 2) + j] = f2bf(acc[i][j]);
}

// row softmax over 8192 bf16, in place; one block per row
__global__ __launch_bounds__(256) void sm3_k(unsigned short* __restrict__ sc)
{
    __shared__ float red[256];
    const int t = threadIdx.x;
    unsigned short* row = sc + (size_t)blockIdx.x * NSEQ;
    float v[32];
    float lmax = -1e30f;
#pragma unroll
    for (int u = 0; u < 4; ++u) {
        uint4 pk = *reinterpret_cast<const uint4*>(row + t * 32 + u * 8);
        unsigned int w[4] = {pk.x, pk.y, pk.z, pk.w};
#pragma unroll
        for (int q = 0; q < 4; ++q) {
            float lo = bf2f((unsigned short)(w[q] & 0xFFFF));
            float hi = bf2f((unsigned short)(w[q] >> 16));
            v[u * 8 + q * 2 + 0] = lo; v[u * 8 + q * 2 + 1] = hi;
            lmax = fmaxf(lmax, fmaxf(lo, hi));
        }
    }
    red[t] = lmax; __syncthreads();
    for (int off = 128; off > 0; off >>= 1) { if (t < off) red[t] = fmaxf(red[t], red[t + off]); __syncthreads(); }
    float m = red[0]; __syncthreads();
    float s = 0.f;
#pragma unroll
    for (int u = 0; u < 32; ++u) { v[u] = __expf(v[u] - m); s += v[u]; }
    red[t] = s; __syncthreads();
    for (int off = 128; off > 0; off >>= 1) { if (t < off) red[t] += red[t + off]; __syncthreads(); }
    float inv = 1.f / red[0];
#pragma unroll
    for (int u = 0; u < 4; ++u) {
        uint4 pk;
        unsigned int w[4];
#pragma unroll
        for (int q = 0; q < 4; ++q) {
            unsigned int lo = f2bf(v[u * 8 + q * 2 + 0] * inv);
            unsigned int hi = f2bf(v[u * 8 + q * 2 + 1] * inv);
            w[q] = lo | (hi << 16);
        }
        pk.x = w[0]; pk.y = w[1]; pk.z = w[2]; pk.w = w[3];
        *reinterpret_cast<uint4*>(row + t * 32 + u * 8) = pk;
    }
}

// PV split-K: part[kc][h][i][d] = sum_{j in chunk kc} P[h,i,j] * v[h,j,d]
__global__ __launch_bounds__(256) void pv3_k(
    const unsigned short* __restrict__ sc, const float* __restrict__ qkv,
    float* __restrict__ part)
{
    __shared__ __align__(16) float As[16][68];
    __shared__ __align__(16) float Bs[16][68];
    const int it = blockIdx.x;
    const int kc = blockIdx.y;
    const int h  = blockIdx.z;
    const int tid = threadIdx.x;
    const int tx = tid & 15, ty = tid >> 4;
    const int lr = tid >> 2, lc = (tid & 3) << 2;
    const int kr = tid >> 4, dc = (tid & 15) << 2;
    const unsigned short* Ap = sc + ((size_t)h * MLM + it * 64 + lr) * NSEQ + kc * 512;
    const float* Bp = qkv + 1024 + h * DH + dc;
    float acc[4][4] = {};
    for (int k0 = 0; k0 < 512; k0 += 16) {
        ushort4 av = *reinterpret_cast<const ushort4*>(Ap + k0 + lc);
        float4 bv = *reinterpret_cast<const float4*>(Bp + (size_t)(kc * 512 + k0 + kr) * QKV_LD);
        __syncthreads();
        As[lc + 0][lr] = bf2f(av.x); As[lc + 1][lr] = bf2f(av.y);
        As[lc + 2][lr] = bf2f(av.z); As[lc + 3][lr] = bf2f(av.w);
        Bs[kr][dc + 0] = bv.x; Bs[kr][dc + 1] = bv.y;
        Bs[kr][dc + 2] = bv.z; Bs[kr][dc + 3] = bv.w;
        __syncthreads();
#pragma unroll
        for (int kk = 0; kk < 16; ++kk) {
            float4 a = *reinterpret_cast<const float4*>(&As[kk][ty << 2]);
            float4 b = *reinterpret_cast<const float4*>(&Bs[kk][tx << 2]);
            acc[0][0] += a.x * b.x; acc[0][1] += a.x * b.y; acc[0][2] += a.x * b.z; acc[0][3] += a.x * b.w;
            acc[1][0] += a.y * b.x; acc[1][1] += a.y * b.y; acc[1][2] += a.y * b.z; acc[1][3] += a.y * b.w;
            acc[2][0] += a.z * b.x; acc[2][1] += a.z * b.y; acc[2][2] += a.z * b.z; acc[2][3] += a.z * b.w;
            acc[3][0] += a.w * b.x; acc[3][1] += a.w * b.y; acc[3][2] += a.w * b.z; acc[3][3] += a.w * b.w;
        }
    }
    float* Cp = part + ((size_t)(kc * 8 + h) * MLM + it * 64) * DH;
#pragma unroll
    for (int i = 0; i < 4; ++i)
#pragma unroll
        for (int j = 0; j < 4; ++j)
            Cp[((ty << 2) + i) * DH + (tx << 2) + j] = acc[i][j];
}

__global__ __launch_bounds__(256) void red3_k(
    const float* __restrict__ part, float* __restrict__ a3v)
{
    int o = blockIdx.x * 256 + threadIdx.x;
    float s = 0.f;
#pragma unroll
    for (int kc = 0; kc < 16; ++kc) s += part[(size_t)kc * 131072 + o];
    a3v[o] = s;
}

// ======================= a1 pipeline (GEMM-style, 4 heads/half) ==========
__global__ __launch_bounds__(256) void qk1_k(
    const float* __restrict__ qkv, const float* __restrict__ k_l,
    unsigned short* __restrict__ sc, int hb)
{
    __shared__ __align__(16) float As[16][68];
    __shared__ __align__(16) float Bs[16][68];
    const int hz = blockIdx.z;
    const int h = hb + hz;
    const int tid = threadIdx.x;
    const int tx = tid & 15, ty = tid >> 4;
    const size_t bm = (size_t)blockIdx.x * 64;
    const size_t bn = (size_t)blockIdx.y * 64;
    const int lr = tid >> 2, lc = (tid & 3) << 2;
    const float* Ap = qkv + (bm + lr) * (size_t)QKV_LD + h * DH + lc;
    const float* Bp = k_l + ((size_t)h * MLM + bn + lr) * DH + lc;
    float acc[4][4] = {};
    for (int k0 = 0; k0 < DH; k0 += 16) {
        float4 av = *reinterpret_cast<const float4*>(Ap + k0);
        float4 bv = *reinterpret_cast<const float4*>(Bp + k0);
        av.x *= 0.125f; av.y *= 0.125f; av.z *= 0.125f; av.w *= 0.125f;
        __syncthreads();
        As[lc + 0][lr] = av.x; As[lc + 1][lr] = av.y;
        As[lc + 2][lr] = av.z; As[lc + 3][lr] = av.w;
        Bs[lc + 0][lr] = bv.x; Bs[lc + 1][lr] = bv.y;
        Bs[lc + 2][lr] = bv.z; Bs[lc + 3][lr] = bv.w;
        __syncthreads();
#pragma unroll
        for (int kk = 0; kk < 16; ++kk) {
            float4 a = *reinterpret_cast<const float4*>(&As[kk][ty << 2]);
            float4 b = *reinterpret_cast<const float4*>(&Bs[kk][tx << 2]);
            acc[0][0] += a.x * b.x; acc[0][1] += a.x * b.y; acc[0][2] += a.x * b.z; acc[0][3] += a.x * b.w;
            acc[1][0] += a.y * b.x; acc[1][1] += a.y * b.y; acc[1][2] += a.y * b.z; acc[1][3] += a.y * b.w;
            acc[2][0] += a.z * b.x; acc[2][1] += a.z * b.y; acc[2][2] += a.z * b.z; acc[2][3] += a.z * b.w;
            acc[3][0] += a.w * b.x; acc[3][1] += a.w * b.y; acc[3][2] += a.w * b.z; acc[3][3] += a.w * b.w;
        }
    }
    unsigned short* C = sc + (size_t)hz * NSEQ * MLM;
#pragma unroll
    for (int i = 0; i < 4; ++i)
#pragma unroll
        for (int j = 0; j < 4; ++j)
            C[(bm + (ty << 2) + i) * MLM + bn + (tx << 2) + j] = f2bf(acc[i][j]);
}

// softmax over rows of length 256, one wave per row (4 rows/block)
__global__ __launch_bounds__(256) void sm1_k(unsigned short* __restrict__ sc)
{
    const int row = blockIdx.x * 4 + (threadIdx.x >> 6);
    const int lane = threadIdx.x & 63;
    unsigned short* rp = sc + (size_t)row * MLM;
    uint2 pk = *reinterpret_cast<const uint2*>(rp + lane * 4);
    float x0 = bf2f((unsigned short)(pk.x & 0xFFFF));
    float x1 = bf2f((unsigned short)(pk.x >> 16));
    float x2 = bf2f((unsigned short)(pk.y & 0xFFFF));
    float x3 = bf2f((unsigned short)(pk.y >> 16));
    float m = fmaxf(fmaxf(x0, x1), fmaxf(x2, x3));
    for (int off = 32; off > 0; off >>= 1) m = fmaxf(m, __shfl_xor(m, off));
    x0 = __expf(x0 - m); x1 = __expf(x1 - m); x2 = __expf(x2 - m); x3 = __expf(x3 - m);
    float s = x0 + x1 + x2 + x3;
    for (int off = 32; off > 0; off >>= 1) s += __shfl_xor(s, off);
    float inv = 1.f / s;
    unsigned int l0 = f2bf(x0 * inv), h0 = f2bf(x1 * inv);
    unsigned int l1 = f2bf(x2 * inv), h1 = f2bf(x3 * inv);
    pk.x = l0 | (h0 << 16); pk.y = l1 | (h1 << 16);
    *reinterpret_cast<uint2*>(rp + lane * 4) = pk;
}

// PV: attn[n, h*64+d] = sum_j P1[hz,n,j] * Bbuf[h,j,d]
__global__ __launch_bounds__(256) void pv1_k(
    const unsigned short* __restrict__ sc, const float* __restrict__ Bb,
    float* __restrict__ attn, int hb)
{
    __shared__ __align__(16) float As[16][68];
    __shared__ __align__(16) float Bs[16][68];
    const int hz = blockIdx.y;
    const int h = hb + hz;
    const int tid = threadIdx.x;
    const int tx = tid & 15, ty = tid >> 4;
    const size_t bm = (size_t)blockIdx.x * 64;
    const int lr = tid >> 2, lc = (tid & 3) << 2;
    const int kr = tid >> 4, dc = (tid & 15) << 2;
    const unsigned short* Ap = sc + ((size_t)hz * NSEQ + bm + lr) * MLM;
    const float* Bp = Bb + (size_t)h * MLM * DH + dc;
    float acc[4][4] = {};
    for (int k0 = 0; k0 < MLM; k0 += 16) {
        ushort4 av = *reinterpret_cast<const ushort4*>(Ap + k0 + lc);
        float4 bv = *reinterpret_cast<const float4*>(Bp + (size_t)(k0 + kr) * DH);
        __syncthreads();
        As[lc + 0][lr] = bf2f(av.x); As[lc + 1][lr] = bf2f(av.y);
        As[lc + 2][lr] = bf2f(av.z); As[lc + 3][lr] = bf2f(av.w);
        Bs[kr][dc + 0] = bv.x; Bs[kr][dc + 1] = bv.y;
        Bs[kr][dc + 2] = bv.z; Bs[kr][dc + 3] = bv.w;
        __syncthreads();
#pragma unroll
        for (int kk = 0; kk < 16; ++kk) {
            float4 a = *reinterpret_cast<const float4*>(&As[kk][ty << 2]);
            float4 b = *reinterpret_cast<const float4*>(&Bs[kk][tx << 2]);
            acc[0][0] += a.x * b.x; acc[0][1] += a.x * b.y; acc[0][2] += a.x * b.z; acc[0][3] += a.x * b.w;
            acc[1][0] += a.y * b.x; acc[1][1] += a.y * b.y; acc[1][2] += a.y * b.z; acc[1][3] += a.y * b.w;
            acc[2][0] += a.z * b.x; acc[2][1] += a.z * b.y; acc[2][2] += a.z * b.z; acc[2][3] += a.z * b.w;
            acc[3][0] += a.w * b.x; acc[3][1] += a.w * b.y; acc[3][2] += a.w * b.z; acc[3][3] += a.w * b.w;
        }
    }
#pragma unroll
    for (int i = 0; i < 4; ++i)
#pragma unroll
        for (int j = 0; j < 4; ++j)
            attn[(bm + (ty << 2) + i) * (size_t)INNER + h * DH + (tx << 2) + j] = acc[i][j];
}

// ------------- depthwise conv residual add -------------
__global__ __launch_bounds__(256) void conv_res_k(
    const float* __restrict__ qkv, const float* __restrict__ kern, float* __restrict__ attnbuf)
{
    size_t idx = (size_t)blockIdx.x * 256 + threadIdx.x;
    int n = (int)(idx >> 9), c = (int)(idx & 511), h = c >> 6;
    float acc = 0.f;
#pragma unroll
    for (int t2 = 0; t2 < KCONV; ++t2) {
        int nn = n + t2 - KCONV / 2;
        if (nn >= 0 && nn < NSEQ)
            acc += qkv[(size_t)nn * QKV_LD + 1024 + c] * kern[h * KCONV + t2];
    }
    attnbuf[idx] += acc;
}

// ------------- sparse edge scores (bf16 fused qke) + segment sum -------------
__global__ __launch_bounds__(256) void edge_k(
    const unsigned short* __restrict__ qke,
    const int* __restrict__ rows, const int* __restrict__ cols,
    const float* __restrict__ vals, float* __restrict__ A_raw)
{
    int e = blockIdx.x * 4 + (threadIdx.x >> 6);
    int lane = threadIdx.x & 63;
    int r = rows[e], c = cols[e];
    const unsigned short* qr = qke + (size_t)r * 512;
    const unsigned short* kr = qke + (size_t)c * 512 + 256;
    ushort4 a = *reinterpret_cast<const ushort4*>(qr + lane * 4);
    ushort4 b = *reinterpret_cast<const ushort4*>(kr + lane * 4);
    float s = bf2f(a.x) * bf2f(b.x) + bf2f(a.y) * bf2f(b.y)
            + bf2f(a.z) * bf2f(b.z) + bf2f(a.w) * bf2f(b.w);
    for (int off = 32; off > 0; off >>= 1) s += __shfl_down(s, off, 64);
    if (lane == 0) atomicAdd(&A_raw[r], s * vals[e] * 0.0625f);
}

// ------------- alpha = softmax(A_raw) -------------
__global__ __launch_bounds__(1024) void alpha_k(
    const float* __restrict__ A_raw, float* __restrict__ alpha)
{
    __shared__ float red[1024];
    int t = threadIdx.x;
    float m = -1e30f;
    for (int i = t; i < NSEQ; i += 1024) m = fmaxf(m, A_raw[i]);
    red[t] = m; __syncthreads();
    for (int off = 512; off > 0; off >>= 1) { if (t < off) red[t] = fmaxf(red[t], red[t + off]); __syncthreads(); }
    m = red[0]; __syncthreads();
    float s = 0.f;
    for (int i = t; i < NSEQ; i += 1024) s += __expf(A_raw[i] - m);
    red[t] = s; __syncthreads();
    for (int off = 512; off > 0; off >>= 1) { if (t < off) red[t] += red[t + off]; __syncthreads(); }
    float inv = 1.f / red[0];
    for (int i = t; i < NSEQ; i += 1024) alpha[i] = __expf(A_raw[i] - m) * inv;
}

// ------------- final gated blend -------------
__global__ __launch_bounds__(256) void final_k(
    const float* __restrict__ alpha, const float* __restrict__ value,
    const float* __restrict__ enc, float* __restrict__ xo)
{
    size_t idx = (size_t)blockIdx.x * 256 + threadIdx.x;
    int n = (int)(idx >> 9);
    float xl = alpha[n] * value[idx];
    float w = 1.f / (1.f + __expf(xl));
    float sq = w * w;
    xo[idx] = xl * 2.f * sq + 2.f * enc[idx] * (1.f - sq);
}

extern "C" void kernel_launch(void* const* d_in, const int* in_sizes, int n_in,
                              void* d_out, int out_size, void* d_ws, size_t ws_size,
                              hipStream_t stream)
{
    const float* dense      = (const float*)d_in[0];
    const int*   adj_rows   = (const int*)d_in[1];
    const int*   adj_cols   = (const int*)d_in[2];
    const float* adj_vals   = (const float*)d_in[3];
    const float* wq         = (const float*)d_in[4];
    const float* wk         = (const float*)d_in[5];
    const float* w_qkv      = (const float*)d_in[6];
    const float* w_out      = (const float*)d_in[7];
    const float* b_out      = (const float*)d_in[8];
    const float* res_kernel = (const float*)d_in[9];
    const float* wv_w       = (const float*)d_in[10];
    const float* wv_b       = (const float*)d_in[11];
    const int E = in_sizes[1];

    float* ws  = (float*)d_ws;
    float* out = (float*)d_out;
    float* A_raw = out + (size_t)NSEQ * DDIM;
    unsigned short* sc3 = (unsigned short*)(ws + OFF_ATTN);   // 8*256*8192 bf16
    unsigned short* sc1 = (unsigned short*)(ws + OFF_ENC);    // 4*8192*256 bf16

    // bf16 overlays
    unsigned short* wqkv_bf  = (unsigned short*)(ws + OFF_ATTN);   // dead before sc3
    unsigned short* dense_bf = (unsigned short*)(ws + OFF_Z0);     // dead before zinit / after pinv
    unsigned short* attn_bf  = (unsigned short*)(ws + OFF_ATTNBF);
    unsigned short* enc_bf   = (unsigned short*)(ws + OFF_ENCBF);
    unsigned short* qke_bf   = (unsigned short*)(ws + OFF_QKE);
    unsigned short* wout_bf  = (unsigned short*)(ws + OFF_ATTN);              // after attn cvt'd
    unsigned short* wqkT_bf  = (unsigned short*)(ws + OFF_ATTN + 131072);     // fused [512][512]
    unsigned short* wv_bf    = (unsigned short*)(ws + OFF_ATTN + 262144);

    hipMemsetAsync(A_raw, 0, NSEQ * sizeof(float), stream);
    hipMemsetAsync(ws + OFF_SCAL, 0, 2 * sizeof(unsigned int), stream);

    // ---- convert inputs for qkv GEMM ----
    cvt_bf16_k<<<(NSEQ * DDIM) / 2048, 256, 0, stream>>>(dense, dense_bf);
    cvt_bf16_k<<<(1536 * DDIM) / 2048, 256, 0, stream>>>(w_qkv, wqkv_bf);

    // qkv = dense @ w_qkv^T   [8192 x 1536], K=512
    gemm_mfma_nt<<<dim3(NSEQ / 64, 1536 / 128), 256, 0, stream>>>(
        dense_bf, DDIM, wqkv_bf, DDIM, ws + OFF_QKV, nullptr, QKV_LD, DDIM,
        nullptr, nullptr);

    landmark_k<<<dim3(MLM, HEADS), 64, 0, stream>>>(ws + OFF_QKV, ws + OFF_QL, ws + OFF_KL);

    // ---- a3 pipeline ----
    qk3_k<<<dim3(4, 128, 8), 256, 0, stream>>>(ws + OFF_QL, ws + OFF_QKV, sc3);
    sm3_k<<<2048, 256, 0, stream>>>(sc3);
    pv3_k<<<dim3(4, 16, 8), 256, 0, stream>>>(sc3, ws + OFF_QKV, ws + OFF_Z1);
    red3_k<<<512, 256, 0, stream>>>(ws + OFF_Z1, ws + OFF_A3V);

    a2_k<<<dim3(MLM, HEADS), 256, 0, stream>>>(ws + OFF_QL, ws + OFF_KL, ws + OFF_A2);
    absmax_k<<<16, 256, 0, stream>>>(ws + OFF_A2, (unsigned int*)(ws + OFF_SCAL));
    zinit_k<<<(HEADS * MLM * MLM) / 256, 256, 0, stream>>>(
        ws + OFF_A2, (const unsigned int*)(ws + OFF_SCAL), ws + OFF_Z0);

    // pinv iterations
    for (int it = 0; it < 6; ++it) {
        float* zin  = ws + ((it & 1) ? OFF_Z1 : OFF_Z0);
        float* zout = ws + ((it & 1) ? OFF_Z0 : OFF_Z1);
        bmm_nn<<<dim3(64, HEADS), 256, 0, stream>>>(ws + OFF_A2, zin, ws + OFF_P,
            256, 256, 256, 65536, 65536, 65536, 0.f, 1.f);
        bmm_nn<<<dim3(64, HEADS), 256, 0, stream>>>(ws + OFF_P, ws + OFF_P, ws + OFF_T1,
            256, 256, 256, 65536, 65536, 65536, 7.f, -1.f);
        bmm_nn<<<dim3(64, HEADS), 256, 0, stream>>>(ws + OFF_P, ws + OFF_T1, ws + OFF_T2,
            256, 256, 256, 65536, 65536, 65536, 15.f, -1.f);
        bmm_nn<<<dim3(64, HEADS), 256, 0, stream>>>(zin, ws + OFF_T2, zout,
            256, 256, 256, 65536, 65536, 65536, 3.25f, -0.25f);
    }
    bmm_nn<<<dim3(16, HEADS), 256, 0, stream>>>(ws + OFF_Z0, ws + OFF_A3V, ws + OFF_BB,
        256, 64, 256, 65536, 16384, 16384, 0.f, 1.f);

    // ---- a1 pipeline (two 4-head halves) ----
    for (int hb = 0; hb < 8; hb += 4) {
        qk1_k<<<dim3(128, 4, 4), 256, 0, stream>>>(ws + OFF_QKV, ws + OFF_KL, sc1, hb);
        sm1_k<<<8192, 256, 0, stream>>>(sc1);
        pv1_k<<<dim3(128, 4), 256, 0, stream>>>(sc1, ws + OFF_BB, ws + OFF_ATTN, hb);
    }
    conv_res_k<<<(NSEQ * INNER) / 256, 256, 0, stream>>>(ws + OFF_QKV, res_kernel, ws + OFF_ATTN);

    // ---- convert attn + late weights to bf16 ----
    cvt_bf16_k<<<(NSEQ * INNER) / 2048, 256, 0, stream>>>(ws + OFF_ATTN, attn_bf);
    cvt_bf16_k<<<(DDIM * INNER) / 2048, 256, 0, stream>>>(w_out, wout_bf);
    tcvt_bf16_k<<<(WP * DDIM + 255) / 256, 256, 0, stream>>>(wq, wqkT_bf, DDIM, WP);
    tcvt_bf16_k<<<(WP * DDIM + 255) / 256, 256, 0, stream>>>(wk, wqkT_bf + 256 * 512, DDIM, WP);
    cvt_bf16_k<<<(DDIM * DDIM) / 2048, 256, 0, stream>>>(wv_w, wv_bf);

    // enc = attn @ w_out^T + b_out + dense   [8192 x 512], dual write fp32+bf16
    gemm_mfma_nt<<<dim3(NSEQ / 64, DDIM / 128), 256, 0, stream>>>(
        attn_bf, INNER, wout_bf, INNER, ws + OFF_ENC, enc_bf, DDIM, INNER,
        b_out, dense);

    // qke = enc @ [wq|wk]  -> bf16 [8192 x 512] (cols 0-255 q_edge, 256-511 k_edge)
    gemm_mfma_nt<<<dim3(NSEQ / 64, 512 / 128), 256, 0, stream>>>(
        enc_bf, DDIM, wqkT_bf, DDIM, nullptr, qke_bf, 512, DDIM,
        nullptr, nullptr);

    edge_k<<<E / 4, 256, 0, stream>>>(qke_bf, adj_rows, adj_cols, adj_vals, A_raw);
    alpha_k<<<1, 1024, 0, stream>>>(A_raw, ws + OFF_ALPHA);

    // value = dense @ wv_w^T + wv_b   [8192 x 512]  (Z region dead again)
    cvt_bf16_k<<<(NSEQ * DDIM) / 2048, 256, 0, stream>>>(dense, dense_bf);
    gemm_mfma_nt<<<dim3(NSEQ / 64, DDIM / 128), 256, 0, stream>>>(
        dense_bf, DDIM, wv_bf, DDIM, ws + OFF_VAL, nullptr, DDIM, DDIM,
        wv_b, nullptr);

    final_k<<<(NSEQ * DDIM) / 256, 256, 0, stream>>>(
        ws + OFF_ALPHA, ws + OFF_VAL, ws + OFF_ENC, out);
}

// Round 5
// 638.941 us; speedup vs baseline: 4.7101x; 1.2599x over previous
//
#include <hip/hip_runtime.h>
#include <hip/hip_bf16.h>

// Problem constants (fixed by reference)
#define NSEQ 8192
#define DDIM 512
#define HEADS 8
#define DH 64
#define MLM 256
#define LSUB 32          // NSEQ / MLM
#define WP 256
#define KCONV 33
#define INNER 512        // HEADS*DH
#define QKV_LD 1536

// ---------------- workspace layout (float offsets) ----------------
// qkv_bf [0, 6.29M) bf16, live step 4..20; enc fp32/enc_bf overlay it later.
static const size_t OFF_QKVBF  = 0;          // bf16 8192*1536 = 6,291,456 fl
static const size_t OFF_VT     = 6291456;    // bf16 8*64*8192 = 2,097,152 fl
static const size_t OFF_SC     = 8388608;    // bf16 scores 8*256*8192 (=sc1 8*8192*256), 8,388,608 fl
// pinv overlay inside SC (alive only between score phases):
static const size_t OFF_A2     = 8388608;
static const size_t OFF_Z0     = 8912896;
static const size_t OFF_Z1     = 9437184;
static const size_t OFF_P      = 9961472;
static const size_t OFF_T1     = 10485760;
static const size_t OFF_T2     = 11010048;
// late overlays inside SC (after pv1 consumed sc1):
static const size_t OFF_QKE    = 10485760;   // bf16 8192*512 = 2,097,152 fl
static const size_t OFF_ATTNBF = 12582912;   // bf16 8192*512
static const size_t OFF_ATTN   = 16777216;   // fp32 attn (also pv3 partials early)
// enc fp32 overlays dead qkv_bf region:
static const size_t OFF_ENC    = 0;          // fp32 8192*512
static const size_t OFF_ENCBF  = 4194304;    // bf16 8192*512
static const size_t OFF_VAL    = 6291456;    // fp32 8192*512 (vT dead)
// tail region:
static const size_t OFF_DENSEBF= 20971520;   // bf16 8192*512
static const size_t OFF_WQKVBF = 23068672;   // bf16 1536*512
static const size_t OFF_WOUTBF = 23461888;   // bf16 512*512
static const size_t OFF_WQKT   = 23592960;   // bf16 512*512 (wq^T rows 0-255, wk^T 256-511)
static const size_t OFF_WVBF   = 23724032;   // bf16 512*512
static const size_t OFF_QL     = 23855104;   // fp32 8*256*64
static const size_t OFF_KL     = 23986176;   // fp32 8*256*64
static const size_t OFF_QLBF   = 24117248;   // bf16 8*256*64
static const size_t OFF_KLSBF  = 24182784;   // bf16 8*256*64 (k_l * 0.125)
static const size_t OFF_A3V    = 24248320;   // fp32 8*256*64
static const size_t OFF_BB     = 24379392;   // fp32 8*256*64
static const size_t OFF_BBT    = 24510464;   // bf16 8*64*256
static const size_t OFF_SCAL   = 24576000;   // 2 uints
static const size_t OFF_ALPHA  = 24576016;   // 8192 fp32

__device__ __forceinline__ float bf2f(unsigned short u) {
    return __uint_as_float(((unsigned int)u) << 16);
}
__device__ __forceinline__ unsigned short f2bf(float x) {
    unsigned int u = __float_as_uint(x);
    u += 0x7FFFu + ((u >> 16) & 1u);   // RNE
    return (unsigned short)(u >> 16);
}

typedef __attribute__((ext_vector_type(8))) short bf16x8;
typedef __attribute__((ext_vector_type(4))) float f32x4;

__device__ __forceinline__ void gload_lds16(const void* g, void* l) {
    __builtin_amdgcn_global_load_lds(
        (const __attribute__((address_space(1))) unsigned int*)g,
        (__attribute__((address_space(3))) unsigned int*)l, 16, 0, 0);
}

// ---------------- fp32 -> bf16 conversion (8 elems/thread) ----------------
__global__ __launch_bounds__(256) void cvt_bf16_k(
    const float* __restrict__ in, unsigned short* __restrict__ out)
{
    size_t i = ((size_t)blockIdx.x * 256 + threadIdx.x) * 8;
    float4 a = *reinterpret_cast<const float4*>(in + i);
    float4 b = *reinterpret_cast<const float4*>(in + i + 4);
    uint4 p;
    p.x = (unsigned int)f2bf(a.x) | ((unsigned int)f2bf(a.y) << 16);
    p.y = (unsigned int)f2bf(a.z) | ((unsigned int)f2bf(a.w) << 16);
    p.z = (unsigned int)f2bf(b.x) | ((unsigned int)f2bf(b.y) << 16);
    p.w = (unsigned int)f2bf(b.z) | ((unsigned int)f2bf(b.w) << 16);
    *reinterpret_cast<uint4*>(out + i) = p;
}

// ---------------- transpose + convert: out[c][r] = bf16(in[r][c]) ----------
__global__ __launch_bounds__(256) void tcvt_bf16_k(
    const float* __restrict__ in, unsigned short* __restrict__ out, int R, int C)
{
    int idx = blockIdx.x * 256 + threadIdx.x;
    if (idx < R * C) {
        int oc = idx / R;
        int orow = idx % R;
        out[idx] = f2bf(in[(size_t)orow * C + oc]);
    }
}

// ===== batched bf16 MFMA NT GEMM: C[b,m,n] = sum_k A[b,m,k]*B[b,n,k] =====
// tile 64x128, BK=64, 256 threads = 4 waves (2x2), wave computes 32x64.
__global__ __launch_bounds__(256) void gemm_mfma_ntb(
    const unsigned short* __restrict__ A, int lda, size_t sA,
    const unsigned short* __restrict__ B, int ldb, size_t sB,
    float* __restrict__ C, unsigned short* __restrict__ Cbf, int ldc, size_t sC,
    int K, const float* __restrict__ bias, const float* __restrict__ addsrc)
{
    __shared__ __align__(16) unsigned short As[64 * 64];
    __shared__ __align__(16) unsigned short Bs[128 * 64];
    const int tid = threadIdx.x;
    const int wave = tid >> 6, lane = tid & 63;
    const int l15 = lane & 15, l4 = lane >> 4;
    const int wm = wave >> 1, wn = wave & 1;
    const size_t bm = (size_t)blockIdx.x * 64;
    const size_t bn = (size_t)blockIdx.y * 128;
    const int z = blockIdx.z;
    const unsigned short* Ab = A + (size_t)z * sA;
    const unsigned short* Bb = B + (size_t)z * sB;
    const int swzr = (l15 & 7) << 3;
    f32x4 acc[2][4] = {};
    for (int k0 = 0; k0 < K; k0 += 64) {
        __syncthreads();
#pragma unroll
        for (int c2 = 0; c2 < 2; ++c2) {       // A: 64x64 = 512 x 16B
            int id = c2 * 256 + tid;
            int row = id >> 3;
            int cg = ((id & 7) ^ (row & 7)) << 3;
            gload_lds16(Ab + (bm + row) * (size_t)lda + k0 + cg, As + id * 8);
        }
#pragma unroll
        for (int c2 = 0; c2 < 4; ++c2) {       // B: 128x64 = 1024 x 16B
            int id = c2 * 256 + tid;
            int row = id >> 3;
            int cg = ((id & 7) ^ (row & 7)) << 3;
            gload_lds16(Bb + (bn + row) * (size_t)ldb + k0 + cg, Bs + id * 8);
        }
        __syncthreads();
#pragma unroll
        for (int c = 0; c < 2; ++c) {
            bf16x8 af[2], bfv[4];
#pragma unroll
            for (int i = 0; i < 2; ++i)
                af[i] = *reinterpret_cast<const bf16x8*>(
                    &As[(wm * 32 + i * 16 + l15) * 64 + ((c * 32 + l4 * 8) ^ swzr)]);
#pragma unroll
            for (int j = 0; j < 4; ++j)
                bfv[j] = *reinterpret_cast<const bf16x8*>(
                    &Bs[(wn * 64 + j * 16 + l15) * 64 + ((c * 32 + l4 * 8) ^ swzr)]);
#pragma unroll
            for (int i = 0; i < 2; ++i)
#pragma unroll
                for (int j = 0; j < 4; ++j)
                    acc[i][j] = __builtin_amdgcn_mfma_f32_16x16x32_bf16(
                        af[i], bfv[j], acc[i][j], 0, 0, 0);
        }
    }
    float* Cz = C ? C + (size_t)z * sC : nullptr;
    unsigned short* Cbz = Cbf ? Cbf + (size_t)z * sC : nullptr;
#pragma unroll
    for (int i = 0; i < 2; ++i)
#pragma unroll
        for (int j = 0; j < 4; ++j)
#pragma unroll
            for (int r = 0; r < 4; ++r) {
                size_t row = bm + wm * 32 + i * 16 + l4 * 4 + r;
                size_t col = bn + wn * 64 + j * 16 + l15;
                float v = acc[i][j][r];
                if (bias)   v += bias[col];
                if (addsrc) v += addsrc[row * (size_t)ldc + col];
                if (Cz)  Cz[row * (size_t)ldc + col] = v;
                if (Cbz) Cbz[row * (size_t)ldc + col] = f2bf(v);
            }
}

// ===== fp32-accurate batched NN GEMM via bf16 hi/lo split MFMA =====
// C = beta*(A@B) + alpha*A  (square-A alpha path); A [Mx K] ld K, B [K x N] ld N
__global__ __launch_bounds__(256) void bmm_split(
    const float* __restrict__ A, const float* __restrict__ B, float* __restrict__ C,
    int K, int N, int ntn, size_t sA, size_t sB, size_t sC, float alpha, float beta)
{
    __shared__ __align__(16) unsigned short Ah[64 * 72], Al[64 * 72];
    __shared__ __align__(16) unsigned short Bh[64 * 72], Bl[64 * 72];
    const int tid = threadIdx.x;
    const int wave = tid >> 6, lane = tid & 63;
    const int l15 = lane & 15, l4 = lane >> 4;
    const int wm = wave >> 1, wn = wave & 1;
    const int b = blockIdx.y;
    const int tm = blockIdx.x / ntn, tn = blockIdx.x % ntn;
    const float* Ab = A + (size_t)b * sA;
    const float* Bb = B + (size_t)b * sB;
    float* Cb = C + (size_t)b * sC;
    const int arow = tid >> 2, akq = (tid & 3) * 16;
    const int kp = tid & 31, nc = tid >> 5;
    f32x4 acc[2][2] = {};
    for (int k0 = 0; k0 < K; k0 += 64) {
        __syncthreads();
#pragma unroll
        for (int s = 0; s < 4; ++s) {
            float4 a = *reinterpret_cast<const float4*>(Ab + (size_t)(tm * 64 + arow) * K + k0 + akq + s * 4);
            unsigned short h0 = f2bf(a.x), h1 = f2bf(a.y), h2 = f2bf(a.z), h3 = f2bf(a.w);
            unsigned short g0 = f2bf(a.x - bf2f(h0)), g1 = f2bf(a.y - bf2f(h1));
            unsigned short g2 = f2bf(a.z - bf2f(h2)), g3 = f2bf(a.w - bf2f(h3));
            uint2 ph, pl;
            ph.x = h0 | ((unsigned int)h1 << 16); ph.y = h2 | ((unsigned int)h3 << 16);
            pl.x = g0 | ((unsigned int)g1 << 16); pl.y = g2 | ((unsigned int)g3 << 16);
            *reinterpret_cast<uint2*>(&Ah[arow * 72 + akq + s * 4]) = ph;
            *reinterpret_cast<uint2*>(&Al[arow * 72 + akq + s * 4]) = pl;
        }
#pragma unroll
        for (int s = 0; s < 2; ++s) {
            int cb = nc * 8 + s * 4;
            float4 b0 = *reinterpret_cast<const float4*>(Bb + (size_t)(k0 + 2 * kp) * N + tn * 64 + cb);
            float4 b1 = *reinterpret_cast<const float4*>(Bb + (size_t)(k0 + 2 * kp + 1) * N + tn * 64 + cb);
            float x0[4] = {b0.x, b0.y, b0.z, b0.w};
            float x1[4] = {b1.x, b1.y, b1.z, b1.w};
#pragma unroll
            for (int c = 0; c < 4; ++c) {
                unsigned short h0 = f2bf(x0[c]), h1 = f2bf(x1[c]);
                unsigned short g0 = f2bf(x0[c] - bf2f(h0)), g1 = f2bf(x1[c] - bf2f(h1));
                *reinterpret_cast<unsigned int*>(&Bh[(cb + c) * 72 + 2 * kp]) =
                    h0 | ((unsigned int)h1 << 16);
                *reinterpret_cast<unsigned int*>(&Bl[(cb + c) * 72 + 2 * kp]) =
                    g0 | ((unsigned int)g1 << 16);
            }
        }
        __syncthreads();
#pragma unroll
        for (int ks = 0; ks < 2; ++ks) {
            bf16x8 ah[2], al[2], bh[2], bl[2];
#pragma unroll
            for (int i = 0; i < 2; ++i) {
                int rr = (wm * 32 + i * 16 + l15) * 72 + ks * 32 + l4 * 8;
                ah[i] = *reinterpret_cast<const bf16x8*>(&Ah[rr]);
                al[i] = *reinterpret_cast<const bf16x8*>(&Al[rr]);
            }
#pragma unroll
            for (int j = 0; j < 2; ++j) {
                int rr = (wn * 32 + j * 16 + l15) * 72 + ks * 32 + l4 * 8;
                bh[j] = *reinterpret_cast<const bf16x8*>(&Bh[rr]);
                bl[j] = *reinterpret_cast<const bf16x8*>(&Bl[rr]);
            }
#pragma unroll
            for (int i = 0; i < 2; ++i)
#pragma unroll
                for (int j = 0; j < 2; ++j) {
                    acc[i][j] = __builtin_amdgcn_mfma_f32_16x16x32_bf16(ah[i], bh[j], acc[i][j], 0, 0, 0);
                    acc[i][j] = __builtin_amdgcn_mfma_f32_16x16x32_bf16(ah[i], bl[j], acc[i][j], 0, 0, 0);
                    acc[i][j] = __builtin_amdgcn_mfma_f32_16x16x32_bf16(al[i], bh[j], acc[i][j], 0, 0, 0);
                }
        }
    }
#pragma unroll
    for (int i = 0; i < 2; ++i)
#pragma unroll
        for (int j = 0; j < 2; ++j)
#pragma unroll
            for (int r = 0; r < 4; ++r) {
                int row = tm * 64 + wm * 32 + i * 16 + l4 * 4 + r;
                int col = tn * 64 + wn * 32 + j * 16 + l15;
                float v = beta * acc[i][j][r];
                if (alpha != 0.f) v += alpha * Ab[(size_t)row * K + col];
                Cb[(size_t)row * N + col] = v;
            }
}

// ===== pv3: partials[kc][h][i][d] = sum_{j in chunk} P[h,i,j]*vT[h,d,j] =====
__global__ __launch_bounds__(256) void pv3_mfma(
    const unsigned short* __restrict__ sc, const unsigned short* __restrict__ vT,
    float* __restrict__ part)
{
    __shared__ __align__(16) unsigned short As[64 * 64];
    __shared__ __align__(16) unsigned short Bs[64 * 64];
    const int tid = threadIdx.x;
    const int wave = tid >> 6, lane = tid & 63;
    const int l15 = lane & 15, l4 = lane >> 4;
    const int wm = wave >> 1, wn = wave & 1;
    const int it = blockIdx.x, kc = blockIdx.y, h = blockIdx.z;
    const unsigned short* Ap = sc + (size_t)h * MLM * NSEQ + (size_t)(it * 64) * NSEQ + kc * 512;
    const unsigned short* Bp = vT + (size_t)h * DH * NSEQ + kc * 512;
    const int swzr = (l15 & 7) << 3;
    f32x4 acc[2][2] = {};
    for (int k0 = 0; k0 < 512; k0 += 64) {
        __syncthreads();
#pragma unroll
        for (int c2 = 0; c2 < 2; ++c2) {
            int id = c2 * 256 + tid;
            int row = id >> 3;
            int cg = ((id & 7) ^ (row & 7)) << 3;
            gload_lds16(Ap + (size_t)row * NSEQ + k0 + cg, As + id * 8);
        }
#pragma unroll
        for (int c2 = 0; c2 < 2; ++c2) {
            int id = c2 * 256 + tid;
            int row = id >> 3;
            int cg = ((id & 7) ^ (row & 7)) << 3;
            gload_lds16(Bp + (size_t)row * NSEQ + k0 + cg, Bs + id * 8);
        }
        __syncthreads();
#pragma unroll
        for (int ks = 0; ks < 2; ++ks) {
            bf16x8 af[2], bfv[2];
#pragma unroll
            for (int i = 0; i < 2; ++i)
                af[i] = *reinterpret_cast<const bf16x8*>(
                    &As[(wm * 32 + i * 16 + l15) * 64 + ((ks * 32 + l4 * 8) ^ swzr)]);
#pragma unroll
            for (int j = 0; j < 2; ++j)
                bfv[j] = *reinterpret_cast<const bf16x8*>(
                    &Bs[(wn * 32 + j * 16 + l15) * 64 + ((ks * 32 + l4 * 8) ^ swzr)]);
#pragma unroll
            for (int i = 0; i < 2; ++i)
#pragma unroll
                for (int j = 0; j < 2; ++j)
                    acc[i][j] = __builtin_amdgcn_mfma_f32_16x16x32_bf16(af[i], bfv[j], acc[i][j], 0, 0, 0);
        }
    }
    float* Cp = part + ((size_t)(kc * 8 + h) * MLM + it * 64) * DH;
#pragma unroll
    for (int i = 0; i < 2; ++i)
#pragma unroll
        for (int j = 0; j < 2; ++j)
#pragma unroll
            for (int r = 0; r < 4; ++r)
                Cp[(wm * 32 + i * 16 + l4 * 4 + r) * DH + wn * 32 + j * 16 + l15] = acc[i][j][r];
}

// ===== pv1: attn[n, h*64+d] = sum_j P1[h,n,j] * bbT[h,d,j] =====
__global__ __launch_bounds__(256) void pv1_mfma(
    const unsigned short* __restrict__ sc, const unsigned short* __restrict__ bbT,
    float* __restrict__ attn)
{
    __shared__ __align__(16) unsigned short As[64 * 64];
    __shared__ __align__(16) unsigned short Bs[64 * 64];
    const int tid = threadIdx.x;
    const int wave = tid >> 6, lane = tid & 63;
    const int l15 = lane & 15, l4 = lane >> 4;
    const int wm = wave >> 1, wn = wave & 1;
    const size_t bm = (size_t)blockIdx.x * 64;
    const int h = blockIdx.y;
    const unsigned short* Ap = sc + (size_t)h * NSEQ * MLM + bm * MLM;
    const unsigned short* Bp = bbT + (size_t)h * DH * MLM;
    const int swzr = (l15 & 7) << 3;
    f32x4 acc[2][2] = {};
    for (int k0 = 0; k0 < MLM; k0 += 64) {
        __syncthreads();
#pragma unroll
        for (int c2 = 0; c2 < 2; ++c2) {
            int id = c2 * 256 + tid;
            int row = id >> 3;
            int cg = ((id & 7) ^ (row & 7)) << 3;
            gload_lds16(Ap + (size_t)row * MLM + k0 + cg, As + id * 8);
        }
#pragma unroll
        for (int c2 = 0; c2 < 2; ++c2) {
            int id = c2 * 256 + tid;
            int row = id >> 3;
            int cg = ((id & 7) ^ (row & 7)) << 3;
            gload_lds16(Bp + (size_t)row * MLM + k0 + cg, Bs + id * 8);
        }
        __syncthreads();
#pragma unroll
        for (int ks = 0; ks < 2; ++ks) {
            bf16x8 af[2], bfv[2];
#pragma unroll
            for (int i = 0; i < 2; ++i)
                af[i] = *reinterpret_cast<const bf16x8*>(
                    &As[(wm * 32 + i * 16 + l15) * 64 + ((ks * 32 + l4 * 8) ^ swzr)]);
#pragma unroll
            for (int j = 0; j < 2; ++j)
                bfv[j] = *reinterpret_cast<const bf16x8*>(
                    &Bs[(wn * 32 + j * 16 + l15) * 64 + ((ks * 32 + l4 * 8) ^ swzr)]);
#pragma unroll
            for (int i = 0; i < 2; ++i)
#pragma unroll
                for (int j = 0; j < 2; ++j)
                    acc[i][j] = __builtin_amdgcn_mfma_f32_16x16x32_bf16(af[i], bfv[j], acc[i][j], 0, 0, 0);
        }
    }
#pragma unroll
    for (int i = 0; i < 2; ++i)
#pragma unroll
        for (int j = 0; j < 2; ++j)
#pragma unroll
            for (int r = 0; r < 4; ++r)
                attn[(bm + wm * 32 + i * 16 + l4 * 4 + r) * (size_t)INNER
                     + h * DH + wn * 32 + j * 16 + l15] = acc[i][j][r];
}

// ------------- landmark means from bf16 qkv (+ bf16 copies) -------------
__global__ __launch_bounds__(64) void landmark2_k(
    const unsigned short* __restrict__ qkvbf, float* __restrict__ q_l, float* __restrict__ k_l,
    unsigned short* __restrict__ ql_bf, unsigned short* __restrict__ kls_bf)
{
    int m = blockIdx.x, h = blockIdx.y, d = threadIdx.x;
    float sq = 0.f, sk = 0.f;
    for (int i = 0; i < LSUB; ++i) {
        size_t n = (size_t)m * LSUB + i;
        sq += bf2f(qkvbf[n * QKV_LD + h * DH + d]);
        sk += bf2f(qkvbf[n * QKV_LD + 512 + h * DH + d]);
    }
    float qv = sq * (0.125f / (float)LSUB);
    float kv = sk * (1.f / (float)LSUB);
    size_t o = ((size_t)h * MLM + m) * DH + d;
    q_l[o] = qv; k_l[o] = kv;
    ql_bf[o] = f2bf(qv);
    kls_bf[o] = f2bf(kv * 0.125f);
}

// ------------- v transpose: vT[h][d][n] = qkv_bf[n][1024+h*64+d] -------------
__global__ __launch_bounds__(256) void vt_k(
    const unsigned short* __restrict__ qkvbf, unsigned short* __restrict__ vT)
{
    __shared__ unsigned short tile[128][72];
    const int t = threadIdx.x;
    const int n0 = blockIdx.x * 128;
    const int h = blockIdx.y;
#pragma unroll
    for (int s = 0; s < 4; ++s) {
        int cid = s * 256 + t;
        int row = cid >> 3, ch = (cid & 7) * 8;
        uint4 v = *reinterpret_cast<const uint4*>(
            qkvbf + (size_t)(n0 + row) * QKV_LD + 1024 + h * 64 + ch);
        *reinterpret_cast<uint4*>(&tile[row][ch]) = v;
    }
    __syncthreads();
#pragma unroll
    for (int s = 0; s < 4; ++s) {
        int cid = s * 256 + t;
        int d = cid >> 4, nch = (cid & 15) * 8;
        unsigned short o[8];
#pragma unroll
        for (int i = 0; i < 8; ++i) o[i] = tile[nch + i][d];
        *reinterpret_cast<uint4*>(vT + (size_t)h * DH * NSEQ + (size_t)d * NSEQ + n0 + nch) =
            *reinterpret_cast<uint4*>(o);
    }
}

// ------------- bbT[h][d][j] = bf16(bb[h][j][d]) -------------
__global__ __launch_bounds__(256) void bbt_k(
    const float* __restrict__ bb, unsigned short* __restrict__ bbT)
{
    int idx = blockIdx.x * 256 + threadIdx.x;
    int h = idx >> 14, rem = idx & 16383;
    int d = rem >> 8, j = rem & 255;
    bbT[idx] = f2bf(bb[(h << 14) + (j << 6) + d]);
}

// ------------- a2 = softmax(q_l @ k_l^T) rows -------------
__global__ __launch_bounds__(256) void a2_k(
    const float* __restrict__ q_l, const float* __restrict__ k_l, float* __restrict__ a2)
{
    int i = blockIdx.x, h = blockIdx.y, t = threadIdx.x;
    __shared__ float ql[64];
    __shared__ float red[256];
    if (t < 64) ql[t] = q_l[((size_t)h * MLM + i) * DH + t];
    __syncthreads();
    const float* kr = k_l + ((size_t)h * MLM + t) * DH;
    float s = 0.f;
#pragma unroll
    for (int d = 0; d < 64; d += 4) {
        float4 kv = *reinterpret_cast<const float4*>(kr + d);
        s += kv.x * ql[d] + kv.y * ql[d + 1] + kv.z * ql[d + 2] + kv.w * ql[d + 3];
    }
    red[t] = s; __syncthreads();
    for (int off = 128; off > 0; off >>= 1) { if (t < off) red[t] = fmaxf(red[t], red[t + off]); __syncthreads(); }
    float m = red[0]; __syncthreads();
    float e = __expf(s - m);
    red[t] = e; __syncthreads();
    for (int off = 128; off > 0; off >>= 1) { if (t < off) red[t] += red[t + off]; __syncthreads(); }
    a2[(((size_t)h * MLM + i) * MLM) + t] = e / red[0];
}

// ------------- global max of row/col abs-sums of a2 -------------
__global__ __launch_bounds__(256) void absmax_k(
    const float* __restrict__ a2, unsigned int* __restrict__ scal)
{
    int b = blockIdx.x, t = threadIdx.x;
    __shared__ float red[256];
    float sum = 0.f;
    if (b < 8) {
        const float* r = a2 + ((size_t)b * MLM + t) * MLM;
        for (int j = 0; j < MLM; ++j) sum += fabsf(r[j]);
    } else {
        int h = b - 8;
        for (int i = 0; i < MLM; ++i) sum += fabsf(a2[((size_t)h * MLM + i) * MLM + t]);
    }
    red[t] = sum; __syncthreads();
    for (int off = 128; off > 0; off >>= 1) { if (t < off) red[t] = fmaxf(red[t], red[t + off]); __syncthreads(); }
    if (t == 0) atomicMax(scal + (b < 8 ? 0 : 1), __float_as_uint(red[0]));
}

// ------------- z0 = a2^T / (rmax*cmax) -------------
__global__ __launch_bounds__(256) void zinit_k(
    const float* __restrict__ a2, const unsigned int* __restrict__ scal, float* __restrict__ z)
{
    int idx = blockIdx.x * 256 + threadIdx.x;
    float rmax = __uint_as_float(scal[0]);
    float cmax = __uint_as_float(scal[1]);
    float inv = 1.f / (rmax * cmax);
    int h = idx >> 16, rem = idx & 65535, i = rem >> 8, j = rem & 255;
    z[idx] = a2[((size_t)h << 16) + (j << 8) + i] * inv;
}

// row softmax over 8192 bf16, in place; one block per row
__global__ __launch_bounds__(256) void sm3_k(unsigned short* __restrict__ sc)
{
    __shared__ float red[256];
    const int t = threadIdx.x;
    unsigned short* row = sc + (size_t)blockIdx.x * NSEQ;
    float v[32];
    float lmax = -1e30f;
#pragma unroll
    for (int u = 0; u < 4; ++u) {
        uint4 pk = *reinterpret_cast<const uint4*>(row + t * 32 + u * 8);
        unsigned int w[4] = {pk.x, pk.y, pk.z, pk.w};
#pragma unroll
        for (int q = 0; q < 4; ++q) {
            float lo = bf2f((unsigned short)(w[q] & 0xFFFF));
            float hi = bf2f((unsigned short)(w[q] >> 16));
            v[u * 8 + q * 2 + 0] = lo; v[u * 8 + q * 2 + 1] = hi;
            lmax = fmaxf(lmax, fmaxf(lo, hi));
        }
    }
    red[t] = lmax; __syncthreads();
    for (int off = 128; off > 0; off >>= 1) { if (t < off) red[t] = fmaxf(red[t], red[t + off]); __syncthreads(); }
    float m = red[0]; __syncthreads();
    float s = 0.f;
#pragma unroll
    for (int u = 0; u < 32; ++u) { v[u] = __expf(v[u] - m); s += v[u]; }
    red[t] = s; __syncthreads();
    for (int off = 128; off > 0; off >>= 1) { if (t < off) red[t] += red[t + off]; __syncthreads(); }
    float inv = 1.f / red[0];
#pragma unroll
    for (int u = 0; u < 4; ++u) {
        uint4 pk;
        unsigned int w[4];
#pragma unroll
        for (int q = 0; q < 4; ++q) {
            unsigned int lo = f2bf(v[u * 8 + q * 2 + 0] * inv);
            unsigned int hi = f2bf(v[u * 8 + q * 2 + 1] * inv);
            w[q] = lo | (hi << 16);
        }
        pk.x = w[0]; pk.y = w[1]; pk.z = w[2]; pk.w = w[3];
        *reinterpret_cast<uint4*>(row + t * 32 + u * 8) = pk;
    }
}

// softmax over rows of length 256, one wave per row (4 rows/block)
__global__ __launch_bounds__(256) void sm1_k(unsigned short* __restrict__ sc)
{
    const int row = blockIdx.x * 4 + (threadIdx.x >> 6);
    const int lane = threadIdx.x & 63;
    unsigned short* rp = sc + (size_t)row * MLM;
    uint2 pk = *reinterpret_cast<const uint2*>(rp + lane * 4);
    float x0 = bf2f((unsigned short)(pk.x & 0xFFFF));
    float x1 = bf2f((unsigned short)(pk.x >> 16));
    float x2 = bf2f((unsigned short)(pk.y & 0xFFFF));
    float x3 = bf2f((unsigned short)(pk.y >> 16));
    float m = fmaxf(fmaxf(x0, x1), fmaxf(x2, x3));
    for (int off = 32; off > 0; off >>= 1) m = fmaxf(m, __shfl_xor(m, off));
    x0 = __expf(x0 - m); x1 = __expf(x1 - m); x2 = __expf(x2 - m); x3 = __expf(x3 - m);
    float s = x0 + x1 + x2 + x3;
    for (int off = 32; off > 0; off >>= 1) s += __shfl_xor(s, off);
    float inv = 1.f / s;
    unsigned int l0 = f2bf(x0 * inv), h0 = f2bf(x1 * inv);
    unsigned int l1 = f2bf(x2 * inv), h1 = f2bf(x3 * inv);
    pk.x = l0 | (h0 << 16); pk.y = l1 | (h1 << 16);
    *reinterpret_cast<uint2*>(rp + lane * 4) = pk;
}

__global__ __launch_bounds__(256) void red3_k(
    const float* __restrict__ part, float* __restrict__ a3v)
{
    int o = blockIdx.x * 256 + threadIdx.x;
    float s = 0.f;
#pragma unroll
    for (int kc = 0; kc < 16; ++kc) s += part[(size_t)kc * 131072 + o];
    a3v[o] = s;
}

// ------------- depthwise conv residual add (register sliding window) -------------
__global__ __launch_bounds__(256) void conv_res2_k(
    const unsigned short* __restrict__ qkvbf, const float* __restrict__ kern,
    float* __restrict__ attn)
{
    const int t = threadIdx.x;
    const int cg = (blockIdx.y * 64 + (t & 63)) * 4;
    const int n0 = blockIdx.x * 32 + (t >> 6) * 8;
    const int h = cg >> 6;
    float kr[KCONV];
#pragma unroll
    for (int i = 0; i < KCONV; ++i) kr[i] = kern[h * KCONV + i];
    float acc[8][4] = {};
#pragma unroll
    for (int r = 0; r < 40; ++r) {
        int nn = n0 + r - 16;
        float v0 = 0.f, v1 = 0.f, v2 = 0.f, v3 = 0.f;
        if (nn >= 0 && nn < NSEQ) {
            ushort4 u = *reinterpret_cast<const ushort4*>(qkvbf + (size_t)nn * QKV_LD + 1024 + cg);
            v0 = bf2f(u.x); v1 = bf2f(u.y); v2 = bf2f(u.z); v3 = bf2f(u.w);
        }
#pragma unroll
        for (int j = 0; j < 8; ++j) {
            int tt = r - j;
            if (tt >= 0 && tt < KCONV) {
                acc[j][0] += kr[tt] * v0; acc[j][1] += kr[tt] * v1;
                acc[j][2] += kr[tt] * v2; acc[j][3] += kr[tt] * v3;
            }
        }
    }
#pragma unroll
    for (int j = 0; j < 8; ++j) {
        float4* p = reinterpret_cast<float4*>(attn + (size_t)(n0 + j) * INNER + cg);
        float4 c = *p;
        c.x += acc[j][0]; c.y += acc[j][1]; c.z += acc[j][2]; c.w += acc[j][3];
        *p = c;
    }
}

// ------------- sparse edge scores (bf16 fused qke) + segment sum -------------
__global__ __launch_bounds__(256) void edge_k(
    const unsigned short* __restrict__ qke,
    const int* __restrict__ rows, const int* __restrict__ cols,
    const float* __restrict__ vals, float* __restrict__ A_raw)
{
    int e = blockIdx.x * 4 + (threadIdx.x >> 6);
    int lane = threadIdx.x & 63;
    int r = rows[e], c = cols[e];
    const unsigned short* qr = qke + (size_t)r * 512;
    const unsigned short* kr = qke + (size_t)c * 512 + 256;
    ushort4 a = *reinterpret_cast<const ushort4*>(qr + lane * 4);
    ushort4 b = *reinterpret_cast<const ushort4*>(kr + lane * 4);
    float s = bf2f(a.x) * bf2f(b.x) + bf2f(a.y) * bf2f(b.y)
            + bf2f(a.z) * bf2f(b.z) + bf2f(a.w) * bf2f(b.w);
    for (int off = 32; off > 0; off >>= 1) s += __shfl_down(s, off, 64);
    if (lane == 0) atomicAdd(&A_raw[r], s * vals[e] * 0.0625f);
}

// ------------- alpha = softmax(A_raw) -------------
__global__ __launch_bounds__(1024) void alpha_k(
    const float* __restrict__ A_raw, float* __restrict__ alpha)
{
    __shared__ float red[1024];
    int t = threadIdx.x;
    float m = -1e30f;
    for (int i = t; i < NSEQ; i += 1024) m = fmaxf(m, A_raw[i]);
    red[t] = m; __syncthreads();
    for (int off = 512; off > 0; off >>= 1) { if (t < off) red[t] = fmaxf(red[t], red[t + off]); __syncthreads(); }
    m = red[0]; __syncthreads();
    float s = 0.f;
    for (int i = t; i < NSEQ; i += 1024) s += __expf(A_raw[i] - m);
    red[t] = s; __syncthreads();
    for (int off = 512; off > 0; off >>= 1) { if (t < off) red[t] += red[t + off]; __syncthreads(); }
    float inv = 1.f / red[0];
    for (int i = t; i < NSEQ; i += 1024) alpha[i] = __expf(A_raw[i] - m) * inv;
}

// ------------- final gated blend -------------
__global__ __launch_bounds__(256) void final_k(
    const float* __restrict__ alpha, const float* __restrict__ value,
    const float* __restrict__ enc, float* __restrict__ xo)
{
    size_t idx = (size_t)blockIdx.x * 256 + threadIdx.x;
    int n = (int)(idx >> 9);
    float xl = alpha[n] * value[idx];
    float w = 1.f / (1.f + __expf(xl));
    float sq = w * w;
    xo[idx] = xl * 2.f * sq + 2.f * enc[idx] * (1.f - sq);
}

extern "C" void kernel_launch(void* const* d_in, const int* in_sizes, int n_in,
                              void* d_out, int out_size, void* d_ws, size_t ws_size,
                              hipStream_t stream)
{
    const float* dense      = (const float*)d_in[0];
    const int*   adj_rows   = (const int*)d_in[1];
    const int*   adj_cols   = (const int*)d_in[2];
    const float* adj_vals   = (const float*)d_in[3];
    const float* wq         = (const float*)d_in[4];
    const float* wk         = (const float*)d_in[5];
    const float* w_qkv      = (const float*)d_in[6];
    const float* w_out      = (const float*)d_in[7];
    const float* b_out      = (const float*)d_in[8];
    const float* res_kernel = (const float*)d_in[9];
    const float* wv_w       = (const float*)d_in[10];
    const float* wv_b       = (const float*)d_in[11];
    const int E = in_sizes[1];

    float* ws  = (float*)d_ws;
    float* out = (float*)d_out;
    float* A_raw = out + (size_t)NSEQ * DDIM;

    unsigned short* qkv_bf   = (unsigned short*)(ws + OFF_QKVBF);
    unsigned short* vT       = (unsigned short*)(ws + OFF_VT);
    unsigned short* sc       = (unsigned short*)(ws + OFF_SC);    // sc3 then sc1
    unsigned short* qke_bf   = (unsigned short*)(ws + OFF_QKE);
    unsigned short* attn_bf  = (unsigned short*)(ws + OFF_ATTNBF);
    unsigned short* dense_bf = (unsigned short*)(ws + OFF_DENSEBF);
    unsigned short* wqkv_bf  = (unsigned short*)(ws + OFF_WQKVBF);
    unsigned short* wout_bf  = (unsigned short*)(ws + OFF_WOUTBF);
    unsigned short* wqkT_bf  = (unsigned short*)(ws + OFF_WQKT);
    unsigned short* wv_bf    = (unsigned short*)(ws + OFF_WVBF);
    unsigned short* ql_bf    = (unsigned short*)(ws + OFF_QLBF);
    unsigned short* kls_bf   = (unsigned short*)(ws + OFF_KLSBF);
    unsigned short* bbT_bf   = (unsigned short*)(ws + OFF_BBT);
    unsigned short* enc_bf   = (unsigned short*)(ws + OFF_ENCBF);

    hipMemsetAsync(A_raw, 0, NSEQ * sizeof(float), stream);
    hipMemsetAsync(ws + OFF_SCAL, 0, 2 * sizeof(unsigned int), stream);

    // ---- input conversions ----
    cvt_bf16_k<<<(NSEQ * DDIM) / 2048, 256, 0, stream>>>(dense, dense_bf);
    cvt_bf16_k<<<(1536 * DDIM) / 2048, 256, 0, stream>>>(w_qkv, wqkv_bf);

    // qkv = dense @ w_qkv^T  -> bf16 only
    gemm_mfma_ntb<<<dim3(NSEQ / 64, 1536 / 128, 1), 256, 0, stream>>>(
        dense_bf, DDIM, 0, wqkv_bf, DDIM, 0, nullptr, qkv_bf, QKV_LD, 0,
        DDIM, nullptr, nullptr);

    landmark2_k<<<dim3(MLM, HEADS), 64, 0, stream>>>(
        qkv_bf, ws + OFF_QL, ws + OFF_KL, ql_bf, kls_bf);
    vt_k<<<dim3(NSEQ / 128, HEADS), 256, 0, stream>>>(qkv_bf, vT);

    // ---- a3 pipeline ----
    gemm_mfma_ntb<<<dim3(MLM / 64, NSEQ / 128, HEADS), 256, 0, stream>>>(
        ql_bf, DH, (size_t)MLM * DH, qkv_bf + 512, QKV_LD, DH,
        nullptr, sc, NSEQ, (size_t)MLM * NSEQ, DH, nullptr, nullptr);
    sm3_k<<<HEADS * MLM, 256, 0, stream>>>(sc);
    pv3_mfma<<<dim3(4, 16, HEADS), 256, 0, stream>>>(sc, vT, ws + OFF_ATTN);
    red3_k<<<512, 256, 0, stream>>>(ws + OFF_ATTN, ws + OFF_A3V);

    a2_k<<<dim3(MLM, HEADS), 256, 0, stream>>>(ws + OFF_QL, ws + OFF_KL, ws + OFF_A2);
    absmax_k<<<16, 256, 0, stream>>>(ws + OFF_A2, (unsigned int*)(ws + OFF_SCAL));
    zinit_k<<<(HEADS * MLM * MLM) / 256, 256, 0, stream>>>(
        ws + OFF_A2, (const unsigned int*)(ws + OFF_SCAL), ws + OFF_Z0);

    // pinv iterations via MFMA hi/lo split (fp32-accurate)
    for (int it = 0; it < 6; ++it) {
        float* zin  = ws + ((it & 1) ? OFF_Z1 : OFF_Z0);
        float* zout = ws + ((it & 1) ? OFF_Z0 : OFF_Z1);
        bmm_split<<<dim3(16, HEADS), 256, 0, stream>>>(ws + OFF_A2, zin, ws + OFF_P,
            256, 256, 4, 65536, 65536, 65536, 0.f, 1.f);
        bmm_split<<<dim3(16, HEADS), 256, 0, stream>>>(ws + OFF_P, ws + OFF_P, ws + OFF_T1,
            256, 256, 4, 65536, 65536, 65536, 7.f, -1.f);
        bmm_split<<<dim3(16, HEADS), 256, 0, stream>>>(ws + OFF_P, ws + OFF_T1, ws + OFF_T2,
            256, 256, 4, 65536, 65536, 65536, 15.f, -1.f);
        bmm_split<<<dim3(16, HEADS), 256, 0, stream>>>(zin, ws + OFF_T2, zout,
            256, 256, 4, 65536, 65536, 65536, 3.25f, -0.25f);
    }
    // bb = z_final @ a3v
    bmm_split<<<dim3(4, HEADS), 256, 0, stream>>>(ws + OFF_Z0, ws + OFF_A3V, ws + OFF_BB,
        256, 64, 1, 65536, 16384, 16384, 0.f, 1.f);
    bbt_k<<<512, 256, 0, stream>>>(ws + OFF_BB, bbT_bf);

    // ---- a1 pipeline (all 8 heads) ----
    gemm_mfma_ntb<<<dim3(NSEQ / 64, MLM / 128, HEADS), 256, 0, stream>>>(
        qkv_bf, QKV_LD, DH, kls_bf, DH, (size_t)MLM * DH,
        nullptr, sc, MLM, (size_t)NSEQ * MLM, DH, nullptr, nullptr);
    sm1_k<<<HEADS * NSEQ / 4, 256, 0, stream>>>(sc);
    pv1_mfma<<<dim3(NSEQ / 64, HEADS), 256, 0, stream>>>(sc, bbT_bf, ws + OFF_ATTN);
    conv_res2_k<<<dim3(NSEQ / 32, 2), 256, 0, stream>>>(qkv_bf, res_kernel, ws + OFF_ATTN);

    // ---- attn + late weights to bf16 ----
    cvt_bf16_k<<<(NSEQ * INNER) / 2048, 256, 0, stream>>>(ws + OFF_ATTN, attn_bf);
    cvt_bf16_k<<<(DDIM * INNER) / 2048, 256, 0, stream>>>(w_out, wout_bf);
    tcvt_bf16_k<<<(WP * DDIM + 255) / 256, 256, 0, stream>>>(wq, wqkT_bf, DDIM, WP);
    tcvt_bf16_k<<<(WP * DDIM + 255) / 256, 256, 0, stream>>>(wk, wqkT_bf + 256 * 512, DDIM, WP);
    cvt_bf16_k<<<(DDIM * DDIM) / 2048, 256, 0, stream>>>(wv_w, wv_bf);

    // enc = attn @ w_out^T + b_out + dense  (fp32 + bf16)
    gemm_mfma_ntb<<<dim3(NSEQ / 64, DDIM / 128, 1), 256, 0, stream>>>(
        attn_bf, INNER, 0, wout_bf, INNER, 0, ws + OFF_ENC, enc_bf, DDIM, 0,
        INNER, b_out, dense);

    // qke = enc @ [wq|wk] -> bf16
    gemm_mfma_ntb<<<dim3(NSEQ / 64, 512 / 128, 1), 256, 0, stream>>>(
        enc_bf, DDIM, 0, wqkT_bf, DDIM, 0, nullptr, qke_bf, 512, 0,
        DDIM, nullptr, nullptr);

    edge_k<<<E / 4, 256, 0, stream>>>(qke_bf, adj_rows, adj_cols, adj_vals, A_raw);
    alpha_k<<<1, 1024, 0, stream>>>(A_raw, ws + OFF_ALPHA);

    // value = dense @ wv_w^T + wv_b
    gemm_mfma_ntb<<<dim3(NSEQ / 64, DDIM / 128, 1), 256, 0, stream>>>(
        dense_bf, DDIM, 0, wv_bf, DDIM, 0, ws + OFF_VAL, nullptr, DDIM, 0,
        DDIM, wv_b, nullptr);

    final_k<<<(NSEQ * DDIM) / 256, 256, 0, stream>>>(
        ws + OFF_ALPHA, ws + OFF_VAL, ws + OFF_ENC, out);
}

// Round 6
// 586.126 us; speedup vs baseline: 5.1346x; 1.0901x over previous
//
#include <hip/hip_runtime.h>
#include <hip/hip_bf16.h>

// Problem constants (fixed by reference)
#define NSEQ 8192
#define DDIM 512
#define HEADS 8
#define DH 64
#define MLM 256
#define LSUB 32          // NSEQ / MLM
#define WP 256
#define KCONV 33
#define INNER 512        // HEADS*DH
#define QKV_LD 1536

// ---------------- workspace layout (float offsets) ----------------
static const size_t OFF_QKVBF  = 0;          // bf16 8192*1536 = 6,291,456 fl
static const size_t OFF_VT     = 6291456;    // bf16 8*64*8192 = 2,097,152 fl
static const size_t OFF_SC     = 8388608;    // bf16 exp-scores 8*256*8192 = 8,388,608 fl
// pinv overlay inside SC (alive only after scores consumed):
static const size_t OFF_A2     = 8388608;
static const size_t OFF_Z0     = 8912896;
static const size_t OFF_Z1     = 9437184;
static const size_t OFF_P      = 9961472;
static const size_t OFF_T1     = 10485760;
static const size_t OFF_T2     = 11010048;
// late overlays inside SC:
static const size_t OFF_QKE    = 10485760;   // bf16 8192*512 = 2,097,152 fl
static const size_t OFF_ATTNBF = 12582912;   // bf16 8192*512
static const size_t OFF_ATTN   = 16777216;   // fp32 attn (also pv3 partials early)
// enc overlays dead qkv_bf region:
static const size_t OFF_ENC    = 0;          // fp32 8192*512
static const size_t OFF_ENCBF  = 4194304;    // bf16 8192*512
static const size_t OFF_VAL    = 6291456;    // fp32 8192*512 (vT dead)
// tail region:
static const size_t OFF_DENSEBF= 20971520;   // bf16 8192*512
static const size_t OFF_WQKVBF = 23068672;   // bf16 1536*512
static const size_t OFF_WOUTBF = 23461888;   // bf16 512*512
static const size_t OFF_WQKT   = 23592960;   // bf16 512*512 (wq^T | wk^T)
static const size_t OFF_WVBF   = 23724032;   // bf16 512*512
static const size_t OFF_QL     = 23855104;   // fp32 8*256*64
static const size_t OFF_KL     = 23986176;   // fp32 8*256*64
static const size_t OFF_QLBF   = 24117248;   // bf16 8*256*64
static const size_t OFF_KLSBF  = 24182784;   // bf16 8*256*64 (k_l * 0.125)
static const size_t OFF_A3V    = 24248320;   // fp32 8*256*64
static const size_t OFF_BB     = 24379392;   // fp32 8*256*64
static const size_t OFF_BBT    = 24510464;   // bf16 8*64*256
static const size_t OFF_SCAL   = 24576000;   // 2 uints
static const size_t OFF_ALPHA  = 24576016;   // 8192 fp32
static const size_t OFF_DEN3   = 24584208;   // 2048 fp32

__device__ __forceinline__ float bf2f(unsigned short u) {
    return __uint_as_float(((unsigned int)u) << 16);
}
__device__ __forceinline__ unsigned short f2bf(float x) {
    unsigned int u = __float_as_uint(x);
    u += 0x7FFFu + ((u >> 16) & 1u);   // RNE
    return (unsigned short)(u >> 16);
}

typedef __attribute__((ext_vector_type(8))) short bf16x8;
typedef __attribute__((ext_vector_type(4))) float f32x4;

__device__ __forceinline__ void gload_lds16(const void* g, void* l) {
    __builtin_amdgcn_global_load_lds(
        (const __attribute__((address_space(1))) unsigned int*)g,
        (__attribute__((address_space(3))) unsigned int*)l, 16, 0, 0);
}

// ---------------- fp32 -> bf16 conversion (8 elems/thread) ----------------
__global__ __launch_bounds__(256) void cvt_bf16_k(
    const float* __restrict__ in, unsigned short* __restrict__ out)
{
    size_t i = ((size_t)blockIdx.x * 256 + threadIdx.x) * 8;
    float4 a = *reinterpret_cast<const float4*>(in + i);
    float4 b = *reinterpret_cast<const float4*>(in + i + 4);
    uint4 p;
    p.x = (unsigned int)f2bf(a.x) | ((unsigned int)f2bf(a.y) << 16);
    p.y = (unsigned int)f2bf(a.z) | ((unsigned int)f2bf(a.w) << 16);
    p.z = (unsigned int)f2bf(b.x) | ((unsigned int)f2bf(b.y) << 16);
    p.w = (unsigned int)f2bf(b.z) | ((unsigned int)f2bf(b.w) << 16);
    *reinterpret_cast<uint4*>(out + i) = p;
}

// ---------------- transpose + convert: out[c][r] = bf16(in[r][c]) ----------
__global__ __launch_bounds__(256) void tcvt_bf16_k(
    const float* __restrict__ in, unsigned short* __restrict__ out, int R, int C)
{
    int idx = blockIdx.x * 256 + threadIdx.x;
    if (idx < R * C) {
        int oc = idx / R;
        int orow = idx % R;
        out[idx] = f2bf(in[(size_t)orow * C + oc]);
    }
}

// ===== batched bf16 MFMA NT GEMM: C[b,m,n] = sum_k A[b,m,k]*B[b,n,k] =====
// tile 64x128, BK=64, 256 threads = 4 waves (2x2), wave computes 32x64.
__global__ __launch_bounds__(256) void gemm_mfma_ntb(
    const unsigned short* __restrict__ A, int lda, size_t sA,
    const unsigned short* __restrict__ B, int ldb, size_t sB,
    float* __restrict__ C, unsigned short* __restrict__ Cbf, int ldc, size_t sC,
    int K, const float* __restrict__ bias, const float* __restrict__ addsrc,
    int expmode)
{
    __shared__ __align__(16) unsigned short As[64 * 64];
    __shared__ __align__(16) unsigned short Bs[128 * 64];
    const int tid = threadIdx.x;
    const int wave = tid >> 6, lane = tid & 63;
    const int l15 = lane & 15, l4 = lane >> 4;
    const int wm = wave >> 1, wn = wave & 1;
    const size_t bm = (size_t)blockIdx.x * 64;
    const size_t bn = (size_t)blockIdx.y * 128;
    const int z = blockIdx.z;
    const unsigned short* Ab = A + (size_t)z * sA;
    const unsigned short* Bb = B + (size_t)z * sB;
    const int swzr = (l15 & 7) << 3;
    f32x4 acc[2][4] = {};
    for (int k0 = 0; k0 < K; k0 += 64) {
        __syncthreads();
#pragma unroll
        for (int c2 = 0; c2 < 2; ++c2) {       // A: 64x64 = 512 x 16B
            int id = c2 * 256 + tid;
            int row = id >> 3;
            int cg = ((id & 7) ^ (row & 7)) << 3;
            gload_lds16(Ab + (bm + row) * (size_t)lda + k0 + cg, As + id * 8);
        }
#pragma unroll
        for (int c2 = 0; c2 < 4; ++c2) {       // B: 128x64 = 1024 x 16B
            int id = c2 * 256 + tid;
            int row = id >> 3;
            int cg = ((id & 7) ^ (row & 7)) << 3;
            gload_lds16(Bb + (bn + row) * (size_t)ldb + k0 + cg, Bs + id * 8);
        }
        __syncthreads();
#pragma unroll
        for (int c = 0; c < 2; ++c) {
            bf16x8 af[2], bfv[4];
#pragma unroll
            for (int i = 0; i < 2; ++i)
                af[i] = *reinterpret_cast<const bf16x8*>(
                    &As[(wm * 32 + i * 16 + l15) * 64 + ((c * 32 + l4 * 8) ^ swzr)]);
#pragma unroll
            for (int j = 0; j < 4; ++j)
                bfv[j] = *reinterpret_cast<const bf16x8*>(
                    &Bs[(wn * 64 + j * 16 + l15) * 64 + ((c * 32 + l4 * 8) ^ swzr)]);
#pragma unroll
            for (int i = 0; i < 2; ++i)
#pragma unroll
                for (int j = 0; j < 4; ++j)
                    acc[i][j] = __builtin_amdgcn_mfma_f32_16x16x32_bf16(
                        af[i], bfv[j], acc[i][j], 0, 0, 0);
        }
    }
    float* Cz = C ? C + (size_t)z * sC : nullptr;
    unsigned short* Cbz = Cbf ? Cbf + (size_t)z * sC : nullptr;
#pragma unroll
    for (int i = 0; i < 2; ++i)
#pragma unroll
        for (int j = 0; j < 4; ++j)
#pragma unroll
            for (int r = 0; r < 4; ++r) {
                size_t row = bm + wm * 32 + i * 16 + l4 * 4 + r;
                size_t col = bn + wn * 64 + j * 16 + l15;
                float v = acc[i][j][r];
                if (bias)   v += bias[col];
                if (addsrc) v += addsrc[row * (size_t)ldc + col];
                if (expmode) v = __expf(v);
                if (Cz)  Cz[row * (size_t)ldc + col] = v;
                if (Cbz) Cbz[row * (size_t)ldc + col] = f2bf(v);
            }
}

// ===== fp32-accurate batched NN GEMM via bf16 hi/lo split MFMA =====
__global__ __launch_bounds__(256) void bmm_split(
    const float* __restrict__ A, const float* __restrict__ B, float* __restrict__ C,
    int K, int N, int ntn, size_t sA, size_t sB, size_t sC, float alpha, float beta)
{
    __shared__ __align__(16) unsigned short Ah[64 * 72], Al[64 * 72];
    __shared__ __align__(16) unsigned short Bh[64 * 72], Bl[64 * 72];
    const int tid = threadIdx.x;
    const int wave = tid >> 6, lane = tid & 63;
    const int l15 = lane & 15, l4 = lane >> 4;
    const int wm = wave >> 1, wn = wave & 1;
    const int b = blockIdx.y;
    const int tm = blockIdx.x / ntn, tn = blockIdx.x % ntn;
    const float* Ab = A + (size_t)b * sA;
    const float* Bb = B + (size_t)b * sB;
    float* Cb = C + (size_t)b * sC;
    const int arow = tid >> 2, akq = (tid & 3) * 16;
    const int kp = tid & 31, nc = tid >> 5;
    f32x4 acc[2][2] = {};
    for (int k0 = 0; k0 < K; k0 += 64) {
        __syncthreads();
#pragma unroll
        for (int s = 0; s < 4; ++s) {
            float4 a = *reinterpret_cast<const float4*>(Ab + (size_t)(tm * 64 + arow) * K + k0 + akq + s * 4);
            unsigned short h0 = f2bf(a.x), h1 = f2bf(a.y), h2 = f2bf(a.z), h3 = f2bf(a.w);
            unsigned short g0 = f2bf(a.x - bf2f(h0)), g1 = f2bf(a.y - bf2f(h1));
            unsigned short g2 = f2bf(a.z - bf2f(h2)), g3 = f2bf(a.w - bf2f(h3));
            uint2 ph, pl;
            ph.x = h0 | ((unsigned int)h1 << 16); ph.y = h2 | ((unsigned int)h3 << 16);
            pl.x = g0 | ((unsigned int)g1 << 16); pl.y = g2 | ((unsigned int)g3 << 16);
            *reinterpret_cast<uint2*>(&Ah[arow * 72 + akq + s * 4]) = ph;
            *reinterpret_cast<uint2*>(&Al[arow * 72 + akq + s * 4]) = pl;
        }
#pragma unroll
        for (int s = 0; s < 2; ++s) {
            int cb = nc * 8 + s * 4;
            float4 b0 = *reinterpret_cast<const float4*>(Bb + (size_t)(k0 + 2 * kp) * N + tn * 64 + cb);
            float4 b1 = *reinterpret_cast<const float4*>(Bb + (size_t)(k0 + 2 * kp + 1) * N + tn * 64 + cb);
            float x0[4] = {b0.x, b0.y, b0.z, b0.w};
            float x1[4] = {b1.x, b1.y, b1.z, b1.w};
#pragma unroll
            for (int c = 0; c < 4; ++c) {
                unsigned short h0 = f2bf(x0[c]), h1 = f2bf(x1[c]);
                unsigned short g0 = f2bf(x0[c] - bf2f(h0)), g1 = f2bf(x1[c] - bf2f(h1));
                *reinterpret_cast<unsigned int*>(&Bh[(cb + c) * 72 + 2 * kp]) =
                    h0 | ((unsigned int)h1 << 16);
                *reinterpret_cast<unsigned int*>(&Bl[(cb + c) * 72 + 2 * kp]) =
                    g0 | ((unsigned int)g1 << 16);
            }
        }
        __syncthreads();
#pragma unroll
        for (int ks = 0; ks < 2; ++ks) {
            bf16x8 ah[2], al[2], bh[2], bl[2];
#pragma unroll
            for (int i = 0; i < 2; ++i) {
                int rr = (wm * 32 + i * 16 + l15) * 72 + ks * 32 + l4 * 8;
                ah[i] = *reinterpret_cast<const bf16x8*>(&Ah[rr]);
                al[i] = *reinterpret_cast<const bf16x8*>(&Al[rr]);
            }
#pragma unroll
            for (int j = 0; j < 2; ++j) {
                int rr = (wn * 32 + j * 16 + l15) * 72 + ks * 32 + l4 * 8;
                bh[j] = *reinterpret_cast<const bf16x8*>(&Bh[rr]);
                bl[j] = *reinterpret_cast<const bf16x8*>(&Bl[rr]);
            }
#pragma unroll
            for (int i = 0; i < 2; ++i)
#pragma unroll
                for (int j = 0; j < 2; ++j) {
                    acc[i][j] = __builtin_amdgcn_mfma_f32_16x16x32_bf16(ah[i], bh[j], acc[i][j], 0, 0, 0);
                    acc[i][j] = __builtin_amdgcn_mfma_f32_16x16x32_bf16(ah[i], bl[j], acc[i][j], 0, 0, 0);
                    acc[i][j] = __builtin_amdgcn_mfma_f32_16x16x32_bf16(al[i], bh[j], acc[i][j], 0, 0, 0);
                }
        }
    }
#pragma unroll
    for (int i = 0; i < 2; ++i)
#pragma unroll
        for (int j = 0; j < 2; ++j)
#pragma unroll
            for (int r = 0; r < 4; ++r) {
                int row = tm * 64 + wm * 32 + i * 16 + l4 * 4 + r;
                int col = tn * 64 + wn * 32 + j * 16 + l15;
                float v = beta * acc[i][j][r];
                if (alpha != 0.f) v += alpha * Ab[(size_t)row * K + col];
                Cb[(size_t)row * N + col] = v;
            }
}

// ===== pv3: partials[kc][h][i][d] = sum_{j in chunk} P[h,i,j]*vT[h,d,j] =====
__global__ __launch_bounds__(256) void pv3_mfma(
    const unsigned short* __restrict__ sc, const unsigned short* __restrict__ vT,
    float* __restrict__ part)
{
    __shared__ __align__(16) unsigned short As[64 * 64];
    __shared__ __align__(16) unsigned short Bs[64 * 64];
    const int tid = threadIdx.x;
    const int wave = tid >> 6, lane = tid & 63;
    const int l15 = lane & 15, l4 = lane >> 4;
    const int wm = wave >> 1, wn = wave & 1;
    const int it = blockIdx.x, kc = blockIdx.y, h = blockIdx.z;
    const unsigned short* Ap = sc + (size_t)h * MLM * NSEQ + (size_t)(it * 64) * NSEQ + kc * 512;
    const unsigned short* Bp = vT + (size_t)h * DH * NSEQ + kc * 512;
    const int swzr = (l15 & 7) << 3;
    f32x4 acc[2][2] = {};
    for (int k0 = 0; k0 < 512; k0 += 64) {
        __syncthreads();
#pragma unroll
        for (int c2 = 0; c2 < 2; ++c2) {
            int id = c2 * 256 + tid;
            int row = id >> 3;
            int cg = ((id & 7) ^ (row & 7)) << 3;
            gload_lds16(Ap + (size_t)row * NSEQ + k0 + cg, As + id * 8);
        }
#pragma unroll
        for (int c2 = 0; c2 < 2; ++c2) {
            int id = c2 * 256 + tid;
            int row = id >> 3;
            int cg = ((id & 7) ^ (row & 7)) << 3;
            gload_lds16(Bp + (size_t)row * NSEQ + k0 + cg, Bs + id * 8);
        }
        __syncthreads();
#pragma unroll
        for (int ks = 0; ks < 2; ++ks) {
            bf16x8 af[2], bfv[2];
#pragma unroll
            for (int i = 0; i < 2; ++i)
                af[i] = *reinterpret_cast<const bf16x8*>(
                    &As[(wm * 32 + i * 16 + l15) * 64 + ((ks * 32 + l4 * 8) ^ swzr)]);
#pragma unroll
            for (int j = 0; j < 2; ++j)
                bfv[j] = *reinterpret_cast<const bf16x8*>(
                    &Bs[(wn * 32 + j * 16 + l15) * 64 + ((ks * 32 + l4 * 8) ^ swzr)]);
#pragma unroll
            for (int i = 0; i < 2; ++i)
#pragma unroll
                for (int j = 0; j < 2; ++j)
                    acc[i][j] = __builtin_amdgcn_mfma_f32_16x16x32_bf16(af[i], bfv[j], acc[i][j], 0, 0, 0);
        }
    }
    float* Cp = part + ((size_t)(kc * 8 + h) * MLM + it * 64) * DH;
#pragma unroll
    for (int i = 0; i < 2; ++i)
#pragma unroll
        for (int j = 0; j < 2; ++j)
#pragma unroll
            for (int r = 0; r < 4; ++r)
                Cp[(wm * 32 + i * 16 + l4 * 4 + r) * DH + wn * 32 + j * 16 + l15] = acc[i][j][r];
}

// ===== fused a1: per block 64 q-rows x 256 landmarks, exp-softmax + PV =====
__global__ __launch_bounds__(256) void a1_fused(
    const unsigned short* __restrict__ qkvbf,
    const unsigned short* __restrict__ kls,     // [h][256][64] (k_l * 0.125)
    const unsigned short* __restrict__ bbT,     // [h][64][256]
    float* __restrict__ attn)
{
    __shared__ __align__(16) unsigned short lds[20480];  // A 0..4096, B/P 4096..20480
    __shared__ float den[2][64];
    const int tid = threadIdx.x;
    const int wave = tid >> 6, lane = tid & 63;
    const int l15 = lane & 15, l4 = lane >> 4;
    const int wm = wave >> 1, wn = wave & 1;
    const int n0 = blockIdx.x * 64;
    const int h = blockIdx.y;
    const int swzr = (l15 & 7) << 3;

    // stage A (q rows 64x64) and B (kls 256x64)
#pragma unroll
    for (int c2 = 0; c2 < 2; ++c2) {
        int id = c2 * 256 + tid;
        int row = id >> 3, cg = ((id & 7) ^ (row & 7)) << 3;
        gload_lds16(qkvbf + (size_t)(n0 + row) * QKV_LD + h * DH + cg, lds + id * 8);
    }
#pragma unroll
    for (int c2 = 0; c2 < 8; ++c2) {
        int id = c2 * 256 + tid;
        int row = id >> 3, cg = ((id & 7) ^ (row & 7)) << 3;
        gload_lds16(kls + (size_t)h * (MLM * DH) + row * DH + cg, lds + 4096 + id * 8);
    }
    __syncthreads();
    // QK: S = q . kls^T  (64 x 256), wave tile 32 x 128
    f32x4 acc[2][8] = {};
#pragma unroll
    for (int c = 0; c < 2; ++c) {
        bf16x8 af[2], bv[8];
#pragma unroll
        for (int i = 0; i < 2; ++i) {
            int row = wm * 32 + i * 16 + l15;
            af[i] = *reinterpret_cast<const bf16x8*>(&lds[row * 64 + ((c * 32 + l4 * 8) ^ swzr)]);
        }
#pragma unroll
        for (int j = 0; j < 8; ++j) {
            int brow = wn * 128 + j * 16 + l15;
            bv[j] = *reinterpret_cast<const bf16x8*>(&lds[4096 + brow * 64 + ((c * 32 + l4 * 8) ^ swzr)]);
        }
#pragma unroll
        for (int i = 0; i < 2; ++i)
#pragma unroll
            for (int j = 0; j < 8; ++j)
                acc[i][j] = __builtin_amdgcn_mfma_f32_16x16x32_bf16(af[i], bv[j], acc[i][j], 0, 0, 0);
    }
    __syncthreads();   // all A/B reads complete
    // exp (scores are tiny: no max needed), row sums, write P (swizzled)
    float rs[2][4] = {};
#pragma unroll
    for (int i = 0; i < 2; ++i)
#pragma unroll
        for (int j = 0; j < 8; ++j)
#pragma unroll
            for (int r = 0; r < 4; ++r) {
                float e = __expf(acc[i][j][r]);
                rs[i][r] += e;
                int row = wm * 32 + i * 16 + l4 * 4 + r;
                int col = wn * 128 + j * 16 + l15;
                lds[4096 + row * 256 + (col ^ ((row & 7) << 3))] = f2bf(e);
            }
#pragma unroll
    for (int i = 0; i < 2; ++i)
#pragma unroll
        for (int r = 0; r < 4; ++r) {
            float s = rs[i][r];
            s += __shfl_xor(s, 1); s += __shfl_xor(s, 2);
            s += __shfl_xor(s, 4); s += __shfl_xor(s, 8);
            if (l15 == 0) den[wn][wm * 32 + i * 16 + l4 * 4 + r] = s;
        }
    __syncthreads();
    // PV: out = P @ bb  (64 x 64), wave tile 32 x 32; B frags direct from L2
    f32x4 acc2[2][2] = {};
    const unsigned short* bbh = bbT + (size_t)h * DH * MLM;
#pragma unroll
    for (int k0 = 0; k0 < 256; k0 += 32) {
        bf16x8 af2[2], bv2[2];
#pragma unroll
        for (int i = 0; i < 2; ++i) {
            int row = wm * 32 + i * 16 + l15;
            af2[i] = *reinterpret_cast<const bf16x8*>(
                &lds[4096 + row * 256 + ((k0 + l4 * 8) ^ ((row & 7) << 3))]);
        }
#pragma unroll
        for (int j = 0; j < 2; ++j) {
            int d = wn * 32 + j * 16 + l15;
            bv2[j] = *reinterpret_cast<const bf16x8*>(&bbh[d * MLM + k0 + l4 * 8]);
        }
#pragma unroll
        for (int i = 0; i < 2; ++i)
#pragma unroll
            for (int j = 0; j < 2; ++j)
                acc2[i][j] = __builtin_amdgcn_mfma_f32_16x16x32_bf16(af2[i], bv2[j], acc2[i][j], 0, 0, 0);
    }
#pragma unroll
    for (int i = 0; i < 2; ++i)
#pragma unroll
        for (int r = 0; r < 4; ++r) {
            int row = wm * 32 + i * 16 + l4 * 4 + r;
            float inv = 1.f / (den[0][row] + den[1][row]);
#pragma unroll
            for (int j = 0; j < 2; ++j)
                attn[(size_t)(n0 + row) * INNER + h * DH + wn * 32 + j * 16 + l15]
                    = acc2[i][j][r] * inv;
        }
}

// ------------- landmark means from bf16 qkv (+ bf16 copies) -------------
__global__ __launch_bounds__(64) void landmark2_k(
    const unsigned short* __restrict__ qkvbf, float* __restrict__ q_l, float* __restrict__ k_l,
    unsigned short* __restrict__ ql_bf, unsigned short* __restrict__ kls_bf)
{
    int m = blockIdx.x, h = blockIdx.y, d = threadIdx.x;
    float sq = 0.f, sk = 0.f;
    for (int i = 0; i < LSUB; ++i) {
        size_t n = (size_t)m * LSUB + i;
        sq += bf2f(qkvbf[n * QKV_LD + h * DH + d]);
        sk += bf2f(qkvbf[n * QKV_LD + 512 + h * DH + d]);
    }
    float qv = sq * (0.125f / (float)LSUB);
    float kv = sk * (1.f / (float)LSUB);
    size_t o = ((size_t)h * MLM + m) * DH + d;
    q_l[o] = qv; k_l[o] = kv;
    ql_bf[o] = f2bf(qv);
    kls_bf[o] = f2bf(kv * 0.125f);
}

// ------------- v transpose: vT[h][d][n] = qkv_bf[n][1024+h*64+d] -------------
__global__ __launch_bounds__(256) void vt_k(
    const unsigned short* __restrict__ qkvbf, unsigned short* __restrict__ vT)
{
    __shared__ unsigned short tile[128][72];
    const int t = threadIdx.x;
    const int n0 = blockIdx.x * 128;
    const int h = blockIdx.y;
#pragma unroll
    for (int s = 0; s < 4; ++s) {
        int cid = s * 256 + t;
        int row = cid >> 3, ch = (cid & 7) * 8;
        uint4 v = *reinterpret_cast<const uint4*>(
            qkvbf + (size_t)(n0 + row) * QKV_LD + 1024 + h * 64 + ch);
        *reinterpret_cast<uint4*>(&tile[row][ch]) = v;
    }
    __syncthreads();
#pragma unroll
    for (int s = 0; s < 4; ++s) {
        int cid = s * 256 + t;
        int d = cid >> 4, nch = (cid & 15) * 8;
        unsigned short o[8];
#pragma unroll
        for (int i = 0; i < 8; ++i) o[i] = tile[nch + i][d];
        *reinterpret_cast<uint4*>(vT + (size_t)h * DH * NSEQ + (size_t)d * NSEQ + n0 + nch) =
            *reinterpret_cast<uint4*>(o);
    }
}

// ------------- bbT[h][d][j] = bf16(bb[h][j][d]) -------------
__global__ __launch_bounds__(256) void bbt_k(
    const float* __restrict__ bb, unsigned short* __restrict__ bbT)
{
    int idx = blockIdx.x * 256 + threadIdx.x;
    int h = idx >> 14, rem = idx & 16383;
    int d = rem >> 8, j = rem & 255;
    bbT[idx] = f2bf(bb[(h << 14) + (j << 6) + d]);
}

// ------------- a2 = softmax(q_l @ k_l^T) rows -------------
__global__ __launch_bounds__(256) void a2_k(
    const float* __restrict__ q_l, const float* __restrict__ k_l, float* __restrict__ a2)
{
    int i = blockIdx.x, h = blockIdx.y, t = threadIdx.x;
    __shared__ float ql[64];
    __shared__ float red[256];
    if (t < 64) ql[t] = q_l[((size_t)h * MLM + i) * DH + t];
    __syncthreads();
    const float* kr = k_l + ((size_t)h * MLM + t) * DH;
    float s = 0.f;
#pragma unroll
    for (int d = 0; d < 64; d += 4) {
        float4 kv = *reinterpret_cast<const float4*>(kr + d);
        s += kv.x * ql[d] + kv.y * ql[d + 1] + kv.z * ql[d + 2] + kv.w * ql[d + 3];
    }
    red[t] = s; __syncthreads();
    for (int off = 128; off > 0; off >>= 1) { if (t < off) red[t] = fmaxf(red[t], red[t + off]); __syncthreads(); }
    float m = red[0]; __syncthreads();
    float e = __expf(s - m);
    red[t] = e; __syncthreads();
    for (int off = 128; off > 0; off >>= 1) { if (t < off) red[t] += red[t + off]; __syncthreads(); }
    a2[(((size_t)h * MLM + i) * MLM) + t] = e / red[0];
}

// ------------- global max of row/col abs-sums of a2 -------------
__global__ __launch_bounds__(256) void absmax_k(
    const float* __restrict__ a2, unsigned int* __restrict__ scal)
{
    int b = blockIdx.x, t = threadIdx.x;
    __shared__ float red[256];
    float sum = 0.f;
    if (b < 8) {
        const float* r = a2 + ((size_t)b * MLM + t) * MLM;
        for (int j = 0; j < MLM; ++j) sum += fabsf(r[j]);
    } else {
        int h = b - 8;
        for (int i = 0; i < MLM; ++i) sum += fabsf(a2[((size_t)h * MLM + i) * MLM + t]);
    }
    red[t] = sum; __syncthreads();
    for (int off = 128; off > 0; off >>= 1) { if (t < off) red[t] = fmaxf(red[t], red[t + off]); __syncthreads(); }
    if (t == 0) atomicMax(scal + (b < 8 ? 0 : 1), __float_as_uint(red[0]));
}

// ------------- z0 = a2^T / (rmax*cmax) -------------
__global__ __launch_bounds__(256) void zinit_k(
    const float* __restrict__ a2, const unsigned int* __restrict__ scal, float* __restrict__ z)
{
    int idx = blockIdx.x * 256 + threadIdx.x;
    float rmax = __uint_as_float(scal[0]);
    float cmax = __uint_as_float(scal[1]);
    float inv = 1.f / (rmax * cmax);
    int h = idx >> 16, rem = idx & 65535, i = rem >> 8, j = rem & 255;
    z[idx] = a2[((size_t)h << 16) + (j << 8) + i] * inv;
}

// ------------- den3: row sums of exp-scores (rows of 8192) -------------
__global__ __launch_bounds__(256) void den3_k(
    const unsigned short* __restrict__ sc, float* __restrict__ den3)
{
    __shared__ float red[256];
    const int t = threadIdx.x;
    const unsigned short* row = sc + (size_t)blockIdx.x * NSEQ;
    float s = 0.f;
#pragma unroll
    for (int u = 0; u < 4; ++u) {
        uint4 pk = *reinterpret_cast<const uint4*>(row + t * 32 + u * 8);
        unsigned int w[4] = {pk.x, pk.y, pk.z, pk.w};
#pragma unroll
        for (int q = 0; q < 4; ++q) {
            s += bf2f((unsigned short)(w[q] & 0xFFFF));
            s += bf2f((unsigned short)(w[q] >> 16));
        }
    }
    red[t] = s; __syncthreads();
    for (int off = 128; off > 0; off >>= 1) { if (t < off) red[t] += red[t + off]; __syncthreads(); }
    if (t == 0) den3[blockIdx.x] = red[0];
}

__global__ __launch_bounds__(256) void red3_k(
    const float* __restrict__ part, const float* __restrict__ den3,
    float* __restrict__ a3v)
{
    int o = blockIdx.x * 256 + threadIdx.x;
    float s = 0.f;
#pragma unroll
    for (int kc = 0; kc < 16; ++kc) s += part[(size_t)kc * 131072 + o];
    a3v[o] = s / den3[o >> 6];
}

// ------------- depthwise conv residual add (register sliding window) -------------
__global__ __launch_bounds__(256) void conv_res2_k(
    const unsigned short* __restrict__ qkvbf, const float* __restrict__ kern,
    float* __restrict__ attn)
{
    const int t = threadIdx.x;
    const int cg = (blockIdx.y * 64 + (t & 63)) * 4;
    const int n0 = blockIdx.x * 32 + (t >> 6) * 8;
    const int h = cg >> 6;
    float kr[KCONV];
#pragma unroll
    for (int i = 0; i < KCONV; ++i) kr[i] = kern[h * KCONV + i];
    float acc[8][4] = {};
#pragma unroll
    for (int r = 0; r < 40; ++r) {
        int nn = n0 + r - 16;
        float v0 = 0.f, v1 = 0.f, v2 = 0.f, v3 = 0.f;
        if (nn >= 0 && nn < NSEQ) {
            ushort4 u = *reinterpret_cast<const ushort4*>(qkvbf + (size_t)nn * QKV_LD + 1024 + cg);
            v0 = bf2f(u.x); v1 = bf2f(u.y); v2 = bf2f(u.z); v3 = bf2f(u.w);
        }
#pragma unroll
        for (int j = 0; j < 8; ++j) {
            int tt = r - j;
            if (tt >= 0 && tt < KCONV) {
                acc[j][0] += kr[tt] * v0; acc[j][1] += kr[tt] * v1;
                acc[j][2] += kr[tt] * v2; acc[j][3] += kr[tt] * v3;
            }
        }
    }
#pragma unroll
    for (int j = 0; j < 8; ++j) {
        float4* p = reinterpret_cast<float4*>(attn + (size_t)(n0 + j) * INNER + cg);
        float4 c = *p;
        c.x += acc[j][0]; c.y += acc[j][1]; c.z += acc[j][2]; c.w += acc[j][3];
        *p = c;
    }
}

// ------------- sparse edge scores: 8 lanes/edge, 32 dims/lane -------------
__global__ __launch_bounds__(256) void edge2_k(
    const unsigned short* __restrict__ qke,
    const int* __restrict__ rows, const int* __restrict__ cols,
    const float* __restrict__ vals, float* __restrict__ A_raw)
{
    const int e = blockIdx.x * 32 + (threadIdx.x >> 3);
    const int g = threadIdx.x & 7;
    const int r = rows[e], c = cols[e];
    const unsigned short* qr = qke + (size_t)r * 512 + g * 32;
    const unsigned short* kr = qke + (size_t)c * 512 + 256 + g * 32;
    float s = 0.f;
#pragma unroll
    for (int u = 0; u < 4; ++u) {
        uint4 qa = *reinterpret_cast<const uint4*>(qr + u * 8);
        uint4 ka = *reinterpret_cast<const uint4*>(kr + u * 8);
        unsigned int qw[4] = {qa.x, qa.y, qa.z, qa.w};
        unsigned int kw[4] = {ka.x, ka.y, ka.z, ka.w};
#pragma unroll
        for (int q = 0; q < 4; ++q) {
            s += bf2f((unsigned short)(qw[q] & 0xFFFF)) * bf2f((unsigned short)(kw[q] & 0xFFFF));
            s += bf2f((unsigned short)(qw[q] >> 16)) * bf2f((unsigned short)(kw[q] >> 16));
        }
    }
    s += __shfl_xor(s, 1); s += __shfl_xor(s, 2); s += __shfl_xor(s, 4);
    if (g == 0) atomicAdd(&A_raw[r], s * vals[e] * 0.0625f);
}

// ------------- alpha = softmax(A_raw) -------------
__global__ __launch_bounds__(1024) void alpha_k(
    const float* __restrict__ A_raw, float* __restrict__ alpha)
{
    __shared__ float red[1024];
    int t = threadIdx.x;
    float m = -1e30f;
    for (int i = t; i < NSEQ; i += 1024) m = fmaxf(m, A_raw[i]);
    red[t] = m; __syncthreads();
    for (int off = 512; off > 0; off >>= 1) { if (t < off) red[t] = fmaxf(red[t], red[t + off]); __syncthreads(); }
    m = red[0]; __syncthreads();
    float s = 0.f;
    for (int i = t; i < NSEQ; i += 1024) s += __expf(A_raw[i] - m);
    red[t] = s; __syncthreads();
    for (int off = 512; off > 0; off >>= 1) { if (t < off) red[t] += red[t + off]; __syncthreads(); }
    float inv = 1.f / red[0];
    for (int i = t; i < NSEQ; i += 1024) alpha[i] = __expf(A_raw[i] - m) * inv;
}

// ------------- final gated blend -------------
__global__ __launch_bounds__(256) void final_k(
    const float* __restrict__ alpha, const float* __restrict__ value,
    const float* __restrict__ enc, float* __restrict__ xo)
{
    size_t idx = (size_t)blockIdx.x * 256 + threadIdx.x;
    int n = (int)(idx >> 9);
    float xl = alpha[n] * value[idx];
    float w = 1.f / (1.f + __expf(xl));
    float sq = w * w;
    xo[idx] = xl * 2.f * sq + 2.f * enc[idx] * (1.f - sq);
}

extern "C" void kernel_launch(void* const* d_in, const int* in_sizes, int n_in,
                              void* d_out, int out_size, void* d_ws, size_t ws_size,
                              hipStream_t stream)
{
    const float* dense      = (const float*)d_in[0];
    const int*   adj_rows   = (const int*)d_in[1];
    const int*   adj_cols   = (const int*)d_in[2];
    const float* adj_vals   = (const float*)d_in[3];
    const float* wq         = (const float*)d_in[4];
    const float* wk         = (const float*)d_in[5];
    const float* w_qkv      = (const float*)d_in[6];
    const float* w_out      = (const float*)d_in[7];
    const float* b_out      = (const float*)d_in[8];
    const float* res_kernel = (const float*)d_in[9];
    const float* wv_w       = (const float*)d_in[10];
    const float* wv_b       = (const float*)d_in[11];
    const int E = in_sizes[1];

    float* ws  = (float*)d_ws;
    float* out = (float*)d_out;
    float* A_raw = out + (size_t)NSEQ * DDIM;

    unsigned short* qkv_bf   = (unsigned short*)(ws + OFF_QKVBF);
    unsigned short* vT       = (unsigned short*)(ws + OFF_VT);
    unsigned short* sc       = (unsigned short*)(ws + OFF_SC);
    unsigned short* qke_bf   = (unsigned short*)(ws + OFF_QKE);
    unsigned short* attn_bf  = (unsigned short*)(ws + OFF_ATTNBF);
    unsigned short* dense_bf = (unsigned short*)(ws + OFF_DENSEBF);
    unsigned short* wqkv_bf  = (unsigned short*)(ws + OFF_WQKVBF);
    unsigned short* wout_bf  = (unsigned short*)(ws + OFF_WOUTBF);
    unsigned short* wqkT_bf  = (unsigned short*)(ws + OFF_WQKT);
    unsigned short* wv_bf    = (unsigned short*)(ws + OFF_WVBF);
    unsigned short* ql_bf    = (unsigned short*)(ws + OFF_QLBF);
    unsigned short* kls_bf   = (unsigned short*)(ws + OFF_KLSBF);
    unsigned short* bbT_bf   = (unsigned short*)(ws + OFF_BBT);
    unsigned short* enc_bf   = (unsigned short*)(ws + OFF_ENCBF);

    hipMemsetAsync(A_raw, 0, NSEQ * sizeof(float), stream);
    hipMemsetAsync(ws + OFF_SCAL, 0, 2 * sizeof(unsigned int), stream);

    // ---- input conversions ----
    cvt_bf16_k<<<(NSEQ * DDIM) / 2048, 256, 0, stream>>>(dense, dense_bf);
    cvt_bf16_k<<<(1536 * DDIM) / 2048, 256, 0, stream>>>(w_qkv, wqkv_bf);

    // qkv = dense @ w_qkv^T  -> bf16
    gemm_mfma_ntb<<<dim3(NSEQ / 64, 1536 / 128, 1), 256, 0, stream>>>(
        dense_bf, DDIM, 0, wqkv_bf, DDIM, 0, nullptr, qkv_bf, QKV_LD, 0,
        DDIM, nullptr, nullptr, 0);

    landmark2_k<<<dim3(MLM, HEADS), 64, 0, stream>>>(
        qkv_bf, ws + OFF_QL, ws + OFF_KL, ql_bf, kls_bf);
    vt_k<<<dim3(NSEQ / 128, HEADS), 256, 0, stream>>>(qkv_bf, vT);

    // ---- a3 pipeline (exp-scores, no softmax pass) ----
    gemm_mfma_ntb<<<dim3(MLM / 64, NSEQ / 128, HEADS), 256, 0, stream>>>(
        ql_bf, DH, (size_t)MLM * DH, qkv_bf + 512, QKV_LD, DH,
        nullptr, sc, NSEQ, (size_t)MLM * NSEQ, DH, nullptr, nullptr, 1);
    den3_k<<<HEADS * MLM, 256, 0, stream>>>(sc, ws + OFF_DEN3);
    pv3_mfma<<<dim3(4, 16, HEADS), 256, 0, stream>>>(sc, vT, ws + OFF_ATTN);
    red3_k<<<512, 256, 0, stream>>>(ws + OFF_ATTN, ws + OFF_DEN3, ws + OFF_A3V);

    a2_k<<<dim3(MLM, HEADS), 256, 0, stream>>>(ws + OFF_QL, ws + OFF_KL, ws + OFF_A2);
    absmax_k<<<16, 256, 0, stream>>>(ws + OFF_A2, (unsigned int*)(ws + OFF_SCAL));
    zinit_k<<<(HEADS * MLM * MLM) / 256, 256, 0, stream>>>(
        ws + OFF_A2, (const unsigned int*)(ws + OFF_SCAL), ws + OFF_Z0);

    // pinv iterations via MFMA hi/lo split (fp32-accurate)
    for (int it = 0; it < 6; ++it) {
        float* zin  = ws + ((it & 1) ? OFF_Z1 : OFF_Z0);
        float* zout = ws + ((it & 1) ? OFF_Z0 : OFF_Z1);
        bmm_split<<<dim3(16, HEADS), 256, 0, stream>>>(ws + OFF_A2, zin, ws + OFF_P,
            256, 256, 4, 65536, 65536, 65536, 0.f, 1.f);
        bmm_split<<<dim3(16, HEADS), 256, 0, stream>>>(ws + OFF_P, ws + OFF_P, ws + OFF_T1,
            256, 256, 4, 65536, 65536, 65536, 7.f, -1.f);
        bmm_split<<<dim3(16, HEADS), 256, 0, stream>>>(ws + OFF_P, ws + OFF_T1, ws + OFF_T2,
            256, 256, 4, 65536, 65536, 65536, 15.f, -1.f);
        bmm_split<<<dim3(16, HEADS), 256, 0, stream>>>(zin, ws + OFF_T2, zout,
            256, 256, 4, 65536, 65536, 65536, 3.25f, -0.25f);
    }
    // bb = z_final @ a3v
    bmm_split<<<dim3(4, HEADS), 256, 0, stream>>>(ws + OFF_Z0, ws + OFF_A3V, ws + OFF_BB,
        256, 64, 1, 65536, 16384, 16384, 0.f, 1.f);
    bbt_k<<<512, 256, 0, stream>>>(ws + OFF_BB, bbT_bf);

    // ---- fused a1 (QK + exp-softmax + PV in one kernel) ----
    a1_fused<<<dim3(NSEQ / 64, HEADS), 256, 0, stream>>>(
        qkv_bf, kls_bf, bbT_bf, ws + OFF_ATTN);
    conv_res2_k<<<dim3(NSEQ / 32, 2), 256, 0, stream>>>(qkv_bf, res_kernel, ws + OFF_ATTN);

    // ---- attn + late weights to bf16 ----
    cvt_bf16_k<<<(NSEQ * INNER) / 2048, 256, 0, stream>>>(ws + OFF_ATTN, attn_bf);
    cvt_bf16_k<<<(DDIM * INNER) / 2048, 256, 0, stream>>>(w_out, wout_bf);
    tcvt_bf16_k<<<(WP * DDIM + 255) / 256, 256, 0, stream>>>(wq, wqkT_bf, DDIM, WP);
    tcvt_bf16_k<<<(WP * DDIM + 255) / 256, 256, 0, stream>>>(wk, wqkT_bf + 256 * 512, DDIM, WP);
    cvt_bf16_k<<<(DDIM * DDIM) / 2048, 256, 0, stream>>>(wv_w, wv_bf);

    // enc = attn @ w_out^T + b_out + dense  (fp32 + bf16)
    gemm_mfma_ntb<<<dim3(NSEQ / 64, DDIM / 128, 1), 256, 0, stream>>>(
        attn_bf, INNER, 0, wout_bf, INNER, 0, ws + OFF_ENC, enc_bf, DDIM, 0,
        INNER, b_out, dense, 0);

    // qke = enc @ [wq|wk] -> bf16
    gemm_mfma_ntb<<<dim3(NSEQ / 64, 512 / 128, 1), 256, 0, stream>>>(
        enc_bf, DDIM, 0, wqkT_bf, DDIM, 0, nullptr, qke_bf, 512, 0,
        DDIM, nullptr, nullptr, 0);

    edge2_k<<<E / 32, 256, 0, stream>>>(qke_bf, adj_rows, adj_cols, adj_vals, A_raw);
    alpha_k<<<1, 1024, 0, stream>>>(A_raw, ws + OFF_ALPHA);

    // value = dense @ wv_w^T + wv_b
    cvt_bf16_k<<<(NSEQ * DDIM) / 2048, 256, 0, stream>>>(dense, dense_bf);
    gemm_mfma_ntb<<<dim3(NSEQ / 64, DDIM / 128, 1), 256, 0, stream>>>(
        dense_bf, DDIM, 0, wv_bf, DDIM, 0, ws + OFF_VAL, nullptr, DDIM, 0,
        DDIM, wv_b, nullptr, 0);

    final_k<<<(NSEQ * DDIM) / 256, 256, 0, stream>>>(
        ws + OFF_ALPHA, ws + OFF_VAL, ws + OFF_ENC, out);
}